// Round 8
// baseline (59608.600 us; speedup 1.0000x reference)
//
#include <hip/hip_runtime.h>
#include <hip/hip_bf16.h>
#include <math.h>

typedef __hip_bfloat16 bf16;

__device__ __forceinline__ float LD(const float* p) { return *p; }
__device__ __forceinline__ float LD(const bf16* p)  { return __bfloat162float(*p); }
__device__ __forceinline__ void  ST(float* p, float v) { *p = v; }
__device__ __forceinline__ void  ST(bf16* p, float v)  { *p = __float2bfloat16(v); }

// ---------------- f32 copy ----------------
__global__ __launch_bounds__(256) void copy_kernel(const float* __restrict__ in,
                                                   float* __restrict__ out, int n) {
    int i = blockIdx.x * blockDim.x + threadIdx.x;
    if (i < n) out[i] = in[i];
}

// ---------------- NAIVE conv: one thread per (b,o,pixel) ----------------
// channels [0,C1) from src1 (T1), [C1,C) from src2 (T2), both at source res (Hs,Ws)
// UP: input is nearest-2x upsample of source; pad applied on upsampled (H,W) grid
// EPI: 0 = f32 store; 1 = tanh -> f32; 2 = raw -> bf16
template<typename T1, typename T2, int K, bool REFLECT, bool UP, int EPI>
__global__ __launch_bounds__(256) void conv_naive(
        const T1* __restrict__ src1, const T2* __restrict__ src2,
        int C1, int C,
        const float* __restrict__ w, const float* __restrict__ bias,
        void* __restrict__ outv, int B, int O, int H, int W)
{
    const int HW = H * W;
    const long long total = (long long)B * O * HW;
    const long long gid = (long long)blockIdx.x * blockDim.x + threadIdx.x;
    if (gid >= total) return;
    const int p = (int)(gid % HW);
    const int o = (int)((gid / HW) % O);
    const int b = (int)(gid / ((long long)HW * O));
    const int y = p / W, x = p - y * W;
    const int Hs = UP ? (H >> 1) : H;
    const int Ws = UP ? (W >> 1) : W;
    const int HsWs = Hs * Ws;
    const int PAD = K / 2;

    float acc = bias[o];
    const float* wo = w + (size_t)o * C * K * K;
    for (int c = 0; c < C; ++c) {
        const float* wc = wo + c * K * K;
        const T1* pl1 = (c < C1) ? (src1 + ((size_t)b * C1 + c) * HsWs) : (const T1*)0;
        const T2* pl2 = (c >= C1) ? (src2 + ((size_t)b * (C - C1) + (c - C1)) * HsWs) : (const T2*)0;
        for (int ty = 0; ty < K; ++ty) {
            int yy = y + ty - PAD;
            if (REFLECT) {
                yy = yy < 0 ? -yy : yy;
                yy = yy >= H ? 2 * H - 2 - yy : yy;
            } else if (yy < 0 || yy >= H) continue;
            const int sy = UP ? (yy >> 1) : yy;
            for (int tx = 0; tx < K; ++tx) {
                int xx = x + tx - PAD;
                if (REFLECT) {
                    xx = xx < 0 ? -xx : xx;
                    xx = xx >= W ? 2 * W - 2 - xx : xx;
                } else if (xx < 0 || xx >= W) continue;
                const int sx = UP ? (xx >> 1) : xx;
                const float v = (c < C1) ? LD(pl1 + sy * Ws + sx) : LD(pl2 + sy * Ws + sx);
                acc += wc[ty * K + tx] * v;
            }
        }
    }
    const size_t oidx = (size_t)(b * O + o) * HW + p;
    if (EPI == 0)      ((float*)outv)[oidx] = acc;
    else if (EPI == 1) ((float*)outv)[oidx] = tanhf(acc);     // OUTPUT IS FLOAT32
    else               ((bf16*)outv)[oidx] = __float2bfloat16(acc);
}

// ---------------- instance norm (per (b,c) plane), LDS-tree reduction ----------------
// mode 0: buf = relu(norm(buf));  mode 1: resid = resid + norm(buf)
template<typename T>
__global__ __launch_bounds__(256) void inorm_kernel(T* __restrict__ buf,
                                                    float* __restrict__ resid,
                                                    int HW, int mode)
{
    __shared__ double sh0[256], sh1[256];
    const int pl = blockIdx.x;
    T* p = buf + (size_t)pl * HW;
    double s = 0.0, ss = 0.0;
    for (int i = threadIdx.x; i < HW; i += 256) {
        float v = LD(p + i);
        s += (double)v; ss += (double)v * (double)v;
    }
    sh0[threadIdx.x] = s; sh1[threadIdx.x] = ss;
    __syncthreads();
    for (int st = 128; st > 0; st >>= 1) {
        if (threadIdx.x < st) {
            sh0[threadIdx.x] += sh0[threadIdx.x + st];
            sh1[threadIdx.x] += sh1[threadIdx.x + st];
        }
        __syncthreads();
    }
    const double mean = sh0[0] / HW;
    const float m = (float)mean;
    const float var = (float)(sh1[0] / HW - mean * mean);
    const float inv = rsqrtf(var + 1e-5f);
    if (mode == 0) {
        for (int i = threadIdx.x; i < HW; i += 256) {
            float v = (LD(p + i) - m) * inv;
            ST(p + i, v > 0.f ? v : 0.f);
        }
    } else {
        float* r = resid + (size_t)pl * HW;
        for (int i = threadIdx.x; i < HW; i += 256)
            r[i] = r[i] + (LD(p + i) - m) * inv;
    }
}

// ---------------- modulated deformable conv, NAIVE (one thread per b,o,pixel) ----------------
// om: [B,27,H,W]: ch 2k=dy_k, 2k+1=dx_k, 18+k=mask logits. skip f32.
template<typename OT>
__global__ __launch_bounds__(256) void mdcn_naive(
        const float* __restrict__ skip, const float* __restrict__ om,
        const float* __restrict__ w, const float* __restrict__ bias,
        OT* __restrict__ out, int C, int O, int H, int W)
{
    const int HW = H * W;
    const int gid = blockIdx.x * blockDim.x + threadIdx.x;
    const int total = 8 * O * HW;
    if (gid >= total) return;
    const int p = gid % HW;
    const int o = (gid / HW) % O;
    const int b = gid / (HW * O);
    const int y = p / W, x = p - y * W;
    const float* omb = om + (size_t)b * 27 * HW;
    const float* xb  = skip + (size_t)b * C * HW;

    float acc = bias[o];
    for (int k = 0; k < 9; ++k) {
        const float dy = omb[(2 * k) * HW + p];
        const float dx = omb[(2 * k + 1) * HW + p];
        const float mk = 1.f / (1.f + expf(-omb[(18 + k) * HW + p]));
        float py = (float)(y + k / 3 - 1) + dy;
        float px = (float)(x + k % 3 - 1) + dx;
        py = fminf(fmaxf(py, -2.f), (float)H + 1.f);   // OOB -> all taps invalid (= ref zero)
        px = fminf(fmaxf(px, -2.f), (float)W + 1.f);
        const float y0f = floorf(py), x0f = floorf(px);
        const int y0 = (int)y0f, x0 = (int)x0f;
        const float wy1 = py - y0f, wx1 = px - x0f;
        const float wy0 = 1.f - wy1, wx0 = 1.f - wx1;
        const bool r0v = (y0 >= 0 && y0 < H);
        const bool r1v = (y0 + 1 >= 0 && y0 + 1 < H);
        const bool c0v = (x0 >= 0 && x0 < W);
        const bool c1v = (x0 + 1 >= 0 && x0 + 1 < W);
        const float w00 = (r0v && c0v) ? wy0 * wx0 : 0.f;
        const float w01 = (r0v && c1v) ? wy0 * wx1 : 0.f;
        const float w10 = (r1v && c0v) ? wy1 * wx0 : 0.f;
        const float w11 = (r1v && c1v) ? wy1 * wx1 : 0.f;
        const int i00 = (r0v ? y0 : 0) * W + (c0v ? x0 : 0);
        const int i01 = (r0v ? y0 : 0) * W + (c1v ? x0 + 1 : 0);
        const int i10 = (r1v ? y0 + 1 : 0) * W + (c0v ? x0 : 0);
        const int i11 = (r1v ? y0 + 1 : 0) * W + (c1v ? x0 + 1 : 0);
        const float* wok = w + (size_t)o * C * 9 + k;
        for (int c = 0; c < C; ++c) {
            const float* pl = xb + (size_t)c * HW;
            const float v = w00 * pl[i00] + w01 * pl[i01] + w10 * pl[i10] + w11 * pl[i11];
            acc += wok[c * 9] * (v * mk);
        }
    }
    ST(out + (size_t)(b * O + o) * HW + p, acc);
}

// ---------------- offset_sum = 0.5*(mean|om1[:, :18]| + mean|om2[:, :18]|) ----------------
__global__ __launch_bounds__(256) void offsum_kernel(const float* __restrict__ om1, int HW1,
                                                     const float* __restrict__ om2, int HW2,
                                                     float* __restrict__ out)
{
    __shared__ double sh1[256], sh2[256];
    double s1 = 0.0, s2 = 0.0;
    const int n1 = 8 * 18 * HW1, n2 = 8 * 18 * HW2;
    for (int i = threadIdx.x; i < n1; i += 256) {
        const int b = i / (18 * HW1); const int r = i - b * 18 * HW1;
        const int c = r / HW1; const int p = r - c * HW1;
        s1 += fabs((double)om1[(size_t)(b * 27 + c) * HW1 + p]);
    }
    for (int i = threadIdx.x; i < n2; i += 256) {
        const int b = i / (18 * HW2); const int r = i - b * 18 * HW2;
        const int c = r / HW2; const int p = r - c * HW2;
        s2 += fabs((double)om2[(size_t)(b * 27 + c) * HW2 + p]);
    }
    sh1[threadIdx.x] = s1; sh2[threadIdx.x] = s2;
    __syncthreads();
    for (int st = 128; st > 0; st >>= 1) {
        if (threadIdx.x < st) {
            sh1[threadIdx.x] += sh1[threadIdx.x + st];
            sh2[threadIdx.x] += sh2[threadIdx.x + st];
        }
        __syncthreads();
    }
    if (threadIdx.x == 0)
        out[0] = (float)(0.5 * (sh1[0] / n1 + sh2[0] / n2));
}

// ---------------- launch ----------------
extern "C" void kernel_launch(void* const* d_in, const int* in_sizes, int n_in,
                              void* d_out, int out_size, void* d_ws, size_t ws_size,
                              hipStream_t stream)
{
    if (n_in < 27) return;
    if (out_size < 393217) return;
    if (in_sizes[0] != 8 * 256 * 32 * 32) return;
    if (in_sizes[1] != 8 * 128 * 64 * 64) return;
    if (in_sizes[2] != 8 * 256 * 32 * 32) return;
    if (in_sizes[25] != 128 * 128 * 9) return;
    if (in_sizes[26] != 128) return;

    // inputs f32; OUTPUT f32 (this round's hypothesis)
    const float* x        = (const float*)d_in[0];
    const float* skip1    = (const float*)d_in[1];
    const float* skip2    = (const float*)d_in[2];
    const float* rbw[2][2] = {{(const float*)d_in[3], (const float*)d_in[5]},
                              {(const float*)d_in[7], (const float*)d_in[9]}};
    const float* rbb[2][2] = {{(const float*)d_in[4], (const float*)d_in[6]},
                              {(const float*)d_in[8], (const float*)d_in[10]}};
    const float* conv1_w = (const float*)d_in[11]; const float* conv1_b = (const float*)d_in[12];
    const float* conv3_w = (const float*)d_in[13]; const float* conv3_b = (const float*)d_in[14];
    const float* conv5_w = (const float*)d_in[15]; const float* conv5_b = (const float*)d_in[16];
    const float* conv6_w = (const float*)d_in[17]; const float* conv6_b = (const float*)d_in[18];
    const float* dcn2_off_w = (const float*)d_in[19]; const float* dcn2_off_b = (const float*)d_in[20];
    const float* dcn2_w = (const float*)d_in[21]; const float* dcn2_b = (const float*)d_in[22];
    const float* dcn1_off_w = (const float*)d_in[23]; const float* dcn1_off_b = (const float*)d_in[24];
    const float* dcn1_w = (const float*)d_in[25]; const float* dcn1_b = (const float*)d_in[26];

    float* outp = (float*)d_out;

    const size_t NEED_F32 = 9494528ull;
    if (ws_size < NEED_F32 * 4ull) return;

    float* ws = (float*)d_ws;
    const size_t NA = 2097152ull;            // 8*256*32*32
    float* A   = ws;                          // [0, 2M)   x / rb accum / pre2
    float* Bb  = ws + NA;                     // [2M, 4M)  h / D
    float* Tmp = ws + 2 * NA;                 // [4M, 6M)  rb second conv out
    float* om2 = ws + 3 * NA;                 // [6M, +221184)
    float* om1 = om2 + 221184;                // [+884736)
    bf16*  Fb  = (bf16*)(om1 + 884736);       // c3 bf16 (2M f32-eq)
    bf16*  Ib  = (bf16*)A;                    // pre1 bf16 (A region, dead by then)
    bf16*  Jb  = (bf16*)Bb;                   // c5 bf16 (Bb+Tmp regions, dead by then)

    copy_kernel<<<8192, 256, 0, stream>>>(x, A, (int)NA);

    // ResBlocks
    for (int r = 0; r < 2; ++r) {
        conv_naive<float, float, 3, true, false, 0><<<8192, 256, 0, stream>>>(
            A, (const float*)nullptr, 256, 256, rbw[r][0], rbb[r][0], Bb, 8, 256, 32, 32);
        inorm_kernel<float><<<2048, 256, 0, stream>>>(Bb, nullptr, 1024, 0);
        conv_naive<float, float, 3, true, false, 0><<<8192, 256, 0, stream>>>(
            Bb, (const float*)nullptr, 256, 256, rbw[r][1], rbb[r][1], Tmp, 8, 256, 32, 32);
        inorm_kernel<float><<<2048, 256, 0, stream>>>(Tmp, A, 1024, 1);
    }

    // conv1 + IN/ReLU
    conv_naive<float, float, 5, true, false, 0><<<8192, 256, 0, stream>>>(
        A, (const float*)nullptr, 256, 256, conv1_w, conv1_b, Bb, 8, 256, 32, 32);
    inorm_kernel<float><<<2048, 256, 0, stream>>>(Bb, nullptr, 1024, 0);

    // dcn2: off-conv (zero-pad) + mdcn
    conv_naive<float, float, 3, false, false, 0><<<864, 256, 0, stream>>>(
        Bb, skip2, 256, 512, dcn2_off_w, dcn2_off_b, om2, 8, 27, 32, 32);
    mdcn_naive<float><<<8192, 256, 0, stream>>>(
        skip2, om2, dcn2_w, dcn2_b, A, 256, 256, 32, 32);

    // conv3 (2x-up fused) + IN/ReLU
    conv_naive<float, float, 5, true, true, 2><<<16384, 256, 0, stream>>>(
        A, Bb, 256, 512, conv3_w, conv3_b, Fb, 8, 128, 64, 64);
    inorm_kernel<bf16><<<1024, 256, 0, stream>>>(Fb, nullptr, 4096, 0);

    // dcn1: off-conv (zero-pad) + mdcn
    conv_naive<bf16, float, 3, false, false, 0><<<3456, 256, 0, stream>>>(
        Fb, skip1, 128, 256, dcn1_off_w, dcn1_off_b, om1, 8, 27, 64, 64);
    mdcn_naive<bf16><<<16384, 256, 0, stream>>>(
        skip1, om1, dcn1_w, dcn1_b, Ib, 128, 128, 64, 64);

    // conv5 (2x-up fused) + IN/ReLU
    conv_naive<bf16, bf16, 5, true, true, 2><<<32768, 256, 0, stream>>>(
        Ib, Fb, 128, 256, conv5_w, conv5_b, Jb, 8, 64, 128, 128);
    inorm_kernel<bf16><<<512, 256, 0, stream>>>(Jb, nullptr, 16384, 0);

    // conv6 + tanh -> d_out (FLOAT32)
    conv_naive<bf16, float, 7, true, false, 1><<<1536, 256, 0, stream>>>(
        Jb, (const float*)nullptr, 64, 64, conv6_w, conv6_b, (void*)outp, 8, 3, 128, 128);

    // offset_sum -> d_out[393216] (FLOAT32)
    offsum_kernel<<<1, 256, 0, stream>>>(om1, 4096, om2, 1024, outp + 393216);
}

// Round 9
// 15659.035 us; speedup vs baseline: 3.8067x; 3.8067x over previous
//
#include <hip/hip_runtime.h>
#include <hip/hip_bf16.h>
#include <math.h>

typedef __hip_bfloat16 bf16;

__device__ __forceinline__ float LD(const float* p) { return *p; }
__device__ __forceinline__ float LD(const bf16* p)  { return __bfloat162float(*p); }
__device__ __forceinline__ void  ST(float* p, float v) { *p = v; }
__device__ __forceinline__ void  ST(bf16* p, float v)  { *p = __float2bfloat16(v); }

// ---------------- f32 copy ----------------
__global__ __launch_bounds__(256) void copy_kernel(const float* __restrict__ in,
                                                   float* __restrict__ out, int n) {
    int i = blockIdx.x * blockDim.x + threadIdx.x;
    if (i < n) out[i] = in[i];
}

// ---------------- register-blocked conv ----------------
// thread = 1 pixel, NO output channels in registers; weights fetched via
// wave-uniform (scalar) loads. PXT pixels per block; 256/PXT o-groups per block.
// grid: (HW/PXT, B, O/( (256/PXT)*NO )) -- o guarded.
// EPI: 0 = f32 store; 1 = tanh -> f32; 2 = raw -> bf16
template<typename T1, typename T2, int K, bool REFLECT, bool UP, int EPI, int PXT, int NO>
__global__ __launch_bounds__(256) void conv_reg(
        const T1* __restrict__ src1, const T2* __restrict__ src2,
        int C1, int C,
        const float* __restrict__ w, const float* __restrict__ bias,
        void* __restrict__ outv, int O, int H, int W)
{
    constexpr int KK = K * K;
    const int tid = threadIdx.x;
    const int px  = tid % PXT;
    // wave-uniform o-base (PXT is 64 or 256 -> all 64 lanes share oset)
    const int o_base = __builtin_amdgcn_readfirstlane(
        blockIdx.z * (256 / PXT) * NO + (tid / PXT) * NO);
    const int b = blockIdx.y;
    const int p = blockIdx.x * PXT + px;
    const int HW = H * W;
    const int y = p / W, x = p - y * W;
    const int Hs = UP ? (H >> 1) : H;
    const int Ws = UP ? (W >> 1) : W;
    const int HsWs = Hs * Ws;
    const int PAD = K / 2;

    int off[KK];
    float msk[KK];
#pragma unroll
    for (int ty = 0; ty < K; ++ty) {
#pragma unroll
        for (int tx = 0; tx < K; ++tx) {
            int yy = y + ty - PAD, xx = x + tx - PAD;
            bool v = true;
            if (REFLECT) {
                yy = yy < 0 ? -yy : yy; yy = yy >= H ? 2 * H - 2 - yy : yy;
                xx = xx < 0 ? -xx : xx; xx = xx >= W ? 2 * W - 2 - xx : xx;
            } else {
                v = (yy >= 0 && yy < H && xx >= 0 && xx < W);
                yy = yy < 0 ? 0 : (yy >= H ? H - 1 : yy);
                xx = xx < 0 ? 0 : (xx >= W ? W - 1 : xx);
            }
            const int sy = UP ? (yy >> 1) : yy;
            const int sx = UP ? (xx >> 1) : xx;
            off[ty * K + tx] = sy * Ws + sx;
            msk[ty * K + tx] = v ? 1.f : 0.f;
        }
    }

    float acc[NO];
#pragma unroll
    for (int no = 0; no < NO; ++no) acc[no] = 0.f;

    const int C2 = C - C1;
    {
        const T1* pb = src1 + (size_t)b * C1 * HsWs;
        for (int c = 0; c < C1; ++c) {
            const T1* pl = pb + (size_t)c * HsWs;
            float tap[KK];
#pragma unroll
            for (int t = 0; t < KK; ++t) {
                const float v = LD(pl + off[t]);
                tap[t] = REFLECT ? v : v * msk[t];
            }
            const float* wc = w + ((size_t)o_base * C + c) * KK;
#pragma unroll
            for (int no = 0; no < NO; ++no) {
                const int oo = (o_base + no < O) ? no : 0;  // avoid OOB weight reads
                const float* wn = wc + (size_t)oo * C * KK;
#pragma unroll
                for (int t = 0; t < KK; ++t) acc[no] += wn[t] * tap[t];
            }
        }
    }
    if (C2 > 0) {
        const T2* pb = src2 + (size_t)b * C2 * HsWs;
        for (int c = 0; c < C2; ++c) {
            const T2* pl = pb + (size_t)c * HsWs;
            float tap[KK];
#pragma unroll
            for (int t = 0; t < KK; ++t) {
                const float v = LD(pl + off[t]);
                tap[t] = REFLECT ? v : v * msk[t];
            }
            const float* wc = w + ((size_t)o_base * C + C1 + c) * KK;
#pragma unroll
            for (int no = 0; no < NO; ++no) {
                const int oo = (o_base + no < O) ? no : 0;
                const float* wn = wc + (size_t)oo * C * KK;
#pragma unroll
                for (int t = 0; t < KK; ++t) acc[no] += wn[t] * tap[t];
            }
        }
    }

#pragma unroll
    for (int no = 0; no < NO; ++no) {
        const int o = o_base + no;
        if (o < O) {
            const float v = acc[no] + bias[o];
            const size_t oidx = (size_t)(b * O + o) * HW + p;
            if (EPI == 0)      ((float*)outv)[oidx] = v;
            else if (EPI == 1) ((float*)outv)[oidx] = tanhf(v);
            else               ((bf16*)outv)[oidx] = __float2bfloat16(v);
        }
    }
}

// ---------------- instance norm (per (b,c) plane), LDS-tree reduction ----------------
template<typename T>
__global__ __launch_bounds__(256) void inorm_kernel(T* __restrict__ buf,
                                                    float* __restrict__ resid,
                                                    int HW, int mode)
{
    __shared__ double sh0[256], sh1[256];
    const int pl = blockIdx.x;
    T* p = buf + (size_t)pl * HW;
    double s = 0.0, ss = 0.0;
    for (int i = threadIdx.x; i < HW; i += 256) {
        float v = LD(p + i);
        s += (double)v; ss += (double)v * (double)v;
    }
    sh0[threadIdx.x] = s; sh1[threadIdx.x] = ss;
    __syncthreads();
    for (int st = 128; st > 0; st >>= 1) {
        if (threadIdx.x < st) {
            sh0[threadIdx.x] += sh0[threadIdx.x + st];
            sh1[threadIdx.x] += sh1[threadIdx.x + st];
        }
        __syncthreads();
    }
    const double mean = sh0[0] / HW;
    const float m = (float)mean;
    const float var = (float)(sh1[0] / HW - mean * mean);
    const float inv = rsqrtf(var + 1e-5f);
    if (mode == 0) {
        for (int i = threadIdx.x; i < HW; i += 256) {
            float v = (LD(p + i) - m) * inv;
            ST(p + i, v > 0.f ? v : 0.f);
        }
    } else {
        float* r = resid + (size_t)pl * HW;
        for (int i = threadIdx.x; i < HW; i += 256)
            r[i] = r[i] + (LD(p + i) - m) * inv;
    }
}

// ---------------- weight transpose: w[o][c][k] -> wT[c*9+k][o] ----------------
__global__ __launch_bounds__(256) void wtrans_kernel(const float* __restrict__ w,
                                                     float* __restrict__ wT, int C, int O)
{
    const int i = blockIdx.x * 256 + threadIdx.x;
    const int n = O * C * 9;
    if (i >= n) return;
    const int o = i / (C * 9);
    const int r = i - o * C * 9;           // r = c*9+k
    wT[(size_t)r * O + o] = w[i];
}

// ---------------- modulated deformable conv, cooperative LDS ----------------
// NT threads = O; T pixels/block; CC channel chunk. wT transposed [c*9+k][O].
template<int NT, int T, int CC, typename OT>
__global__ __launch_bounds__(256) void mdcn_lds(
        const float* __restrict__ skip, const float* __restrict__ om,
        const float* __restrict__ wT, const float* __restrict__ bias,
        OT* __restrict__ out, int C, int O, int H, int W)
{
    __shared__ __align__(16) float smp[CC * 9 * T];
    __shared__ float tpy[9 * T], tpx[9 * T], tm[9 * T];
    const int b = blockIdx.y;
    const int p0 = blockIdx.x * T;
    const int tid = threadIdx.x;
    const int HW = H * W;
    const float* omb = om + (size_t)b * 27 * HW;
    for (int i = tid; i < 9 * T; i += NT) {
        const int k = i / T, t = i - k * T;
        const int p = p0 + t;
        const int y = p / W, x = p - y * W;
        const float dy = omb[(2 * k) * HW + p];
        const float dx = omb[(2 * k + 1) * HW + p];
        const float mk = 1.f / (1.f + expf(-omb[(18 + k) * HW + p]));
        float py = (float)(y + k / 3 - 1) + dy;
        float pxx = (float)(x + k % 3 - 1) + dx;
        py  = fminf(fmaxf(py, -2.f), (float)H + 1.f);
        pxx = fminf(fmaxf(pxx, -2.f), (float)W + 1.f);
        tpy[i] = py; tpx[i] = pxx; tm[i] = mk;
    }

    float acc[T];
#pragma unroll
    for (int t = 0; t < T; ++t) acc[t] = 0.f;
    const int o = tid;                       // NT == O
    const float* xb = skip + (size_t)b * C * HW;

    for (int c0 = 0; c0 < C; c0 += CC) {
        __syncthreads();
        for (int i = tid; i < CC * 9 * T; i += NT) {
            const int t = i % T;
            const int kk = (i / T) % 9;
            const int ci = i / (9 * T);
            const int ti = kk * T + t;
            const float py = tpy[ti], pxx = tpx[ti], mk = tm[ti];
            const float y0f = floorf(py), x0f = floorf(pxx);
            const int y0 = (int)y0f, x0 = (int)x0f;
            const float wy1 = py - y0f, wx1 = pxx - x0f;
            const float wy0 = 1.f - wy1, wx0 = 1.f - wx1;
            const float* pl = xb + (size_t)(c0 + ci) * HW;
            float v = 0.f;
            if (y0 >= 0 && y0 < H) {
                const float* r = pl + y0 * W;
                if (x0 >= 0 && x0 < W)         v += wy0 * wx0 * r[x0];
                if (x0 + 1 >= 0 && x0 + 1 < W) v += wy0 * wx1 * r[x0 + 1];
            }
            if (y0 + 1 >= 0 && y0 + 1 < H) {
                const float* r = pl + (y0 + 1) * W;
                if (x0 >= 0 && x0 < W)         v += wy1 * wx0 * r[x0];
                if (x0 + 1 >= 0 && x0 + 1 < W) v += wy1 * wx1 * r[x0 + 1];
            }
            smp[i] = v * mk;
        }
        __syncthreads();
        for (int ci = 0; ci < CC; ++ci) {
#pragma unroll
            for (int k = 0; k < 9; ++k) {
                const float wv = wT[((size_t)(c0 + ci) * 9 + k) * O + o];
                const float4* sp = (const float4*)(smp + (ci * 9 + k) * T);
#pragma unroll
                for (int q = 0; q < T / 4; ++q) {
                    const float4 s = sp[q];
                    acc[q * 4 + 0] += wv * s.x;
                    acc[q * 4 + 1] += wv * s.y;
                    acc[q * 4 + 2] += wv * s.z;
                    acc[q * 4 + 3] += wv * s.w;
                }
            }
        }
    }
    const float bv = bias[o];
    OT* op = out + (size_t)(b * O + o) * HW + p0;
#pragma unroll
    for (int t = 0; t < T; ++t) ST(op + t, acc[t] + bv);
}

// ---------------- offset_sum (multi-block, atomic accumulate) ----------------
__global__ void zero1_kernel(float* __restrict__ out) { if (threadIdx.x == 0) out[0] = 0.f; }

__global__ __launch_bounds__(256) void offsum_part(const float* __restrict__ om1, int HW1,
                                                   const float* __restrict__ om2, int HW2,
                                                   float* __restrict__ out)
{
    __shared__ double sh[256];
    const int n1 = 8 * 18 * HW1, n2 = 8 * 18 * HW2;
    double s = 0.0;
    for (int i = blockIdx.x * 256 + threadIdx.x; i < n1; i += gridDim.x * 256) {
        const int b = i / (18 * HW1); const int r = i - b * 18 * HW1;
        const int c = r / HW1; const int p = r - c * HW1;
        s += 0.5 / n1 * fabs((double)om1[(size_t)(b * 27 + c) * HW1 + p]);
    }
    for (int i = blockIdx.x * 256 + threadIdx.x; i < n2; i += gridDim.x * 256) {
        const int b = i / (18 * HW2); const int r = i - b * 18 * HW2;
        const int c = r / HW2; const int p = r - c * HW2;
        s += 0.5 / n2 * fabs((double)om2[(size_t)(b * 27 + c) * HW2 + p]);
    }
    sh[threadIdx.x] = s;
    __syncthreads();
    for (int st = 128; st > 0; st >>= 1) {
        if (threadIdx.x < st) sh[threadIdx.x] += sh[threadIdx.x + st];
        __syncthreads();
    }
    if (threadIdx.x == 0) atomicAdd(out, (float)sh[0]);
}

// ---------------- launch ----------------
extern "C" void kernel_launch(void* const* d_in, const int* in_sizes, int n_in,
                              void* d_out, int out_size, void* d_ws, size_t ws_size,
                              hipStream_t stream)
{
    if (n_in < 27) return;
    if (out_size < 393217) return;
    if (in_sizes[0] != 8 * 256 * 32 * 32) return;
    if (in_sizes[1] != 8 * 128 * 64 * 64) return;
    if (in_sizes[2] != 8 * 256 * 32 * 32) return;
    if (in_sizes[25] != 128 * 128 * 9) return;
    if (in_sizes[26] != 128) return;

    const float* x        = (const float*)d_in[0];
    const float* skip1    = (const float*)d_in[1];
    const float* skip2    = (const float*)d_in[2];
    const float* rbw[2][2] = {{(const float*)d_in[3], (const float*)d_in[5]},
                              {(const float*)d_in[7], (const float*)d_in[9]}};
    const float* rbb[2][2] = {{(const float*)d_in[4], (const float*)d_in[6]},
                              {(const float*)d_in[8], (const float*)d_in[10]}};
    const float* conv1_w = (const float*)d_in[11]; const float* conv1_b = (const float*)d_in[12];
    const float* conv3_w = (const float*)d_in[13]; const float* conv3_b = (const float*)d_in[14];
    const float* conv5_w = (const float*)d_in[15]; const float* conv5_b = (const float*)d_in[16];
    const float* conv6_w = (const float*)d_in[17]; const float* conv6_b = (const float*)d_in[18];
    const float* dcn2_off_w = (const float*)d_in[19]; const float* dcn2_off_b = (const float*)d_in[20];
    const float* dcn2_w = (const float*)d_in[21]; const float* dcn2_b = (const float*)d_in[22];
    const float* dcn1_off_w = (const float*)d_in[23]; const float* dcn1_off_b = (const float*)d_in[24];
    const float* dcn1_w = (const float*)d_in[25]; const float* dcn1_b = (const float*)d_in[26];

    float* outp = (float*)d_out;

    const size_t NEED_F32 = 9494528ull;      // unchanged (fits, verified R8)
    if (ws_size < NEED_F32 * 4ull) return;

    float* ws = (float*)d_ws;
    const size_t NA = 2097152ull;            // 8*256*32*32
    float* A   = ws;                          // x / rb accum / pre2 ; later Ib
    float* Bb  = ws + NA;                     // h / D ; later wT1 ; later Jb(lower)
    float* Tmp = ws + 2 * NA;                 // rb conv2 out ; later wT2 ; later Jb(upper)
    float* om2 = ws + 3 * NA;                 // [221184]
    float* om1 = om2 + 221184;                // [884736]
    bf16*  Fb  = (bf16*)(om1 + 884736);       // c3 bf16 (2M f32-eq)
    bf16*  Ib  = (bf16*)A;                    // pre1 bf16 (A dead by then)
    bf16*  Jb  = (bf16*)Bb;                   // c5 bf16 (Bb+Tmp dead by then)
    float* wT2 = Tmp;                         // 589824 f32 (Tmp dead at dcn2 time)
    float* wT1 = Bb;                          // 147456 f32 (Bb dead at dcn1 time)

    copy_kernel<<<8192, 256, 0, stream>>>(x, A, (int)NA);

    // ResBlocks: A = A + IN(conv(relu(IN(conv(A)))))
    for (int r = 0; r < 2; ++r) {
        conv_reg<float, float, 3, true, false, 0, 256, 16><<<dim3(4, 8, 16), 256, 0, stream>>>(
            A, (const float*)nullptr, 256, 256, rbw[r][0], rbb[r][0], Bb, 256, 32, 32);
        inorm_kernel<float><<<2048, 256, 0, stream>>>(Bb, nullptr, 1024, 0);
        conv_reg<float, float, 3, true, false, 0, 256, 16><<<dim3(4, 8, 16), 256, 0, stream>>>(
            Bb, (const float*)nullptr, 256, 256, rbw[r][1], rbb[r][1], Tmp, 256, 32, 32);
        inorm_kernel<float><<<2048, 256, 0, stream>>>(Tmp, A, 1024, 1);
    }

    // conv1 (5x5, 256->256) + IN/ReLU
    conv_reg<float, float, 5, true, false, 0, 256, 16><<<dim3(4, 8, 16), 256, 0, stream>>>(
        A, (const float*)nullptr, 256, 256, conv1_w, conv1_b, Bb, 256, 32, 32);
    inorm_kernel<float><<<2048, 256, 0, stream>>>(Bb, nullptr, 1024, 0);

    // dcn2: off-conv (zero-pad, O=27) -> om2 ; transpose w ; mdcn -> A (pre2 f32)
    conv_reg<float, float, 3, false, false, 0, 64, 7><<<dim3(16, 8, 1), 256, 0, stream>>>(
        Bb, skip2, 256, 512, dcn2_off_w, dcn2_off_b, om2, 27, 32, 32);
    wtrans_kernel<<<2304, 256, 0, stream>>>(dcn2_w, wT2, 256, 256);
    mdcn_lds<256, 8, 32, float><<<dim3(128, 8), 256, 0, stream>>>(
        skip2, om2, wT2, dcn2_b, A, 256, 256, 32, 32);

    // conv3: 5x5 over 2x-up concat(A=pre2, Bb=D), 512->128 @64x64 -> Fb + IN/ReLU
    conv_reg<float, float, 5, true, true, 2, 256, 16><<<dim3(16, 8, 8), 256, 0, stream>>>(
        A, Bb, 256, 512, conv3_w, conv3_b, Fb, 128, 64, 64);
    inorm_kernel<bf16><<<1024, 256, 0, stream>>>(Fb, nullptr, 4096, 0);

    // dcn1: off-conv -> om1 ; transpose w (into Bb, now dead) ; mdcn -> Ib (bf16)
    conv_reg<bf16, float, 3, false, false, 0, 64, 7><<<dim3(64, 8, 1), 256, 0, stream>>>(
        Fb, skip1, 128, 256, dcn1_off_w, dcn1_off_b, om1, 27, 64, 64);
    wtrans_kernel<<<576, 256, 0, stream>>>(dcn1_w, wT1, 128, 128);
    mdcn_lds<128, 16, 32, bf16><<<dim3(256, 8), 128, 0, stream>>>(
        skip1, om1, wT1, dcn1_b, Ib, 128, 128, 64, 64);

    // conv5: 5x5 over 2x-up concat(Ib, Fb), 256->64 @128x128 -> Jb + IN/ReLU
    conv_reg<bf16, bf16, 5, true, true, 2, 256, 16><<<dim3(64, 8, 4), 256, 0, stream>>>(
        Ib, Fb, 128, 256, conv5_w, conv5_b, Jb, 64, 128, 128);
    inorm_kernel<bf16><<<512, 256, 0, stream>>>(Jb, nullptr, 16384, 0);

    // conv6: 7x7, 64->3, tanh -> d_out (f32)
    conv_reg<bf16, float, 7, true, false, 1, 256, 3><<<dim3(64, 8, 1), 256, 0, stream>>>(
        Jb, (const float*)nullptr, 64, 64, conv6_w, conv6_b, (void*)outp, 3, 128, 128);

    // offset_sum -> d_out[393216]
    zero1_kernel<<<1, 64, 0, stream>>>(outp + 393216);
    offsum_part<<<128, 256, 0, stream>>>(om1, 4096, om2, 1024, outp + 393216);
}

// Round 10
// 7663.003 us; speedup vs baseline: 7.7788x; 2.0435x over previous
//
#include <hip/hip_runtime.h>
#include <hip/hip_bf16.h>
#include <math.h>

typedef __hip_bfloat16 bf16;
typedef unsigned short u16;
typedef __attribute__((ext_vector_type(8))) short short8;   // 8 bf16 (4 VGPRs)
typedef __attribute__((ext_vector_type(4))) float f32x4;

__device__ __forceinline__ float LD(const float* p) { return *p; }
__device__ __forceinline__ float LD(const bf16* p)  { return __bfloat162float(*p); }
__device__ __forceinline__ void  ST(float* p, float v) { *p = v; }
__device__ __forceinline__ void  ST(bf16* p, float v)  { *p = __float2bfloat16(v); }
__device__ __forceinline__ u16   f2b(float v) { bf16 h = __float2bfloat16(v); return *reinterpret_cast<u16*>(&h); }

// ---------------- f32 copy ----------------
__global__ __launch_bounds__(256) void copy_kernel(const float* __restrict__ in,
                                                   float* __restrict__ out, int n) {
    int i = blockIdx.x * blockDim.x + threadIdx.x;
    if (i < n) out[i] = in[i];
}

// ---------------- register-blocked conv (f32, scalar weights) ----------------
template<typename T1, typename T2, int K, bool REFLECT, bool UP, int EPI, int PXT, int NO>
__global__ __launch_bounds__(256) void conv_reg(
        const T1* __restrict__ src1, const T2* __restrict__ src2,
        int C1, int C,
        const float* __restrict__ w, const float* __restrict__ bias,
        void* __restrict__ outv, int O, int H, int W)
{
    constexpr int KK = K * K;
    const int tid = threadIdx.x;
    const int px  = tid % PXT;
    const int o_base = __builtin_amdgcn_readfirstlane(
        blockIdx.z * (256 / PXT) * NO + (tid / PXT) * NO);
    const int b = blockIdx.y;
    const int p = blockIdx.x * PXT + px;
    const int HW = H * W;
    const int y = p / W, x = p - y * W;
    const int Hs = UP ? (H >> 1) : H;
    const int Ws = UP ? (W >> 1) : W;
    const int HsWs = Hs * Ws;
    const int PAD = K / 2;

    int off[KK];
    float msk[KK];
#pragma unroll
    for (int ty = 0; ty < K; ++ty) {
#pragma unroll
        for (int tx = 0; tx < K; ++tx) {
            int yy = y + ty - PAD, xx = x + tx - PAD;
            bool v = true;
            if (REFLECT) {
                yy = yy < 0 ? -yy : yy; yy = yy >= H ? 2 * H - 2 - yy : yy;
                xx = xx < 0 ? -xx : xx; xx = xx >= W ? 2 * W - 2 - xx : xx;
            } else {
                v = (yy >= 0 && yy < H && xx >= 0 && xx < W);
                yy = yy < 0 ? 0 : (yy >= H ? H - 1 : yy);
                xx = xx < 0 ? 0 : (xx >= W ? W - 1 : xx);
            }
            const int sy = UP ? (yy >> 1) : yy;
            const int sx = UP ? (xx >> 1) : xx;
            off[ty * K + tx] = sy * Ws + sx;
            msk[ty * K + tx] = v ? 1.f : 0.f;
        }
    }

    float acc[NO];
#pragma unroll
    for (int no = 0; no < NO; ++no) acc[no] = 0.f;

    const int C2 = C - C1;
    {
        const T1* pb = src1 + (size_t)b * C1 * HsWs;
        for (int c = 0; c < C1; ++c) {
            const T1* pl = pb + (size_t)c * HsWs;
            float tap[KK];
#pragma unroll
            for (int t = 0; t < KK; ++t) {
                const float v = LD(pl + off[t]);
                tap[t] = REFLECT ? v : v * msk[t];
            }
            const float* wc = w + ((size_t)o_base * C + c) * KK;
#pragma unroll
            for (int no = 0; no < NO; ++no) {
                const int oo = (o_base + no < O) ? no : 0;
                const float* wn = wc + (size_t)oo * C * KK;
#pragma unroll
                for (int t = 0; t < KK; ++t) acc[no] += wn[t] * tap[t];
            }
        }
    }
    if (C2 > 0) {
        const T2* pb = src2 + (size_t)b * C2 * HsWs;
        for (int c = 0; c < C2; ++c) {
            const T2* pl = pb + (size_t)c * HsWs;
            float tap[KK];
#pragma unroll
            for (int t = 0; t < KK; ++t) {
                const float v = LD(pl + off[t]);
                tap[t] = REFLECT ? v : v * msk[t];
            }
            const float* wc = w + ((size_t)o_base * C + C1 + c) * KK;
#pragma unroll
            for (int no = 0; no < NO; ++no) {
                const int oo = (o_base + no < O) ? no : 0;
                const float* wn = wc + (size_t)oo * C * KK;
#pragma unroll
                for (int t = 0; t < KK; ++t) acc[no] += wn[t] * tap[t];
            }
        }
    }

#pragma unroll
    for (int no = 0; no < NO; ++no) {
        const int o = o_base + no;
        if (o < O) {
            const float v = acc[no] + bias[o];
            const size_t oidx = (size_t)(b * O + o) * HW + p;
            if (EPI == 0)      ((float*)outv)[oidx] = v;
            else if (EPI == 1) ((float*)outv)[oidx] = tanhf(v);
            else               ((bf16*)outv)[oidx] = __float2bfloat16(v);
        }
    }
}

// ---------------- weight split+transpose for MFMA: w[o][c][t] f32 -> hi/lo [t][o][c] bf16 ----
__global__ __launch_bounds__(256) void wsplit_kernel(const float* __restrict__ w,
                                                     u16* __restrict__ hi, u16* __restrict__ lo,
                                                     int O, int C, int KK)
{
    const int i = blockIdx.x * 256 + threadIdx.x;
    const int n = O * C * KK;
    if (i >= n) return;
    const int o = i / (C * KK);
    const int r = i - o * C * KK;
    const int c = r / KK;
    const int t = r - c * KK;
    const float v = w[i];
    const bf16 h = __float2bfloat16(v);
    const float hv = __bfloat162float(h);
    const bf16 l = __float2bfloat16(v - hv);
    const size_t dst = ((size_t)t * O + o) * C + c;
    hi[dst] = *(const u16*)&h;
    lo[dst] = *(const u16*)&l;
}

// ---------------- MFMA implicit-GEMM conv (REFLECT+UP, K=5) ----------------
// block: 256 thr = 4 waves; 64 pixels (M) x 64 out-channels (N, obase=z*64).
// K-loop: taps t(25) x C-chunks(32). W hi/lo split -> 2 MFMAs (weights ~f32 precise).
template<typename T1, typename T2, int K, int EPI>
__global__ __launch_bounds__(256) void conv_mfma(
        const T1* __restrict__ src1, const T2* __restrict__ src2,
        int C1, int C,
        const u16* __restrict__ wth, const u16* __restrict__ wtl,
        const float* __restrict__ bias,
        void* __restrict__ outv, int O, int H, int W)
{
    constexpr int KK = K * K;
    __shared__ __align__(16) u16 As[64 * 40];
    __shared__ __align__(16) u16 Bh[64 * 40];
    __shared__ __align__(16) u16 Bl[64 * 40];

    const int tid  = threadIdx.x;
    const int wv   = tid >> 6;          // wave 0..3
    const int lane = tid & 63;
    const int ln15 = lane & 15;
    const int kb   = (lane >> 4) << 3;  // 0,8,16,24
    const int b    = blockIdx.y;
    const int p0   = blockIdx.x * 64;
    const int obase = blockIdx.z * 64;
    const int HW = H * W;
    const int Hs = H >> 1, Ws = W >> 1;
    const int HsWs = Hs * Ws;
    const int PAD = K / 2;
    const int C2 = C - C1;

    // per-thread staging pixel
    const int m_stage = tid & 63;
    const int ci0 = tid >> 6;          // 0..3
    const int o_l = tid & 63;          // B staging o
    const int part = tid >> 6;         // B staging col-part

    const int p = p0 + m_stage;
    const int y = p / W, x = p - y * W;
    int off[KK];
#pragma unroll
    for (int ty = 0; ty < K; ++ty) {
#pragma unroll
        for (int tx = 0; tx < K; ++tx) {
            int yy = y + ty - PAD, xx = x + tx - PAD;
            yy = yy < 0 ? -yy : yy; yy = yy >= H ? 2 * H - 2 - yy : yy;
            xx = xx < 0 ? -xx : xx; xx = xx >= W ? 2 * W - 2 - xx : xx;
            off[ty * K + tx] = (yy >> 1) * Ws + (xx >> 1);
        }
    }

    f32x4 acc[4];
#pragma unroll
    for (int nt = 0; nt < 4; ++nt) acc[nt] = (f32x4)0.f;

    const int nch = C >> 5;
    for (int t = 0; t < KK; ++t) {
        const int offt = off[t];
        for (int cc = 0; cc < nch; ++cc) {
            const int c0 = cc << 5;
            __syncthreads();
            // stage A: As[m][ci] = src[c0+ci][off_t[m]]
#pragma unroll
            for (int q = 0; q < 8; ++q) {
                const int ci = ci0 + (q << 2);
                const int c = c0 + ci;
                float v;
                if (c < C1) v = LD(src1 + ((size_t)(b * C1 + c)) * HsWs + offt);
                else        v = LD(src2 + ((size_t)(b * C2 + (c - C1))) * HsWs + offt);
                As[m_stage * 40 + ci] = f2b(v);
            }
            // stage B: Bs[o][ci] from wt[t][obase+o][c0..]
            {
                const size_t wb = ((size_t)t * O + obase + o_l) * C + c0 + (part << 3);
                *(short8*)&Bh[o_l * 40 + (part << 3)] = *(const short8*)(wth + wb);
                *(short8*)&Bl[o_l * 40 + (part << 3)] = *(const short8*)(wtl + wb);
            }
            __syncthreads();
            const short8 a = *(const short8*)&As[(wv * 16 + ln15) * 40 + kb];
#pragma unroll
            for (int nt = 0; nt < 4; ++nt) {
                const short8 bh = *(const short8*)&Bh[(nt * 16 + ln15) * 40 + kb];
                acc[nt] = __builtin_amdgcn_mfma_f32_16x16x32_bf16(a, bh, acc[nt], 0, 0, 0);
                const short8 bl = *(const short8*)&Bl[(nt * 16 + ln15) * 40 + kb];
                acc[nt] = __builtin_amdgcn_mfma_f32_16x16x32_bf16(a, bl, acc[nt], 0, 0, 0);
            }
        }
    }

    // epilogue: D col=lane&15 -> o, row=(lane>>4)*4+r -> pixel
#pragma unroll
    for (int nt = 0; nt < 4; ++nt) {
        const int o = obase + nt * 16 + ln15;
        const float bv = bias[o];
#pragma unroll
        for (int r = 0; r < 4; ++r) {
            const int pp = p0 + wv * 16 + ((lane >> 4) << 2) + r;
            const float v = acc[nt][r] + bv;
            const size_t oidx = ((size_t)(b * O + o)) * HW + pp;
            if (EPI == 0) ((float*)outv)[oidx] = v;
            else          ((bf16*)outv)[oidx] = __float2bfloat16(v);
        }
    }
}

// ---------------- instance norm ----------------
template<typename T>
__global__ __launch_bounds__(256) void inorm_kernel(T* __restrict__ buf,
                                                    float* __restrict__ resid,
                                                    int HW, int mode)
{
    __shared__ double sh0[256], sh1[256];
    const int pl = blockIdx.x;
    T* p = buf + (size_t)pl * HW;
    double s = 0.0, ss = 0.0;
    for (int i = threadIdx.x; i < HW; i += 256) {
        float v = LD(p + i);
        s += (double)v; ss += (double)v * (double)v;
    }
    sh0[threadIdx.x] = s; sh1[threadIdx.x] = ss;
    __syncthreads();
    for (int st = 128; st > 0; st >>= 1) {
        if (threadIdx.x < st) {
            sh0[threadIdx.x] += sh0[threadIdx.x + st];
            sh1[threadIdx.x] += sh1[threadIdx.x + st];
        }
        __syncthreads();
    }
    const double mean = sh0[0] / HW;
    const float m = (float)mean;
    const float var = (float)(sh1[0] / HW - mean * mean);
    const float inv = rsqrtf(var + 1e-5f);
    if (mode == 0) {
        for (int i = threadIdx.x; i < HW; i += 256) {
            float v = (LD(p + i) - m) * inv;
            ST(p + i, v > 0.f ? v : 0.f);
        }
    } else {
        float* r = resid + (size_t)pl * HW;
        for (int i = threadIdx.x; i < HW; i += 256)
            r[i] = r[i] + (LD(p + i) - m) * inv;
    }
}

// ---------------- weight transpose for mdcn: w[o][c][k] -> wT[c*9+k][o] ----------------
__global__ __launch_bounds__(256) void wtrans_kernel(const float* __restrict__ w,
                                                     float* __restrict__ wT, int C, int O)
{
    const int i = blockIdx.x * 256 + threadIdx.x;
    const int n = O * C * 9;
    if (i >= n) return;
    const int o = i / (C * 9);
    const int r = i - o * C * 9;
    wT[(size_t)r * O + o] = w[i];
}

// ---------------- modulated deformable conv, cooperative LDS ----------------
template<int NT, int T, int CC, typename OT>
__global__ __launch_bounds__(256) void mdcn_lds(
        const float* __restrict__ skip, const float* __restrict__ om,
        const float* __restrict__ wT, const float* __restrict__ bias,
        OT* __restrict__ out, int C, int O, int H, int W)
{
    __shared__ __align__(16) float smp[CC * 9 * T];
    __shared__ float tpy[9 * T], tpx[9 * T], tm[9 * T];
    const int b = blockIdx.y;
    const int p0 = blockIdx.x * T;
    const int tid = threadIdx.x;
    const int HW = H * W;
    const float* omb = om + (size_t)b * 27 * HW;
    for (int i = tid; i < 9 * T; i += NT) {
        const int k = i / T, t = i - k * T;
        const int p = p0 + t;
        const int y = p / W, x = p - y * W;
        const float dy = omb[(2 * k) * HW + p];
        const float dx = omb[(2 * k + 1) * HW + p];
        const float mk = 1.f / (1.f + expf(-omb[(18 + k) * HW + p]));
        float py = (float)(y + k / 3 - 1) + dy;
        float pxx = (float)(x + k % 3 - 1) + dx;
        py  = fminf(fmaxf(py, -2.f), (float)H + 1.f);
        pxx = fminf(fmaxf(pxx, -2.f), (float)W + 1.f);
        tpy[i] = py; tpx[i] = pxx; tm[i] = mk;
    }

    float acc[T];
#pragma unroll
    for (int t = 0; t < T; ++t) acc[t] = 0.f;
    const int o = tid;
    const float* xb = skip + (size_t)b * C * HW;

    for (int c0 = 0; c0 < C; c0 += CC) {
        __syncthreads();
        for (int i = tid; i < CC * 9 * T; i += NT) {
            const int t = i % T;
            const int kk = (i / T) % 9;
            const int ci = i / (9 * T);
            const int ti = kk * T + t;
            const float py = tpy[ti], pxx = tpx[ti], mk = tm[ti];
            const float y0f = floorf(py), x0f = floorf(pxx);
            const int y0 = (int)y0f, x0 = (int)x0f;
            const float wy1 = py - y0f, wx1 = pxx - x0f;
            const float wy0 = 1.f - wy1, wx0 = 1.f - wx1;
            const float* pl = xb + (size_t)(c0 + ci) * HW;
            float v = 0.f;
            if (y0 >= 0 && y0 < H) {
                const float* r = pl + y0 * W;
                if (x0 >= 0 && x0 < W)         v += wy0 * wx0 * r[x0];
                if (x0 + 1 >= 0 && x0 + 1 < W) v += wy0 * wx1 * r[x0 + 1];
            }
            if (y0 + 1 >= 0 && y0 + 1 < H) {
                const float* r = pl + (y0 + 1) * W;
                if (x0 >= 0 && x0 < W)         v += wy1 * wx0 * r[x0];
                if (x0 + 1 >= 0 && x0 + 1 < W) v += wy1 * wx1 * r[x0 + 1];
            }
            smp[i] = v * mk;
        }
        __syncthreads();
        for (int ci = 0; ci < CC; ++ci) {
#pragma unroll
            for (int k = 0; k < 9; ++k) {
                const float wvv = wT[((size_t)(c0 + ci) * 9 + k) * O + o];
                const float4* sp = (const float4*)(smp + (ci * 9 + k) * T);
#pragma unroll
                for (int q = 0; q < T / 4; ++q) {
                    const float4 s = sp[q];
                    acc[q * 4 + 0] += wvv * s.x;
                    acc[q * 4 + 1] += wvv * s.y;
                    acc[q * 4 + 2] += wvv * s.z;
                    acc[q * 4 + 3] += wvv * s.w;
                }
            }
        }
    }
    const float bv = bias[o];
    OT* op = out + (size_t)(b * O + o) * HW + p0;
#pragma unroll
    for (int t = 0; t < T; ++t) ST(op + t, acc[t] + bv);
}

// ---------------- offset_sum ----------------
__global__ void zero1_kernel(float* __restrict__ out) { if (threadIdx.x == 0) out[0] = 0.f; }

__global__ __launch_bounds__(256) void offsum_one(const float* __restrict__ om, int HW,
                                                  float* __restrict__ out)
{
    __shared__ double sh[256];
    const int n = 8 * 18 * HW;
    double s = 0.0;
    for (int i = blockIdx.x * 256 + threadIdx.x; i < n; i += gridDim.x * 256) {
        const int b = i / (18 * HW); const int r = i - b * 18 * HW;
        const int c = r / HW; const int p = r - c * HW;
        s += fabs((double)om[(size_t)(b * 27 + c) * HW + p]);
    }
    sh[threadIdx.x] = s;
    __syncthreads();
    for (int st = 128; st > 0; st >>= 1) {
        if (threadIdx.x < st) sh[threadIdx.x] += sh[threadIdx.x + st];
        __syncthreads();
    }
    if (threadIdx.x == 0) atomicAdd(out, (float)(0.5 * sh[0] / n));
}

// ---------------- launch ----------------
extern "C" void kernel_launch(void* const* d_in, const int* in_sizes, int n_in,
                              void* d_out, int out_size, void* d_ws, size_t ws_size,
                              hipStream_t stream)
{
    if (n_in < 27) return;
    if (out_size < 393217) return;
    if (in_sizes[0] != 8 * 256 * 32 * 32) return;
    if (in_sizes[1] != 8 * 128 * 64 * 64) return;
    if (in_sizes[2] != 8 * 256 * 32 * 32) return;
    if (in_sizes[25] != 128 * 128 * 9) return;
    if (in_sizes[26] != 128) return;

    const float* x        = (const float*)d_in[0];
    const float* skip1    = (const float*)d_in[1];
    const float* skip2    = (const float*)d_in[2];
    const float* rbw[2][2] = {{(const float*)d_in[3], (const float*)d_in[5]},
                              {(const float*)d_in[7], (const float*)d_in[9]}};
    const float* rbb[2][2] = {{(const float*)d_in[4], (const float*)d_in[6]},
                              {(const float*)d_in[8], (const float*)d_in[10]}};
    const float* conv1_w = (const float*)d_in[11]; const float* conv1_b = (const float*)d_in[12];
    const float* conv3_w = (const float*)d_in[13]; const float* conv3_b = (const float*)d_in[14];
    const float* conv5_w = (const float*)d_in[15]; const float* conv5_b = (const float*)d_in[16];
    const float* conv6_w = (const float*)d_in[17]; const float* conv6_b = (const float*)d_in[18];
    const float* dcn2_off_w = (const float*)d_in[19]; const float* dcn2_off_b = (const float*)d_in[20];
    const float* dcn2_w = (const float*)d_in[21]; const float* dcn2_b = (const float*)d_in[22];
    const float* dcn1_off_w = (const float*)d_in[23]; const float* dcn1_off_b = (const float*)d_in[24];
    const float* dcn1_w = (const float*)d_in[25]; const float* dcn1_b = (const float*)d_in[26];

    float* outp = (float*)d_out;

    const size_t NEED_F32 = 9494528ull;      // unchanged, proven in R8/R9
    if (ws_size < NEED_F32 * 4ull) return;

    float* ws = (float*)d_ws;
    const size_t NA = 2097152ull;            // 8*256*32*32
    float* A   = ws;                          // x / rb accum / pre2 ; later Ib
    float* Bb  = ws + NA;                     // h / D ; later wT1 ; later Jb(lo half)
    float* Tmp = ws + 2 * NA;                 // rb tmp ; wT2 ; conv3 wt ; Jb(hi half)
    float* om2 = ws + 3 * NA;                 // [221184]
    float* om1 = om2 + 221184;                // [884736] ; later conv5 wt
    bf16*  Fb  = (bf16*)(om1 + 884736);       // c3 bf16
    bf16*  Ib  = (bf16*)A;                    // pre1 bf16
    bf16*  Jb  = (bf16*)Bb;                   // c5 bf16 (Bb+Tmp)
    float* wT2 = Tmp;                         // mdcn2 transposed weights (2.25MB)
    float* wT1 = Bb;                          // mdcn1 transposed weights
    u16*   wt3h = (u16*)Tmp;                  // conv3 MFMA weights hi (overwrites wT2 after mdcn2)
    u16*   wt3l = wt3h + 25 * 128 * 512;      // +1.6M u16 (total 6.55MB < 8MB Tmp)
    u16*   wt5h = (u16*)om1;                  // conv5 MFMA weights (after offsum consumed om1)
    u16*   wt5l = wt5h + 25 * 64 * 256;       // total 1.6MB < 3.4MB om1 region

    copy_kernel<<<8192, 256, 0, stream>>>(x, A, (int)NA);

    // ResBlocks (f32 conv_reg -- precision-critical early stages)
    for (int r = 0; r < 2; ++r) {
        conv_reg<float, float, 3, true, false, 0, 256, 16><<<dim3(4, 8, 16), 256, 0, stream>>>(
            A, (const float*)nullptr, 256, 256, rbw[r][0], rbb[r][0], Bb, 256, 32, 32);
        inorm_kernel<float><<<2048, 256, 0, stream>>>(Bb, nullptr, 1024, 0);
        conv_reg<float, float, 3, true, false, 0, 256, 16><<<dim3(4, 8, 16), 256, 0, stream>>>(
            Bb, (const float*)nullptr, 256, 256, rbw[r][1], rbb[r][1], Tmp, 256, 32, 32);
        inorm_kernel<float><<<2048, 256, 0, stream>>>(Tmp, A, 1024, 1);
    }

    // conv1 (5x5, 256->256) + IN/ReLU
    conv_reg<float, float, 5, true, false, 0, 256, 16><<<dim3(4, 8, 16), 256, 0, stream>>>(
        A, (const float*)nullptr, 256, 256, conv1_w, conv1_b, Bb, 256, 32, 32);
    inorm_kernel<float><<<2048, 256, 0, stream>>>(Bb, nullptr, 1024, 0);

    // dcn2
    conv_reg<float, float, 3, false, false, 0, 64, 7><<<dim3(16, 8, 1), 256, 0, stream>>>(
        Bb, skip2, 256, 512, dcn2_off_w, dcn2_off_b, om2, 27, 32, 32);
    wtrans_kernel<<<2304, 256, 0, stream>>>(dcn2_w, wT2, 256, 256);
    mdcn_lds<256, 8, 32, float><<<dim3(128, 8), 256, 0, stream>>>(
        skip2, om2, wT2, dcn2_b, A, 256, 256, 32, 32);

    // conv3: MFMA implicit GEMM (bf16 A, hi/lo-split W), 512->128 @64x64 -> Fb + IN/ReLU
    wsplit_kernel<<<6400, 256, 0, stream>>>(conv3_w, wt3h, wt3l, 128, 512, 25);
    conv_mfma<float, float, 5, 2><<<dim3(64, 8, 2), 256, 0, stream>>>(
        A, Bb, 256, 512, wt3h, wt3l, conv3_b, Fb, 128, 64, 64);
    inorm_kernel<bf16><<<1024, 256, 0, stream>>>(Fb, nullptr, 4096, 0);

    // dcn1
    conv_reg<bf16, float, 3, false, false, 0, 64, 7><<<dim3(64, 8, 1), 256, 0, stream>>>(
        Fb, skip1, 128, 256, dcn1_off_w, dcn1_off_b, om1, 27, 64, 64);
    wtrans_kernel<<<576, 256, 0, stream>>>(dcn1_w, wT1, 128, 128);
    mdcn_lds<128, 16, 32, bf16><<<dim3(256, 8), 128, 0, stream>>>(
        skip1, om1, wT1, dcn1_b, Ib, 128, 128, 64, 64);

    // offset_sum now (frees om1 region for conv5 weights)
    zero1_kernel<<<1, 64, 0, stream>>>(outp + 393216);
    offsum_one<<<64, 256, 0, stream>>>(om1, 4096, outp + 393216);
    offsum_one<<<64, 256, 0, stream>>>(om2, 1024, outp + 393216);

    // conv5: MFMA implicit GEMM, 256->64 @128x128 -> Jb + IN/ReLU
    wsplit_kernel<<<1600, 256, 0, stream>>>(conv5_w, wt5h, wt5l, 64, 256, 25);
    conv_mfma<bf16, bf16, 5, 2><<<dim3(256, 8, 1), 256, 0, stream>>>(
        Ib, Fb, 128, 256, wt5h, wt5l, conv5_b, Jb, 64, 128, 128);
    inorm_kernel<bf16><<<512, 256, 0, stream>>>(Jb, nullptr, 16384, 0);

    // conv6: 7x7, 64->3, tanh -> d_out (f32)
    conv_reg<bf16, float, 7, true, false, 1, 256, 3><<<dim3(64, 8, 1), 256, 0, stream>>>(
        Jb, (const float*)nullptr, 64, 64, conv6_w, conv6_b, (void*)outp, 3, 128, 128);
}

// Round 11
// 5507.499 us; speedup vs baseline: 10.8232x; 1.3914x over previous
//
#include <hip/hip_runtime.h>
#include <hip/hip_bf16.h>
#include <math.h>

typedef __hip_bfloat16 bf16;
typedef unsigned short u16;
typedef __attribute__((ext_vector_type(8))) short short8;   // 8 bf16 (4 VGPRs)
typedef __attribute__((ext_vector_type(4))) float f32x4;

__device__ __forceinline__ float LD(const float* p) { return *p; }
__device__ __forceinline__ float LD(const bf16* p)  { return __bfloat162float(*p); }
__device__ __forceinline__ void  ST(float* p, float v) { *p = v; }
__device__ __forceinline__ void  ST(bf16* p, float v)  { *p = __float2bfloat16(v); }
__device__ __forceinline__ u16   f2b(float v) { bf16 h = __float2bfloat16(v); return *reinterpret_cast<u16*>(&h); }

// ---------------- f32 copy ----------------
__global__ __launch_bounds__(256) void copy_kernel(const float* __restrict__ in,
                                                   float* __restrict__ out, int n) {
    int i = blockIdx.x * blockDim.x + threadIdx.x;
    if (i < n) out[i] = in[i];
}

// ---------------- register-blocked conv (f32, scalar weights) ----------------
template<typename T1, typename T2, int K, bool REFLECT, bool UP, int EPI, int PXT, int NO>
__global__ __launch_bounds__(256) void conv_reg(
        const T1* __restrict__ src1, const T2* __restrict__ src2,
        int C1, int C,
        const float* __restrict__ w, const float* __restrict__ bias,
        void* __restrict__ outv, int O, int H, int W)
{
    constexpr int KK = K * K;
    const int tid = threadIdx.x;
    const int px  = tid % PXT;
    const int o_base = __builtin_amdgcn_readfirstlane(
        blockIdx.z * (256 / PXT) * NO + (tid / PXT) * NO);
    const int b = blockIdx.y;
    const int p = blockIdx.x * PXT + px;
    const int HW = H * W;
    const int y = p / W, x = p - y * W;
    const int Hs = UP ? (H >> 1) : H;
    const int Ws = UP ? (W >> 1) : W;
    const int HsWs = Hs * Ws;
    const int PAD = K / 2;

    int off[KK];
    float msk[KK];
#pragma unroll
    for (int ty = 0; ty < K; ++ty) {
#pragma unroll
        for (int tx = 0; tx < K; ++tx) {
            int yy = y + ty - PAD, xx = x + tx - PAD;
            bool v = true;
            if (REFLECT) {
                yy = yy < 0 ? -yy : yy; yy = yy >= H ? 2 * H - 2 - yy : yy;
                xx = xx < 0 ? -xx : xx; xx = xx >= W ? 2 * W - 2 - xx : xx;
            } else {
                v = (yy >= 0 && yy < H && xx >= 0 && xx < W);
                yy = yy < 0 ? 0 : (yy >= H ? H - 1 : yy);
                xx = xx < 0 ? 0 : (xx >= W ? W - 1 : xx);
            }
            const int sy = UP ? (yy >> 1) : yy;
            const int sx = UP ? (xx >> 1) : xx;
            off[ty * K + tx] = sy * Ws + sx;
            msk[ty * K + tx] = v ? 1.f : 0.f;
        }
    }

    float acc[NO];
#pragma unroll
    for (int no = 0; no < NO; ++no) acc[no] = 0.f;

    const int C2 = C - C1;
    {
        const T1* pb = src1 + (size_t)b * C1 * HsWs;
        for (int c = 0; c < C1; ++c) {
            const T1* pl = pb + (size_t)c * HsWs;
            float tap[KK];
#pragma unroll
            for (int t = 0; t < KK; ++t) {
                const float v = LD(pl + off[t]);
                tap[t] = REFLECT ? v : v * msk[t];
            }
            const float* wc = w + ((size_t)o_base * C + c) * KK;
#pragma unroll
            for (int no = 0; no < NO; ++no) {
                const int oo = (o_base + no < O) ? no : 0;
                const float* wn = wc + (size_t)oo * C * KK;
#pragma unroll
                for (int t = 0; t < KK; ++t) acc[no] += wn[t] * tap[t];
            }
        }
    }
    if (C2 > 0) {
        const T2* pb = src2 + (size_t)b * C2 * HsWs;
        for (int c = 0; c < C2; ++c) {
            const T2* pl = pb + (size_t)c * HsWs;
            float tap[KK];
#pragma unroll
            for (int t = 0; t < KK; ++t) {
                const float v = LD(pl + off[t]);
                tap[t] = REFLECT ? v : v * msk[t];
            }
            const float* wc = w + ((size_t)o_base * C + C1 + c) * KK;
#pragma unroll
            for (int no = 0; no < NO; ++no) {
                const int oo = (o_base + no < O) ? no : 0;
                const float* wn = wc + (size_t)oo * C * KK;
#pragma unroll
                for (int t = 0; t < KK; ++t) acc[no] += wn[t] * tap[t];
            }
        }
    }

#pragma unroll
    for (int no = 0; no < NO; ++no) {
        const int o = o_base + no;
        if (o < O) {
            const float v = acc[no] + bias[o];
            const size_t oidx = (size_t)(b * O + o) * HW + p;
            if (EPI == 0)      ((float*)outv)[oidx] = v;
            else if (EPI == 1) ((float*)outv)[oidx] = tanhf(v);
            else               ((bf16*)outv)[oidx] = __float2bfloat16(v);
        }
    }
}

// ---------------- weight split+transpose for MFMA: w[o][c][t] f32 -> hi/lo [t][o][c] bf16 ----
__global__ __launch_bounds__(256) void wsplit_kernel(const float* __restrict__ w,
                                                     u16* __restrict__ hi, u16* __restrict__ lo,
                                                     int O, int C, int KK)
{
    const int i = blockIdx.x * 256 + threadIdx.x;
    const int n = O * C * KK;
    if (i >= n) return;
    const int o = i / (C * KK);
    const int r = i - o * C * KK;
    const int c = r / KK;
    const int t = r - c * KK;
    const float v = w[i];
    const bf16 h = __float2bfloat16(v);
    const float hv = __bfloat162float(h);
    const bf16 l = __float2bfloat16(v - hv);
    const size_t dst = ((size_t)t * O + o) * C + c;
    hi[dst] = *(const u16*)&h;
    lo[dst] = *(const u16*)&l;
}

// ---------------- MFMA implicit-GEMM conv (generalized) ----------------
// block: 256 thr = 4 waves; M=64 pixels x N=NTN*16 out-channels (obase=z*NTN*16).
// K-loop: taps t(K*K) x C-chunks(32). W hi/lo split -> 2 MFMAs (weights ~f32 precise).
// REFLECT=false -> zero-pad via staged-A masking. EPI: 0=f32, 2=bf16.
template<typename T1, typename T2, int K, bool REFLECT, bool UP, int NTN, int EPI>
__global__ __launch_bounds__(256) void conv_mfma(
        const T1* __restrict__ src1, const T2* __restrict__ src2,
        int C1, int C,
        const u16* __restrict__ wth, const u16* __restrict__ wtl,
        const float* __restrict__ bias,
        void* __restrict__ outv, int O, int H, int W)
{
    constexpr int KK = K * K;
    __shared__ __align__(16) u16 As[64 * 40];
    __shared__ __align__(16) u16 Bh[NTN * 16 * 40];
    __shared__ __align__(16) u16 Bl[NTN * 16 * 40];

    const int tid  = threadIdx.x;
    const int wv   = tid >> 6;          // wave 0..3
    const int lane = tid & 63;
    const int ln15 = lane & 15;
    const int kb   = (lane >> 4) << 3;  // 0,8,16,24
    const int b    = blockIdx.y;
    const int p0   = blockIdx.x * 64;
    const int obase = blockIdx.z * (NTN * 16);
    const int HW = H * W;
    const int Hs = UP ? (H >> 1) : H;
    const int Ws = UP ? (W >> 1) : W;
    const int HsWs = Hs * Ws;
    const int PAD = K / 2;
    const int C2 = C - C1;

    const int m_stage = tid & 63;
    const int ci0 = tid >> 6;          // 0..3

    const int p = p0 + m_stage;
    const int y = p / W, x = p - y * W;
    int off[KK];
    float msk[KK];
#pragma unroll
    for (int ty = 0; ty < K; ++ty) {
#pragma unroll
        for (int tx = 0; tx < K; ++tx) {
            int yy = y + ty - PAD, xx = x + tx - PAD;
            bool vv = true;
            if (REFLECT) {
                yy = yy < 0 ? -yy : yy; yy = yy >= H ? 2 * H - 2 - yy : yy;
                xx = xx < 0 ? -xx : xx; xx = xx >= W ? 2 * W - 2 - xx : xx;
            } else {
                vv = (yy >= 0 && yy < H && xx >= 0 && xx < W);
                yy = yy < 0 ? 0 : (yy >= H ? H - 1 : yy);
                xx = xx < 0 ? 0 : (xx >= W ? W - 1 : xx);
            }
            off[ty * K + tx] = (UP ? (yy >> 1) : yy) * Ws + (UP ? (xx >> 1) : xx);
            msk[ty * K + tx] = vv ? 1.f : 0.f;
        }
    }

    f32x4 acc[NTN];
#pragma unroll
    for (int nt = 0; nt < NTN; ++nt) acc[nt] = (f32x4)0.f;

    const int nch = C >> 5;
    for (int t = 0; t < KK; ++t) {
        const int offt = off[t];
        const float mskt = msk[t];
        for (int cc = 0; cc < nch; ++cc) {
            const int c0 = cc << 5;
            __syncthreads();
            // stage A: As[m][ci] = src[c0+ci][off_t[m]] (zero-pad masked)
#pragma unroll
            for (int q = 0; q < 8; ++q) {
                const int ci = ci0 + (q << 2);
                const int c = c0 + ci;
                float v;
                if (c < C1) v = LD(src1 + ((size_t)(b * C1 + c)) * HsWs + offt);
                else        v = LD(src2 + ((size_t)(b * C2 + (c - C1))) * HsWs + offt);
                if (!REFLECT) v *= mskt;
                As[m_stage * 40 + ci] = f2b(v);
            }
            // stage B: rows = NTN*16 out-chans, 32 chans each (clamped at O-1)
            for (int i = tid; i < NTN * 16 * 4; i += 256) {
                const int row = i >> 2, part = i & 3;
                int o = obase + row; if (o >= O) o = O - 1;
                const size_t wb = ((size_t)t * O + o) * C + c0 + (part << 3);
                *(short8*)&Bh[row * 40 + (part << 3)] = *(const short8*)(wth + wb);
                *(short8*)&Bl[row * 40 + (part << 3)] = *(const short8*)(wtl + wb);
            }
            __syncthreads();
            const short8 a = *(const short8*)&As[(wv * 16 + ln15) * 40 + kb];
#pragma unroll
            for (int nt = 0; nt < NTN; ++nt) {
                const short8 bh = *(const short8*)&Bh[(nt * 16 + ln15) * 40 + kb];
                acc[nt] = __builtin_amdgcn_mfma_f32_16x16x32_bf16(a, bh, acc[nt], 0, 0, 0);
                const short8 bl = *(const short8*)&Bl[(nt * 16 + ln15) * 40 + kb];
                acc[nt] = __builtin_amdgcn_mfma_f32_16x16x32_bf16(a, bl, acc[nt], 0, 0, 0);
            }
        }
    }

    // epilogue: D col=lane&15 -> o, row=(lane>>4)*4+r -> pixel
#pragma unroll
    for (int nt = 0; nt < NTN; ++nt) {
        const int o = obase + nt * 16 + ln15;
        if (o < O) {
            const float bv = bias[o];
#pragma unroll
            for (int r = 0; r < 4; ++r) {
                const int pp = p0 + wv * 16 + ((lane >> 4) << 2) + r;
                const float v = acc[nt][r] + bv;
                const size_t oidx = ((size_t)(b * O + o)) * HW + pp;
                if (EPI == 0) ((float*)outv)[oidx] = v;
                else          ((bf16*)outv)[oidx] = __float2bfloat16(v);
            }
        }
    }
}

// ---------------- instance norm ----------------
template<typename T>
__global__ __launch_bounds__(256) void inorm_kernel(T* __restrict__ buf,
                                                    float* __restrict__ resid,
                                                    int HW, int mode)
{
    __shared__ double sh0[256], sh1[256];
    const int pl = blockIdx.x;
    T* p = buf + (size_t)pl * HW;
    double s = 0.0, ss = 0.0;
    for (int i = threadIdx.x; i < HW; i += 256) {
        float v = LD(p + i);
        s += (double)v; ss += (double)v * (double)v;
    }
    sh0[threadIdx.x] = s; sh1[threadIdx.x] = ss;
    __syncthreads();
    for (int st = 128; st > 0; st >>= 1) {
        if (threadIdx.x < st) {
            sh0[threadIdx.x] += sh0[threadIdx.x + st];
            sh1[threadIdx.x] += sh1[threadIdx.x + st];
        }
        __syncthreads();
    }
    const double mean = sh0[0] / HW;
    const float m = (float)mean;
    const float var = (float)(sh1[0] / HW - mean * mean);
    const float inv = rsqrtf(var + 1e-5f);
    if (mode == 0) {
        for (int i = threadIdx.x; i < HW; i += 256) {
            float v = (LD(p + i) - m) * inv;
            ST(p + i, v > 0.f ? v : 0.f);
        }
    } else {
        float* r = resid + (size_t)pl * HW;
        for (int i = threadIdx.x; i < HW; i += 256)
            r[i] = r[i] + (LD(p + i) - m) * inv;
    }
}

// ---------------- weight transpose for mdcn: w[o][c][k] -> wT[c*9+k][o] ----------------
__global__ __launch_bounds__(256) void wtrans_kernel(const float* __restrict__ w,
                                                     float* __restrict__ wT, int C, int O)
{
    const int i = blockIdx.x * 256 + threadIdx.x;
    const int n = O * C * 9;
    if (i >= n) return;
    const int o = i / (C * 9);
    const int r = i - o * C * 9;
    wT[(size_t)r * O + o] = w[i];
}

// ---------------- modulated deformable conv, cooperative LDS ----------------
template<int NT, int T, int CC, typename OT>
__global__ __launch_bounds__(256) void mdcn_lds(
        const float* __restrict__ skip, const float* __restrict__ om,
        const float* __restrict__ wT, const float* __restrict__ bias,
        OT* __restrict__ out, int C, int O, int H, int W)
{
    __shared__ __align__(16) float smp[CC * 9 * T];
    __shared__ float tpy[9 * T], tpx[9 * T], tm[9 * T];
    const int b = blockIdx.y;
    const int p0 = blockIdx.x * T;
    const int tid = threadIdx.x;
    const int HW = H * W;
    const float* omb = om + (size_t)b * 27 * HW;
    for (int i = tid; i < 9 * T; i += NT) {
        const int k = i / T, t = i - k * T;
        const int p = p0 + t;
        const int y = p / W, x = p - y * W;
        const float dy = omb[(2 * k) * HW + p];
        const float dx = omb[(2 * k + 1) * HW + p];
        const float mk = 1.f / (1.f + expf(-omb[(18 + k) * HW + p]));
        float py = (float)(y + k / 3 - 1) + dy;
        float pxx = (float)(x + k % 3 - 1) + dx;
        py  = fminf(fmaxf(py, -2.f), (float)H + 1.f);
        pxx = fminf(fmaxf(pxx, -2.f), (float)W + 1.f);
        tpy[i] = py; tpx[i] = pxx; tm[i] = mk;
    }

    float acc[T];
#pragma unroll
    for (int t = 0; t < T; ++t) acc[t] = 0.f;
    const int o = tid;
    const float* xb = skip + (size_t)b * C * HW;

    for (int c0 = 0; c0 < C; c0 += CC) {
        __syncthreads();
        for (int i = tid; i < CC * 9 * T; i += NT) {
            const int t = i % T;
            const int kk = (i / T) % 9;
            const int ci = i / (9 * T);
            const int ti = kk * T + t;
            const float py = tpy[ti], pxx = tpx[ti], mk = tm[ti];
            const float y0f = floorf(py), x0f = floorf(pxx);
            const int y0 = (int)y0f, x0 = (int)x0f;
            const float wy1 = py - y0f, wx1 = pxx - x0f;
            const float wy0 = 1.f - wy1, wx0 = 1.f - wx1;
            const float* pl = xb + (size_t)(c0 + ci) * HW;
            float v = 0.f;
            if (y0 >= 0 && y0 < H) {
                const float* r = pl + y0 * W;
                if (x0 >= 0 && x0 < W)         v += wy0 * wx0 * r[x0];
                if (x0 + 1 >= 0 && x0 + 1 < W) v += wy0 * wx1 * r[x0 + 1];
            }
            if (y0 + 1 >= 0 && y0 + 1 < H) {
                const float* r = pl + (y0 + 1) * W;
                if (x0 >= 0 && x0 < W)         v += wy1 * wx0 * r[x0];
                if (x0 + 1 >= 0 && x0 + 1 < W) v += wy1 * wx1 * r[x0 + 1];
            }
            smp[i] = v * mk;
        }
        __syncthreads();
        for (int ci = 0; ci < CC; ++ci) {
#pragma unroll
            for (int k = 0; k < 9; ++k) {
                const float wvv = wT[((size_t)(c0 + ci) * 9 + k) * O + o];
                const float4* sp = (const float4*)(smp + (ci * 9 + k) * T);
#pragma unroll
                for (int q = 0; q < T / 4; ++q) {
                    const float4 s = sp[q];
                    acc[q * 4 + 0] += wvv * s.x;
                    acc[q * 4 + 1] += wvv * s.y;
                    acc[q * 4 + 2] += wvv * s.z;
                    acc[q * 4 + 3] += wvv * s.w;
                }
            }
        }
    }
    const float bv = bias[o];
    OT* op = out + (size_t)(b * O + o) * HW + p0;
#pragma unroll
    for (int t = 0; t < T; ++t) ST(op + t, acc[t] + bv);
}

// ---------------- offset_sum ----------------
__global__ void zero1_kernel(float* __restrict__ out) { if (threadIdx.x == 0) out[0] = 0.f; }

__global__ __launch_bounds__(256) void offsum_one(const float* __restrict__ om, int HW,
                                                  float* __restrict__ out)
{
    __shared__ double sh[256];
    const int n = 8 * 18 * HW;
    double s = 0.0;
    for (int i = blockIdx.x * 256 + threadIdx.x; i < n; i += gridDim.x * 256) {
        const int b = i / (18 * HW); const int r = i - b * 18 * HW;
        const int c = r / HW; const int p = r - c * HW;
        s += fabs((double)om[(size_t)(b * 27 + c) * HW + p]);
    }
    sh[threadIdx.x] = s;
    __syncthreads();
    for (int st = 128; st > 0; st >>= 1) {
        if (threadIdx.x < st) sh[threadIdx.x] += sh[threadIdx.x + st];
        __syncthreads();
    }
    if (threadIdx.x == 0) atomicAdd(out, (float)(0.5 * sh[0] / n));
}

// ---------------- launch ----------------
extern "C" void kernel_launch(void* const* d_in, const int* in_sizes, int n_in,
                              void* d_out, int out_size, void* d_ws, size_t ws_size,
                              hipStream_t stream)
{
    if (n_in < 27) return;
    if (out_size < 393217) return;
    if (in_sizes[0] != 8 * 256 * 32 * 32) return;
    if (in_sizes[1] != 8 * 128 * 64 * 64) return;
    if (in_sizes[2] != 8 * 256 * 32 * 32) return;
    if (in_sizes[25] != 128 * 128 * 9) return;
    if (in_sizes[26] != 128) return;

    const float* x        = (const float*)d_in[0];
    const float* skip1    = (const float*)d_in[1];
    const float* skip2    = (const float*)d_in[2];
    const float* rbw[2][2] = {{(const float*)d_in[3], (const float*)d_in[5]},
                              {(const float*)d_in[7], (const float*)d_in[9]}};
    const float* rbb[2][2] = {{(const float*)d_in[4], (const float*)d_in[6]},
                              {(const float*)d_in[8], (const float*)d_in[10]}};
    const float* conv1_w = (const float*)d_in[11]; const float* conv1_b = (const float*)d_in[12];
    const float* conv3_w = (const float*)d_in[13]; const float* conv3_b = (const float*)d_in[14];
    const float* conv5_w = (const float*)d_in[15]; const float* conv5_b = (const float*)d_in[16];
    const float* conv6_w = (const float*)d_in[17]; const float* conv6_b = (const float*)d_in[18];
    const float* dcn2_off_w = (const float*)d_in[19]; const float* dcn2_off_b = (const float*)d_in[20];
    const float* dcn2_w = (const float*)d_in[21]; const float* dcn2_b = (const float*)d_in[22];
    const float* dcn1_off_w = (const float*)d_in[23]; const float* dcn1_off_b = (const float*)d_in[24];
    const float* dcn1_w = (const float*)d_in[25]; const float* dcn1_b = (const float*)d_in[26];

    float* outp = (float*)d_out;

    const size_t NEED_F32 = 9494528ull;      // unchanged, proven R8-R10
    if (ws_size < NEED_F32 * 4ull) return;

    float* ws = (float*)d_ws;
    const size_t NA = 2097152ull;            // 8*256*32*32
    float* A   = ws;                          // x / rb accum / pre2 ; later Ib
    float* Bb  = ws + NA;                     // h / D ; later wT1 ; later Jb(lo half)
    float* Tmp = ws + 2 * NA;                 // rb tmp ; {wT2,wo2} ; wt3 ; wo1 ; Jb(hi half)
    float* om2 = ws + 3 * NA;                 // [221184]
    float* om1 = om2 + 221184;                // [884736] ; later conv5 wt
    bf16*  Fb  = (bf16*)(om1 + 884736);       // c3 bf16
    bf16*  Ib  = (bf16*)A;                    // pre1 bf16
    bf16*  Jb  = (bf16*)Bb;                   // c5 bf16 (Bb+Tmp)
    float* wT2 = Tmp;                         // mdcn2 transposed weights (589824 f32)
    u16*   wo2h = (u16*)(Tmp + 589824);       // dcn2 off-conv MFMA w hi (124416 u16)
    u16*   wo2l = wo2h + 124416;              // .. lo (ends at Tmp+714240 f32-eq)
    u16*   wt3h = (u16*)Tmp;                  // conv3 MFMA w (after mdcn2; 1.64M u16 x2)
    u16*   wt3l = wt3h + 25 * 128 * 512;
    u16*   wo1h = (u16*)Tmp;                  // dcn1 off-conv MFMA w (after conv3; 62208 x2)
    u16*   wo1l = wo1h + 62208;
    float* wT1 = Bb;                          // mdcn1 transposed weights (after conv3)
    u16*   wt5h = (u16*)om1;                  // conv5 MFMA w (after offsum; 409600 x2)
    u16*   wt5l = wt5h + 25 * 64 * 256;

    copy_kernel<<<8192, 256, 0, stream>>>(x, A, (int)NA);

    // ResBlocks (f32 conv_reg, NO=8 for occupancy -- precision-critical early stages)
    for (int r = 0; r < 2; ++r) {
        conv_reg<float, float, 3, true, false, 0, 256, 8><<<dim3(4, 8, 32), 256, 0, stream>>>(
            A, (const float*)nullptr, 256, 256, rbw[r][0], rbb[r][0], Bb, 256, 32, 32);
        inorm_kernel<float><<<2048, 256, 0, stream>>>(Bb, nullptr, 1024, 0);
        conv_reg<float, float, 3, true, false, 0, 256, 8><<<dim3(4, 8, 32), 256, 0, stream>>>(
            Bb, (const float*)nullptr, 256, 256, rbw[r][1], rbb[r][1], Tmp, 256, 32, 32);
        inorm_kernel<float><<<2048, 256, 0, stream>>>(Tmp, A, 1024, 1);
    }

    // conv1 (5x5, 256->256) + IN/ReLU
    conv_reg<float, float, 5, true, false, 0, 256, 8><<<dim3(4, 8, 32), 256, 0, stream>>>(
        A, (const float*)nullptr, 256, 256, conv1_w, conv1_b, Bb, 256, 32, 32);
    inorm_kernel<float><<<2048, 256, 0, stream>>>(Bb, nullptr, 1024, 0);

    // dcn2 off-conv: MFMA (zero-pad, K=3, O=27 in 2 N-tiles) -> om2
    wsplit_kernel<<<486, 256, 0, stream>>>(dcn2_off_w, wo2h, wo2l, 27, 512, 9);
    conv_mfma<float, float, 3, false, false, 2, 0><<<dim3(16, 8, 1), 256, 0, stream>>>(
        Bb, skip2, 256, 512, wo2h, wo2l, dcn2_off_b, om2, 27, 32, 32);
    wtrans_kernel<<<2304, 256, 0, stream>>>(dcn2_w, wT2, 256, 256);
    mdcn_lds<256, 8, 32, float><<<dim3(128, 8), 256, 0, stream>>>(
        skip2, om2, wT2, dcn2_b, A, 256, 256, 32, 32);

    // conv3: MFMA implicit GEMM, 512->128 @64x64 -> Fb + IN/ReLU
    wsplit_kernel<<<6400, 256, 0, stream>>>(conv3_w, wt3h, wt3l, 128, 512, 25);
    conv_mfma<float, float, 5, true, true, 4, 2><<<dim3(64, 8, 2), 256, 0, stream>>>(
        A, Bb, 256, 512, wt3h, wt3l, conv3_b, Fb, 128, 64, 64);
    inorm_kernel<bf16><<<1024, 256, 0, stream>>>(Fb, nullptr, 4096, 0);

    // dcn1 off-conv: MFMA -> om1
    wsplit_kernel<<<243, 256, 0, stream>>>(dcn1_off_w, wo1h, wo1l, 27, 256, 9);
    conv_mfma<bf16, float, 3, false, false, 2, 0><<<dim3(64, 8, 1), 256, 0, stream>>>(
        Fb, skip1, 128, 256, wo1h, wo1l, dcn1_off_b, om1, 27, 64, 64);
    wtrans_kernel<<<576, 256, 0, stream>>>(dcn1_w, wT1, 128, 128);
    mdcn_lds<128, 16, 32, bf16><<<dim3(256, 8), 128, 0, stream>>>(
        skip1, om1, wT1, dcn1_b, Ib, 128, 128, 64, 64);

    // offset_sum now (frees om1 region for conv5 weights)
    zero1_kernel<<<1, 64, 0, stream>>>(outp + 393216);
    offsum_one<<<64, 256, 0, stream>>>(om1, 4096, outp + 393216);
    offsum_one<<<64, 256, 0, stream>>>(om2, 1024, outp + 393216);

    // conv5: MFMA implicit GEMM, 256->64 @128x128 -> Jb + IN/ReLU
    wsplit_kernel<<<1600, 256, 0, stream>>>(conv5_w, wt5h, wt5l, 64, 256, 25);
    conv_mfma<bf16, bf16, 5, true, true, 4, 2><<<dim3(256, 8, 1), 256, 0, stream>>>(
        Ib, Fb, 128, 256, wt5h, wt5l, conv5_b, Jb, 64, 128, 128);
    inorm_kernel<bf16><<<512, 256, 0, stream>>>(Jb, nullptr, 16384, 0);

    // conv6: 7x7, 64->3, tanh -> d_out (f32)
    conv_reg<bf16, float, 7, true, false, 1, 256, 3><<<dim3(64, 8, 1), 256, 0, stream>>>(
        Jb, (const float*)nullptr, 64, 64, conv6_w, conv6_b, (void*)outp, 3, 128, 128);
}

// Round 12
// 3469.864 us; speedup vs baseline: 17.1789x; 1.5872x over previous
//
#include <hip/hip_runtime.h>
#include <hip/hip_bf16.h>
#include <math.h>

typedef __hip_bfloat16 bf16;
typedef unsigned short u16;
typedef __attribute__((ext_vector_type(8))) short short8;   // 8 bf16 (4 VGPRs)
typedef __attribute__((ext_vector_type(4))) float f32x4;

__device__ __forceinline__ float LD(const float* p) { return *p; }
__device__ __forceinline__ float LD(const bf16* p)  { return __bfloat162float(*p); }
__device__ __forceinline__ void  ST(float* p, float v) { *p = v; }
__device__ __forceinline__ void  ST(bf16* p, float v)  { *p = __float2bfloat16(v); }
__device__ __forceinline__ u16   f2b(float v) { bf16 h = __float2bfloat16(v); return *reinterpret_cast<u16*>(&h); }
__device__ __forceinline__ float b2fu(u16 u) { bf16 h = *reinterpret_cast<bf16*>(&u); return __bfloat162float(h); }

// ---------------- f32 copy ----------------
__global__ __launch_bounds__(256) void copy_kernel(const float* __restrict__ in,
                                                   float* __restrict__ out, int n) {
    int i = blockIdx.x * blockDim.x + threadIdx.x;
    if (i < n) out[i] = in[i];
}

// ---------------- register-blocked conv (f32, scalar weights) ----------------
template<typename T1, typename T2, int K, bool REFLECT, bool UP, int EPI, int PXT, int NO>
__global__ __launch_bounds__(256) void conv_reg(
        const T1* __restrict__ src1, const T2* __restrict__ src2,
        int C1, int C,
        const float* __restrict__ w, const float* __restrict__ bias,
        void* __restrict__ outv, int O, int H, int W)
{
    constexpr int KK = K * K;
    const int tid = threadIdx.x;
    const int px  = tid % PXT;
    const int o_base = __builtin_amdgcn_readfirstlane(
        blockIdx.z * (256 / PXT) * NO + (tid / PXT) * NO);
    const int b = blockIdx.y;
    const int p = blockIdx.x * PXT + px;
    const int HW = H * W;
    const int y = p / W, x = p - y * W;
    const int Hs = UP ? (H >> 1) : H;
    const int Ws = UP ? (W >> 1) : W;
    const int HsWs = Hs * Ws;
    const int PAD = K / 2;

    int off[KK];
    float msk[KK];
#pragma unroll
    for (int ty = 0; ty < K; ++ty) {
#pragma unroll
        for (int tx = 0; tx < K; ++tx) {
            int yy = y + ty - PAD, xx = x + tx - PAD;
            bool v = true;
            if (REFLECT) {
                yy = yy < 0 ? -yy : yy; yy = yy >= H ? 2 * H - 2 - yy : yy;
                xx = xx < 0 ? -xx : xx; xx = xx >= W ? 2 * W - 2 - xx : xx;
            } else {
                v = (yy >= 0 && yy < H && xx >= 0 && xx < W);
                yy = yy < 0 ? 0 : (yy >= H ? H - 1 : yy);
                xx = xx < 0 ? 0 : (xx >= W ? W - 1 : xx);
            }
            const int sy = UP ? (yy >> 1) : yy;
            const int sx = UP ? (xx >> 1) : xx;
            off[ty * K + tx] = sy * Ws + sx;
            msk[ty * K + tx] = v ? 1.f : 0.f;
        }
    }

    float acc[NO];
#pragma unroll
    for (int no = 0; no < NO; ++no) acc[no] = 0.f;

    const int C2 = C - C1;
    {
        const T1* pb = src1 + (size_t)b * C1 * HsWs;
        for (int c = 0; c < C1; ++c) {
            const T1* pl = pb + (size_t)c * HsWs;
            float tap[KK];
#pragma unroll
            for (int t = 0; t < KK; ++t) {
                const float v = LD(pl + off[t]);
                tap[t] = REFLECT ? v : v * msk[t];
            }
            const float* wc = w + ((size_t)o_base * C + c) * KK;
#pragma unroll
            for (int no = 0; no < NO; ++no) {
                const int oo = (o_base + no < O) ? no : 0;
                const float* wn = wc + (size_t)oo * C * KK;
#pragma unroll
                for (int t = 0; t < KK; ++t) acc[no] += wn[t] * tap[t];
            }
        }
    }
    if (C2 > 0) {
        const T2* pb = src2 + (size_t)b * C2 * HsWs;
        for (int c = 0; c < C2; ++c) {
            const T2* pl = pb + (size_t)c * HsWs;
            float tap[KK];
#pragma unroll
            for (int t = 0; t < KK; ++t) {
                const float v = LD(pl + off[t]);
                tap[t] = REFLECT ? v : v * msk[t];
            }
            const float* wc = w + ((size_t)o_base * C + C1 + c) * KK;
#pragma unroll
            for (int no = 0; no < NO; ++no) {
                const int oo = (o_base + no < O) ? no : 0;
                const float* wn = wc + (size_t)oo * C * KK;
#pragma unroll
                for (int t = 0; t < KK; ++t) acc[no] += wn[t] * tap[t];
            }
        }
    }

#pragma unroll
    for (int no = 0; no < NO; ++no) {
        const int o = o_base + no;
        if (o < O) {
            const float v = acc[no] + bias[o];
            const size_t oidx = (size_t)(b * O + o) * HW + p;
            if (EPI == 0)      ((float*)outv)[oidx] = v;
            else if (EPI == 1) ((float*)outv)[oidx] = tanhf(v);
            else               ((bf16*)outv)[oidx] = __float2bfloat16(v);
        }
    }
}

// ---------------- weight split+transpose for MFMA: w[o][c][t] f32 -> hi/lo [t][o][c] bf16 ----
__global__ __launch_bounds__(256) void wsplit_kernel(const float* __restrict__ w,
                                                     u16* __restrict__ hi, u16* __restrict__ lo,
                                                     int O, int C, int KK)
{
    const int i = blockIdx.x * 256 + threadIdx.x;
    const int n = O * C * KK;
    if (i >= n) return;
    const int o = i / (C * KK);
    const int r = i - o * C * KK;
    const int c = r / KK;
    const int t = r - c * KK;
    const float v = w[i];
    const bf16 h = __float2bfloat16(v);
    const float hv = __bfloat162float(h);
    const bf16 l = __float2bfloat16(v - hv);
    const size_t dst = ((size_t)t * O + o) * C + c;
    hi[dst] = *(const u16*)&h;
    lo[dst] = *(const u16*)&l;
}

// ---------------- MFMA implicit-GEMM conv (generalized) ----------------
// block: 256 thr = 4 waves; M=64 pixels x N=NTN*16 out-channels (obase=z*NTN*16).
// K-loop: taps t(K*K) x C-chunks(32). W hi/lo split -> 2 MFMAs.
// ASPLIT: A also hi/lo split -> +1 MFMA (Al*Bh) => ~f32 precision end to end.
template<typename T1, typename T2, int K, bool REFLECT, bool UP, int NTN, int EPI, bool ASPLIT>
__global__ __launch_bounds__(256) void conv_mfma(
        const T1* __restrict__ src1, const T2* __restrict__ src2,
        int C1, int C,
        const u16* __restrict__ wth, const u16* __restrict__ wtl,
        const float* __restrict__ bias,
        void* __restrict__ outv, int O, int H, int W)
{
    constexpr int KK = K * K;
    __shared__ __align__(16) u16 As[64 * 40];
    __shared__ __align__(16) u16 Alo[ASPLIT ? 64 * 40 : 8];
    __shared__ __align__(16) u16 Bh[NTN * 16 * 40];
    __shared__ __align__(16) u16 Bl[NTN * 16 * 40];

    const int tid  = threadIdx.x;
    const int wv   = tid >> 6;          // wave 0..3
    const int lane = tid & 63;
    const int ln15 = lane & 15;
    const int kb   = (lane >> 4) << 3;  // 0,8,16,24
    const int b    = blockIdx.y;
    const int p0   = blockIdx.x * 64;
    const int obase = blockIdx.z * (NTN * 16);
    const int HW = H * W;
    const int Hs = UP ? (H >> 1) : H;
    const int Ws = UP ? (W >> 1) : W;
    const int HsWs = Hs * Ws;
    const int PAD = K / 2;
    const int C2 = C - C1;

    const int m_stage = tid & 63;
    const int ci0 = tid >> 6;          // 0..3

    const int p = p0 + m_stage;
    const int y = p / W, x = p - y * W;
    int off[KK];
    float msk[KK];
#pragma unroll
    for (int ty = 0; ty < K; ++ty) {
#pragma unroll
        for (int tx = 0; tx < K; ++tx) {
            int yy = y + ty - PAD, xx = x + tx - PAD;
            bool vv = true;
            if (REFLECT) {
                yy = yy < 0 ? -yy : yy; yy = yy >= H ? 2 * H - 2 - yy : yy;
                xx = xx < 0 ? -xx : xx; xx = xx >= W ? 2 * W - 2 - xx : xx;
            } else {
                vv = (yy >= 0 && yy < H && xx >= 0 && xx < W);
                yy = yy < 0 ? 0 : (yy >= H ? H - 1 : yy);
                xx = xx < 0 ? 0 : (xx >= W ? W - 1 : xx);
            }
            off[ty * K + tx] = (UP ? (yy >> 1) : yy) * Ws + (UP ? (xx >> 1) : xx);
            msk[ty * K + tx] = vv ? 1.f : 0.f;
        }
    }

    f32x4 acc[NTN];
#pragma unroll
    for (int nt = 0; nt < NTN; ++nt) acc[nt] = (f32x4)0.f;

    const int nch = C >> 5;
    for (int t = 0; t < KK; ++t) {
        const int offt = off[t];
        const float mskt = msk[t];
        for (int cc = 0; cc < nch; ++cc) {
            const int c0 = cc << 5;
            __syncthreads();
            // stage A: As[m][ci] = src[c0+ci][off_t[m]] (zero-pad masked)
#pragma unroll
            for (int q = 0; q < 8; ++q) {
                const int ci = ci0 + (q << 2);
                const int c = c0 + ci;
                float v;
                if (c < C1) v = LD(src1 + ((size_t)(b * C1 + c)) * HsWs + offt);
                else        v = LD(src2 + ((size_t)(b * C2 + (c - C1))) * HsWs + offt);
                if (!REFLECT) v *= mskt;
                const u16 hv = f2b(v);
                As[m_stage * 40 + ci] = hv;
                if (ASPLIT) Alo[m_stage * 40 + ci] = f2b(v - b2fu(hv));
            }
            // stage B: rows = NTN*16 out-chans, 32 chans each (clamped at O-1)
            for (int i = tid; i < NTN * 16 * 4; i += 256) {
                const int row = i >> 2, part = i & 3;
                int o = obase + row; if (o >= O) o = O - 1;
                const size_t wb = ((size_t)t * O + o) * C + c0 + (part << 3);
                *(short8*)&Bh[row * 40 + (part << 3)] = *(const short8*)(wth + wb);
                *(short8*)&Bl[row * 40 + (part << 3)] = *(const short8*)(wtl + wb);
            }
            __syncthreads();
            const short8 a = *(const short8*)&As[(wv * 16 + ln15) * 40 + kb];
            short8 al;
            if (ASPLIT) al = *(const short8*)&Alo[(wv * 16 + ln15) * 40 + kb];
#pragma unroll
            for (int nt = 0; nt < NTN; ++nt) {
                const short8 bh = *(const short8*)&Bh[(nt * 16 + ln15) * 40 + kb];
                acc[nt] = __builtin_amdgcn_mfma_f32_16x16x32_bf16(a, bh, acc[nt], 0, 0, 0);
                const short8 bl = *(const short8*)&Bl[(nt * 16 + ln15) * 40 + kb];
                acc[nt] = __builtin_amdgcn_mfma_f32_16x16x32_bf16(a, bl, acc[nt], 0, 0, 0);
                if (ASPLIT)
                    acc[nt] = __builtin_amdgcn_mfma_f32_16x16x32_bf16(al, bh, acc[nt], 0, 0, 0);
            }
        }
    }

    // epilogue: D col=lane&15 -> o, row=(lane>>4)*4+r -> pixel
#pragma unroll
    for (int nt = 0; nt < NTN; ++nt) {
        const int o = obase + nt * 16 + ln15;
        if (o < O) {
            const float bv = bias[o];
#pragma unroll
            for (int r = 0; r < 4; ++r) {
                const int pp = p0 + wv * 16 + ((lane >> 4) << 2) + r;
                const float v = acc[nt][r] + bv;
                const size_t oidx = ((size_t)(b * O + o)) * HW + pp;
                if (EPI == 0) ((float*)outv)[oidx] = v;
                else          ((bf16*)outv)[oidx] = __float2bfloat16(v);
            }
        }
    }
}

// ---------------- instance norm ----------------
template<typename T>
__global__ __launch_bounds__(256) void inorm_kernel(T* __restrict__ buf,
                                                    float* __restrict__ resid,
                                                    int HW, int mode)
{
    __shared__ double sh0[256], sh1[256];
    const int pl = blockIdx.x;
    T* p = buf + (size_t)pl * HW;
    double s = 0.0, ss = 0.0;
    for (int i = threadIdx.x; i < HW; i += 256) {
        float v = LD(p + i);
        s += (double)v; ss += (double)v * (double)v;
    }
    sh0[threadIdx.x] = s; sh1[threadIdx.x] = ss;
    __syncthreads();
    for (int st = 128; st > 0; st >>= 1) {
        if (threadIdx.x < st) {
            sh0[threadIdx.x] += sh0[threadIdx.x + st];
            sh1[threadIdx.x] += sh1[threadIdx.x + st];
        }
        __syncthreads();
    }
    const double mean = sh0[0] / HW;
    const float m = (float)mean;
    const float var = (float)(sh1[0] / HW - mean * mean);
    const float inv = rsqrtf(var + 1e-5f);
    if (mode == 0) {
        for (int i = threadIdx.x; i < HW; i += 256) {
            float v = (LD(p + i) - m) * inv;
            ST(p + i, v > 0.f ? v : 0.f);
        }
    } else {
        float* r = resid + (size_t)pl * HW;
        for (int i = threadIdx.x; i < HW; i += 256)
            r[i] = r[i] + (LD(p + i) - m) * inv;
    }
}

// ---------------- weight transpose for mdcn: w[o][c][k] -> wT[c*9+k][o] ----------------
__global__ __launch_bounds__(256) void wtrans_kernel(const float* __restrict__ w,
                                                     float* __restrict__ wT, int C, int O)
{
    const int i = blockIdx.x * 256 + threadIdx.x;
    const int n = O * C * 9;
    if (i >= n) return;
    const int o = i / (C * 9);
    const int r = i - o * C * 9;
    wT[(size_t)r * O + o] = w[i];
}

// ---------------- modulated deformable conv, cooperative LDS ----------------
template<int NT, int T, int CC, typename OT>
__global__ __launch_bounds__(256) void mdcn_lds(
        const float* __restrict__ skip, const float* __restrict__ om,
        const float* __restrict__ wT, const float* __restrict__ bias,
        OT* __restrict__ out, int C, int O, int H, int W)
{
    __shared__ __align__(16) float smp[CC * 9 * T];
    __shared__ float tpy[9 * T], tpx[9 * T], tm[9 * T];
    const int b = blockIdx.y;
    const int p0 = blockIdx.x * T;
    const int tid = threadIdx.x;
    const int HW = H * W;
    const float* omb = om + (size_t)b * 27 * HW;
    for (int i = tid; i < 9 * T; i += NT) {
        const int k = i / T, t = i - k * T;
        const int p = p0 + t;
        const int y = p / W, x = p - y * W;
        const float dy = omb[(2 * k) * HW + p];
        const float dx = omb[(2 * k + 1) * HW + p];
        const float mk = 1.f / (1.f + expf(-omb[(18 + k) * HW + p]));
        float py = (float)(y + k / 3 - 1) + dy;
        float pxx = (float)(x + k % 3 - 1) + dx;
        py  = fminf(fmaxf(py, -2.f), (float)H + 1.f);
        pxx = fminf(fmaxf(pxx, -2.f), (float)W + 1.f);
        tpy[i] = py; tpx[i] = pxx; tm[i] = mk;
    }

    float acc[T];
#pragma unroll
    for (int t = 0; t < T; ++t) acc[t] = 0.f;
    const int o = tid;
    const float* xb = skip + (size_t)b * C * HW;

    for (int c0 = 0; c0 < C; c0 += CC) {
        __syncthreads();
        for (int i = tid; i < CC * 9 * T; i += NT) {
            const int t = i % T;
            const int kk = (i / T) % 9;
            const int ci = i / (9 * T);
            const int ti = kk * T + t;
            const float py = tpy[ti], pxx = tpx[ti], mk = tm[ti];
            const float y0f = floorf(py), x0f = floorf(pxx);
            const int y0 = (int)y0f, x0 = (int)x0f;
            const float wy1 = py - y0f, wx1 = pxx - x0f;
            const float wy0 = 1.f - wy1, wx0 = 1.f - wx1;
            const float* pl = xb + (size_t)(c0 + ci) * HW;
            float v = 0.f;
            if (y0 >= 0 && y0 < H) {
                const float* r = pl + y0 * W;
                if (x0 >= 0 && x0 < W)         v += wy0 * wx0 * r[x0];
                if (x0 + 1 >= 0 && x0 + 1 < W) v += wy0 * wx1 * r[x0 + 1];
            }
            if (y0 + 1 >= 0 && y0 + 1 < H) {
                const float* r = pl + (y0 + 1) * W;
                if (x0 >= 0 && x0 < W)         v += wy1 * wx0 * r[x0];
                if (x0 + 1 >= 0 && x0 + 1 < W) v += wy1 * wx1 * r[x0 + 1];
            }
            smp[i] = v * mk;
        }
        __syncthreads();
        for (int ci = 0; ci < CC; ++ci) {
#pragma unroll
            for (int k = 0; k < 9; ++k) {
                const float wvv = wT[((size_t)(c0 + ci) * 9 + k) * O + o];
                const float4* sp = (const float4*)(smp + (ci * 9 + k) * T);
#pragma unroll
                for (int q = 0; q < T / 4; ++q) {
                    const float4 s = sp[q];
                    acc[q * 4 + 0] += wvv * s.x;
                    acc[q * 4 + 1] += wvv * s.y;
                    acc[q * 4 + 2] += wvv * s.z;
                    acc[q * 4 + 3] += wvv * s.w;
                }
            }
        }
    }
    const float bv = bias[o];
    OT* op = out + (size_t)(b * O + o) * HW + p0;
#pragma unroll
    for (int t = 0; t < T; ++t) ST(op + t, acc[t] + bv);
}

// ---------------- offset_sum ----------------
__global__ void zero1_kernel(float* __restrict__ out) { if (threadIdx.x == 0) out[0] = 0.f; }

__global__ __launch_bounds__(256) void offsum_one(const float* __restrict__ om, int HW,
                                                  float* __restrict__ out)
{
    __shared__ double sh[256];
    const int n = 8 * 18 * HW;
    double s = 0.0;
    for (int i = blockIdx.x * 256 + threadIdx.x; i < n; i += gridDim.x * 256) {
        const int b = i / (18 * HW); const int r = i - b * 18 * HW;
        const int c = r / HW; const int p = r - c * HW;
        s += fabs((double)om[(size_t)(b * 27 + c) * HW + p]);
    }
    sh[threadIdx.x] = s;
    __syncthreads();
    for (int st = 128; st > 0; st >>= 1) {
        if (threadIdx.x < st) sh[threadIdx.x] += sh[threadIdx.x + st];
        __syncthreads();
    }
    if (threadIdx.x == 0) atomicAdd(out, (float)(0.5 * sh[0] / n));
}

// ---------------- launch ----------------
extern "C" void kernel_launch(void* const* d_in, const int* in_sizes, int n_in,
                              void* d_out, int out_size, void* d_ws, size_t ws_size,
                              hipStream_t stream)
{
    if (n_in < 27) return;
    if (out_size < 393217) return;
    if (in_sizes[0] != 8 * 256 * 32 * 32) return;
    if (in_sizes[1] != 8 * 128 * 64 * 64) return;
    if (in_sizes[2] != 8 * 256 * 32 * 32) return;
    if (in_sizes[25] != 128 * 128 * 9) return;
    if (in_sizes[26] != 128) return;

    const float* x        = (const float*)d_in[0];
    const float* skip1    = (const float*)d_in[1];
    const float* skip2    = (const float*)d_in[2];
    const float* rbw[2][2] = {{(const float*)d_in[3], (const float*)d_in[5]},
                              {(const float*)d_in[7], (const float*)d_in[9]}};
    const float* rbb[2][2] = {{(const float*)d_in[4], (const float*)d_in[6]},
                              {(const float*)d_in[8], (const float*)d_in[10]}};
    const float* conv1_w = (const float*)d_in[11]; const float* conv1_b = (const float*)d_in[12];
    const float* conv3_w = (const float*)d_in[13]; const float* conv3_b = (const float*)d_in[14];
    const float* conv5_w = (const float*)d_in[15]; const float* conv5_b = (const float*)d_in[16];
    const float* conv6_w = (const float*)d_in[17]; const float* conv6_b = (const float*)d_in[18];
    const float* dcn2_off_w = (const float*)d_in[19]; const float* dcn2_off_b = (const float*)d_in[20];
    const float* dcn2_w = (const float*)d_in[21]; const float* dcn2_b = (const float*)d_in[22];
    const float* dcn1_off_w = (const float*)d_in[23]; const float* dcn1_off_b = (const float*)d_in[24];
    const float* dcn1_w = (const float*)d_in[25]; const float* dcn1_b = (const float*)d_in[26];

    float* outp = (float*)d_out;

    const size_t NEED_F32 = 9494528ull;      // unchanged, proven R8-R11
    if (ws_size < NEED_F32 * 4ull) return;

    float* ws = (float*)d_ws;
    const size_t NA = 2097152ull;            // 8*256*32*32
    float* A   = ws;                          // x / rb accum / pre2 ; later Ib
    float* Bb  = ws + NA;                     // h / D ; later wT1 ; later Jb(lo half)
    float* Tmp = ws + 2 * NA;                 // rb tmp ; {wT2,wo2} ; wt3 ; wo1 ; Jb(hi half)
    float* om2 = ws + 3 * NA;                 // [221184]
    float* om1 = om2 + 221184;                // [884736] ; later conv5 wt
    bf16*  Fb  = (bf16*)(om1 + 884736);       // c3 bf16 ; BEFORE conv3: early MFMA weights
    bf16*  Ib  = (bf16*)A;                    // pre1 bf16
    bf16*  Jb  = (bf16*)Bb;                   // c5 bf16 (Bb+Tmp)
    float* wT2 = Tmp;                         // mdcn2 transposed weights (589824 f32)
    u16*   wo2h = (u16*)(Tmp + 589824);       // dcn2 off-conv MFMA w hi (124416 u16)
    u16*   wo2l = wo2h + 124416;
    u16*   wt3h = (u16*)Tmp;                  // conv3 MFMA w (after mdcn2)
    u16*   wt3l = wt3h + 25 * 128 * 512;
    u16*   wo1h = (u16*)Tmp;                  // dcn1 off-conv MFMA w (after conv3)
    u16*   wo1l = wo1h + 62208;
    float* wT1 = Bb;                          // mdcn1 transposed weights (after conv3)
    u16*   wt5h = (u16*)om1;                  // conv5 MFMA w (after offsum)
    u16*   wt5l = wt5h + 25 * 64 * 256;
    u16*   wEh = (u16*)Fb;                    // early conv MFMA weights (Fb free until conv3)
                                              //   rb: 589824x2 u16; conv1: 1638400x2 u16 (fits 4.19M)

    copy_kernel<<<8192, 256, 0, stream>>>(x, A, (int)NA);

    // ResBlocks via MFMA (A+W hi/lo split -> ~f32 precision)
    for (int r = 0; r < 2; ++r) {
        wsplit_kernel<<<2304, 256, 0, stream>>>(rbw[r][0], wEh, wEh + 589824, 256, 256, 9);
        conv_mfma<float, float, 3, true, false, 4, 0, true><<<dim3(16, 8, 4), 256, 0, stream>>>(
            A, (const float*)nullptr, 256, 256, wEh, wEh + 589824, rbb[r][0], Bb, 256, 32, 32);
        inorm_kernel<float><<<2048, 256, 0, stream>>>(Bb, nullptr, 1024, 0);
        wsplit_kernel<<<2304, 256, 0, stream>>>(rbw[r][1], wEh, wEh + 589824, 256, 256, 9);
        conv_mfma<float, float, 3, true, false, 4, 0, true><<<dim3(16, 8, 4), 256, 0, stream>>>(
            Bb, (const float*)nullptr, 256, 256, wEh, wEh + 589824, rbb[r][1], Tmp, 256, 32, 32);
        inorm_kernel<float><<<2048, 256, 0, stream>>>(Tmp, A, 1024, 1);
    }

    // conv1 (5x5, 256->256) via MFMA + IN/ReLU
    wsplit_kernel<<<6400, 256, 0, stream>>>(conv1_w, wEh, wEh + 1638400, 256, 256, 25);
    conv_mfma<float, float, 5, true, false, 4, 0, true><<<dim3(16, 8, 4), 256, 0, stream>>>(
        A, (const float*)nullptr, 256, 256, wEh, wEh + 1638400, conv1_b, Bb, 256, 32, 32);
    inorm_kernel<float><<<2048, 256, 0, stream>>>(Bb, nullptr, 1024, 0);

    // dcn2 off-conv: MFMA (zero-pad, K=3, O=27 in 2 N-tiles) -> om2
    wsplit_kernel<<<486, 256, 0, stream>>>(dcn2_off_w, wo2h, wo2l, 27, 512, 9);
    conv_mfma<float, float, 3, false, false, 2, 0, false><<<dim3(16, 8, 1), 256, 0, stream>>>(
        Bb, skip2, 256, 512, wo2h, wo2l, dcn2_off_b, om2, 27, 32, 32);
    wtrans_kernel<<<2304, 256, 0, stream>>>(dcn2_w, wT2, 256, 256);
    mdcn_lds<256, 8, 32, float><<<dim3(128, 8), 256, 0, stream>>>(
        skip2, om2, wT2, dcn2_b, A, 256, 256, 32, 32);

    // conv3: MFMA implicit GEMM, 512->128 @64x64 -> Fb + IN/ReLU
    wsplit_kernel<<<6400, 256, 0, stream>>>(conv3_w, wt3h, wt3l, 128, 512, 25);
    conv_mfma<float, float, 5, true, true, 4, 2, false><<<dim3(64, 8, 2), 256, 0, stream>>>(
        A, Bb, 256, 512, wt3h, wt3l, conv3_b, Fb, 128, 64, 64);
    inorm_kernel<bf16><<<1024, 256, 0, stream>>>(Fb, nullptr, 4096, 0);

    // dcn1 off-conv: MFMA -> om1
    wsplit_kernel<<<243, 256, 0, stream>>>(dcn1_off_w, wo1h, wo1l, 27, 256, 9);
    conv_mfma<bf16, float, 3, false, false, 2, 0, false><<<dim3(64, 8, 1), 256, 0, stream>>>(
        Fb, skip1, 128, 256, wo1h, wo1l, dcn1_off_b, om1, 27, 64, 64);
    wtrans_kernel<<<576, 256, 0, stream>>>(dcn1_w, wT1, 128, 128);
    mdcn_lds<128, 16, 32, bf16><<<dim3(256, 8), 128, 0, stream>>>(
        skip1, om1, wT1, dcn1_b, Ib, 128, 128, 64, 64);

    // offset_sum now (frees om1 region for conv5 weights)
    zero1_kernel<<<1, 64, 0, stream>>>(outp + 393216);
    offsum_one<<<64, 256, 0, stream>>>(om1, 4096, outp + 393216);
    offsum_one<<<64, 256, 0, stream>>>(om2, 1024, outp + 393216);

    // conv5: MFMA implicit GEMM, 256->64 @128x128 -> Jb + IN/ReLU
    wsplit_kernel<<<1600, 256, 0, stream>>>(conv5_w, wt5h, wt5l, 64, 256, 25);
    conv_mfma<bf16, bf16, 5, true, true, 4, 2, false><<<dim3(256, 8, 1), 256, 0, stream>>>(
        Ib, Fb, 128, 256, wt5h, wt5l, conv5_b, Jb, 64, 128, 128);
    inorm_kernel<bf16><<<512, 256, 0, stream>>>(Jb, nullptr, 16384, 0);

    // conv6: 7x7, 64->3, tanh -> d_out (f32)
    conv_reg<bf16, float, 7, true, false, 1, 256, 3><<<dim3(64, 8, 1), 256, 0, stream>>>(
        Jb, (const float*)nullptr, 64, 64, conv6_w, conv6_b, (void*)outp, 3, 128, 128);
}

// Round 13
// 3050.958 us; speedup vs baseline: 19.5377x; 1.1373x over previous
//
#include <hip/hip_runtime.h>
#include <hip/hip_bf16.h>
#include <math.h>

typedef __hip_bfloat16 bf16;
typedef unsigned short u16;
typedef __attribute__((ext_vector_type(8))) short short8;   // 8 bf16 (4 VGPRs)
typedef __attribute__((ext_vector_type(4))) float f32x4;

__device__ __forceinline__ float LD(const float* p) { return *p; }
__device__ __forceinline__ float LD(const bf16* p)  { return __bfloat162float(*p); }
__device__ __forceinline__ void  ST(float* p, float v) { *p = v; }
__device__ __forceinline__ void  ST(bf16* p, float v)  { *p = __float2bfloat16(v); }
__device__ __forceinline__ u16   f2b(float v) { bf16 h = __float2bfloat16(v); return *reinterpret_cast<u16*>(&h); }
__device__ __forceinline__ float b2fu(u16 u) { bf16 h = *reinterpret_cast<bf16*>(&u); return __bfloat162float(h); }

// ---------------- f32 copy ----------------
__global__ __launch_bounds__(256) void copy_kernel(const float* __restrict__ in,
                                                   float* __restrict__ out, int n) {
    int i = blockIdx.x * blockDim.x + threadIdx.x;
    if (i < n) out[i] = in[i];
}

// ---------------- weight split+transpose for MFMA: w[o][c][t] f32 -> hi/lo [t][o][c] bf16 ----
__global__ __launch_bounds__(256) void wsplit_kernel(const float* __restrict__ w,
                                                     u16* __restrict__ hi, u16* __restrict__ lo,
                                                     int O, int C, int KK)
{
    const int i = blockIdx.x * 256 + threadIdx.x;
    const int n = O * C * KK;
    if (i >= n) return;
    const int o = i / (C * KK);
    const int r = i - o * C * KK;
    const int c = r / KK;
    const int t = r - c * KK;
    const float v = w[i];
    const bf16 h = __float2bfloat16(v);
    const float hv = __bfloat162float(h);
    const bf16 l = __float2bfloat16(v - hv);
    const size_t dst = ((size_t)t * O + o) * C + c;
    hi[dst] = *(const u16*)&h;
    lo[dst] = *(const u16*)&l;
}

// ---------------- MFMA implicit-GEMM conv (generalized) ----------------
// block: 256 thr = 4 waves; M=64 pixels x N=NTN*16 out-channels (obase=z*NTN*16).
// K-loop: taps t(K*K) x C-chunks(32). W hi/lo split -> 2 MFMAs.
// ASPLIT: A also hi/lo split -> +1 MFMA (Al*Bh) => ~f32 precision end to end.
// EPI: 0=f32, 1=tanh->f32, 2=bf16
template<typename T1, typename T2, int K, bool REFLECT, bool UP, int NTN, int EPI, bool ASPLIT>
__global__ __launch_bounds__(256) void conv_mfma(
        const T1* __restrict__ src1, const T2* __restrict__ src2,
        int C1, int C,
        const u16* __restrict__ wth, const u16* __restrict__ wtl,
        const float* __restrict__ bias,
        void* __restrict__ outv, int O, int H, int W)
{
    constexpr int KK = K * K;
    __shared__ __align__(16) u16 As[64 * 40];
    __shared__ __align__(16) u16 Alo[ASPLIT ? 64 * 40 : 8];
    __shared__ __align__(16) u16 Bh[NTN * 16 * 40];
    __shared__ __align__(16) u16 Bl[NTN * 16 * 40];

    const int tid  = threadIdx.x;
    const int wv   = tid >> 6;          // wave 0..3
    const int lane = tid & 63;
    const int ln15 = lane & 15;
    const int kb   = (lane >> 4) << 3;  // 0,8,16,24
    const int b    = blockIdx.y;
    const int p0   = blockIdx.x * 64;
    const int obase = blockIdx.z * (NTN * 16);
    const int HW = H * W;
    const int Hs = UP ? (H >> 1) : H;
    const int Ws = UP ? (W >> 1) : W;
    const int HsWs = Hs * Ws;
    const int PAD = K / 2;
    const int C2 = C - C1;

    const int m_stage = tid & 63;
    const int ci0 = tid >> 6;          // 0..3

    const int p = p0 + m_stage;
    const int y = p / W, x = p - y * W;
    int off[KK];
    float msk[KK];
#pragma unroll
    for (int ty = 0; ty < K; ++ty) {
#pragma unroll
        for (int tx = 0; tx < K; ++tx) {
            int yy = y + ty - PAD, xx = x + tx - PAD;
            bool vv = true;
            if (REFLECT) {
                yy = yy < 0 ? -yy : yy; yy = yy >= H ? 2 * H - 2 - yy : yy;
                xx = xx < 0 ? -xx : xx; xx = xx >= W ? 2 * W - 2 - xx : xx;
            } else {
                vv = (yy >= 0 && yy < H && xx >= 0 && xx < W);
                yy = yy < 0 ? 0 : (yy >= H ? H - 1 : yy);
                xx = xx < 0 ? 0 : (xx >= W ? W - 1 : xx);
            }
            off[ty * K + tx] = (UP ? (yy >> 1) : yy) * Ws + (UP ? (xx >> 1) : xx);
            msk[ty * K + tx] = vv ? 1.f : 0.f;
        }
    }

    f32x4 acc[NTN];
#pragma unroll
    for (int nt = 0; nt < NTN; ++nt) acc[nt] = (f32x4)0.f;

    const int nch = C >> 5;
    for (int t = 0; t < KK; ++t) {
        const int offt = off[t];
        const float mskt = msk[t];
        for (int cc = 0; cc < nch; ++cc) {
            const int c0 = cc << 5;
            __syncthreads();
            // stage A: As[m][ci] = src[c0+ci][off_t[m]] (zero-pad masked)
#pragma unroll
            for (int q = 0; q < 8; ++q) {
                const int ci = ci0 + (q << 2);
                const int c = c0 + ci;
                float v;
                if (c < C1) v = LD(src1 + ((size_t)(b * C1 + c)) * HsWs + offt);
                else        v = LD(src2 + ((size_t)(b * C2 + (c - C1))) * HsWs + offt);
                if (!REFLECT) v *= mskt;
                const u16 hv = f2b(v);
                As[m_stage * 40 + ci] = hv;
                if (ASPLIT) Alo[m_stage * 40 + ci] = f2b(v - b2fu(hv));
            }
            // stage B: rows = NTN*16 out-chans, 32 chans each (clamped at O-1)
            for (int i = tid; i < NTN * 16 * 4; i += 256) {
                const int row = i >> 2, part = i & 3;
                int o = obase + row; if (o >= O) o = O - 1;
                const size_t wb = ((size_t)t * O + o) * C + c0 + (part << 3);
                *(short8*)&Bh[row * 40 + (part << 3)] = *(const short8*)(wth + wb);
                *(short8*)&Bl[row * 40 + (part << 3)] = *(const short8*)(wtl + wb);
            }
            __syncthreads();
            const short8 a = *(const short8*)&As[(wv * 16 + ln15) * 40 + kb];
            short8 al;
            if (ASPLIT) al = *(const short8*)&Alo[(wv * 16 + ln15) * 40 + kb];
#pragma unroll
            for (int nt = 0; nt < NTN; ++nt) {
                const short8 bh = *(const short8*)&Bh[(nt * 16 + ln15) * 40 + kb];
                acc[nt] = __builtin_amdgcn_mfma_f32_16x16x32_bf16(a, bh, acc[nt], 0, 0, 0);
                const short8 bl = *(const short8*)&Bl[(nt * 16 + ln15) * 40 + kb];
                acc[nt] = __builtin_amdgcn_mfma_f32_16x16x32_bf16(a, bl, acc[nt], 0, 0, 0);
                if (ASPLIT)
                    acc[nt] = __builtin_amdgcn_mfma_f32_16x16x32_bf16(al, bh, acc[nt], 0, 0, 0);
            }
        }
    }

    // epilogue: D col=lane&15 -> o, row=(lane>>4)*4+r -> pixel
#pragma unroll
    for (int nt = 0; nt < NTN; ++nt) {
        const int o = obase + nt * 16 + ln15;
        if (o < O) {
            const float bv = bias[o];
#pragma unroll
            for (int r = 0; r < 4; ++r) {
                const int pp = p0 + wv * 16 + ((lane >> 4) << 2) + r;
                const float v = acc[nt][r] + bv;
                const size_t oidx = ((size_t)(b * O + o)) * HW + pp;
                if (EPI == 0)      ((float*)outv)[oidx] = v;
                else if (EPI == 1) ((float*)outv)[oidx] = tanhf(v);
                else               ((bf16*)outv)[oidx] = __float2bfloat16(v);
            }
        }
    }
}

// ---------------- instance norm ----------------
template<typename T>
__global__ __launch_bounds__(256) void inorm_kernel(T* __restrict__ buf,
                                                    float* __restrict__ resid,
                                                    int HW, int mode)
{
    __shared__ double sh0[256], sh1[256];
    const int pl = blockIdx.x;
    T* p = buf + (size_t)pl * HW;
    double s = 0.0, ss = 0.0;
    for (int i = threadIdx.x; i < HW; i += 256) {
        float v = LD(p + i);
        s += (double)v; ss += (double)v * (double)v;
    }
    sh0[threadIdx.x] = s; sh1[threadIdx.x] = ss;
    __syncthreads();
    for (int st = 128; st > 0; st >>= 1) {
        if (threadIdx.x < st) {
            sh0[threadIdx.x] += sh0[threadIdx.x + st];
            sh1[threadIdx.x] += sh1[threadIdx.x + st];
        }
        __syncthreads();
    }
    const double mean = sh0[0] / HW;
    const float m = (float)mean;
    const float var = (float)(sh1[0] / HW - mean * mean);
    const float inv = rsqrtf(var + 1e-5f);
    if (mode == 0) {
        for (int i = threadIdx.x; i < HW; i += 256) {
            float v = (LD(p + i) - m) * inv;
            ST(p + i, v > 0.f ? v : 0.f);
        }
    } else {
        float* r = resid + (size_t)pl * HW;
        for (int i = threadIdx.x; i < HW; i += 256)
            r[i] = r[i] + (LD(p + i) - m) * inv;
    }
}

// ---------------- weight transpose for mdcn: w[o][c][k] -> wT[c*9+k][o] ----------------
__global__ __launch_bounds__(256) void wtrans_kernel(const float* __restrict__ w,
                                                     float* __restrict__ wT, int C, int O)
{
    const int i = blockIdx.x * 256 + threadIdx.x;
    const int n = O * C * 9;
    if (i >= n) return;
    const int o = i / (C * 9);
    const int r = i - o * C * 9;
    wT[(size_t)r * O + o] = w[i];
}

// ---------------- modulated deformable conv, cooperative LDS ----------------
template<int NT, int T, int CC, typename OT>
__global__ __launch_bounds__(256) void mdcn_lds(
        const float* __restrict__ skip, const float* __restrict__ om,
        const float* __restrict__ wT, const float* __restrict__ bias,
        OT* __restrict__ out, int C, int O, int H, int W)
{
    __shared__ __align__(16) float smp[CC * 9 * T];
    __shared__ float tpy[9 * T], tpx[9 * T], tm[9 * T];
    const int b = blockIdx.y;
    const int p0 = blockIdx.x * T;
    const int tid = threadIdx.x;
    const int HW = H * W;
    const float* omb = om + (size_t)b * 27 * HW;
    for (int i = tid; i < 9 * T; i += NT) {
        const int k = i / T, t = i - k * T;
        const int p = p0 + t;
        const int y = p / W, x = p - y * W;
        const float dy = omb[(2 * k) * HW + p];
        const float dx = omb[(2 * k + 1) * HW + p];
        const float mk = 1.f / (1.f + expf(-omb[(18 + k) * HW + p]));
        float py = (float)(y + k / 3 - 1) + dy;
        float pxx = (float)(x + k % 3 - 1) + dx;
        py  = fminf(fmaxf(py, -2.f), (float)H + 1.f);
        pxx = fminf(fmaxf(pxx, -2.f), (float)W + 1.f);
        tpy[i] = py; tpx[i] = pxx; tm[i] = mk;
    }

    float acc[T];
#pragma unroll
    for (int t = 0; t < T; ++t) acc[t] = 0.f;
    const int o = tid;
    const float* xb = skip + (size_t)b * C * HW;

    for (int c0 = 0; c0 < C; c0 += CC) {
        __syncthreads();
        for (int i = tid; i < CC * 9 * T; i += NT) {
            const int t = i % T;
            const int kk = (i / T) % 9;
            const int ci = i / (9 * T);
            const int ti = kk * T + t;
            const float py = tpy[ti], pxx = tpx[ti], mk = tm[ti];
            const float y0f = floorf(py), x0f = floorf(pxx);
            const int y0 = (int)y0f, x0 = (int)x0f;
            const float wy1 = py - y0f, wx1 = pxx - x0f;
            const float wy0 = 1.f - wy1, wx0 = 1.f - wx1;
            const float* pl = xb + (size_t)(c0 + ci) * HW;
            float v = 0.f;
            if (y0 >= 0 && y0 < H) {
                const float* r = pl + y0 * W;
                if (x0 >= 0 && x0 < W)         v += wy0 * wx0 * r[x0];
                if (x0 + 1 >= 0 && x0 + 1 < W) v += wy0 * wx1 * r[x0 + 1];
            }
            if (y0 + 1 >= 0 && y0 + 1 < H) {
                const float* r = pl + (y0 + 1) * W;
                if (x0 >= 0 && x0 < W)         v += wy1 * wx0 * r[x0];
                if (x0 + 1 >= 0 && x0 + 1 < W) v += wy1 * wx1 * r[x0 + 1];
            }
            smp[i] = v * mk;
        }
        __syncthreads();
        for (int ci = 0; ci < CC; ++ci) {
#pragma unroll
            for (int k = 0; k < 9; ++k) {
                const float wvv = wT[((size_t)(c0 + ci) * 9 + k) * O + o];
                const float4* sp = (const float4*)(smp + (ci * 9 + k) * T);
#pragma unroll
                for (int q = 0; q < T / 4; ++q) {
                    const float4 s = sp[q];
                    acc[q * 4 + 0] += wvv * s.x;
                    acc[q * 4 + 1] += wvv * s.y;
                    acc[q * 4 + 2] += wvv * s.z;
                    acc[q * 4 + 3] += wvv * s.w;
                }
            }
        }
    }
    const float bv = bias[o];
    OT* op = out + (size_t)(b * O + o) * HW + p0;
#pragma unroll
    for (int t = 0; t < T; ++t) ST(op + t, acc[t] + bv);
}

// ---------------- offset_sum ----------------
__global__ void zero1_kernel(float* __restrict__ out) { if (threadIdx.x == 0) out[0] = 0.f; }

__global__ __launch_bounds__(256) void offsum_one(const float* __restrict__ om, int HW,
                                                  float* __restrict__ out)
{
    __shared__ double sh[256];
    const int n = 8 * 18 * HW;
    double s = 0.0;
    for (int i = blockIdx.x * 256 + threadIdx.x; i < n; i += gridDim.x * 256) {
        const int b = i / (18 * HW); const int r = i - b * 18 * HW;
        const int c = r / HW; const int p = r - c * HW;
        s += fabs((double)om[(size_t)(b * 27 + c) * HW + p]);
    }
    sh[threadIdx.x] = s;
    __syncthreads();
    for (int st = 128; st > 0; st >>= 1) {
        if (threadIdx.x < st) sh[threadIdx.x] += sh[threadIdx.x + st];
        __syncthreads();
    }
    if (threadIdx.x == 0) atomicAdd(out, (float)(0.5 * sh[0] / n));
}

// ---------------- launch ----------------
extern "C" void kernel_launch(void* const* d_in, const int* in_sizes, int n_in,
                              void* d_out, int out_size, void* d_ws, size_t ws_size,
                              hipStream_t stream)
{
    if (n_in < 27) return;
    if (out_size < 393217) return;
    if (in_sizes[0] != 8 * 256 * 32 * 32) return;
    if (in_sizes[1] != 8 * 128 * 64 * 64) return;
    if (in_sizes[2] != 8 * 256 * 32 * 32) return;
    if (in_sizes[25] != 128 * 128 * 9) return;
    if (in_sizes[26] != 128) return;

    const float* x        = (const float*)d_in[0];
    const float* skip1    = (const float*)d_in[1];
    const float* skip2    = (const float*)d_in[2];
    const float* rbw[2][2] = {{(const float*)d_in[3], (const float*)d_in[5]},
                              {(const float*)d_in[7], (const float*)d_in[9]}};
    const float* rbb[2][2] = {{(const float*)d_in[4], (const float*)d_in[6]},
                              {(const float*)d_in[8], (const float*)d_in[10]}};
    const float* conv1_w = (const float*)d_in[11]; const float* conv1_b = (const float*)d_in[12];
    const float* conv3_w = (const float*)d_in[13]; const float* conv3_b = (const float*)d_in[14];
    const float* conv5_w = (const float*)d_in[15]; const float* conv5_b = (const float*)d_in[16];
    const float* conv6_w = (const float*)d_in[17]; const float* conv6_b = (const float*)d_in[18];
    const float* dcn2_off_w = (const float*)d_in[19]; const float* dcn2_off_b = (const float*)d_in[20];
    const float* dcn2_w = (const float*)d_in[21]; const float* dcn2_b = (const float*)d_in[22];
    const float* dcn1_off_w = (const float*)d_in[23]; const float* dcn1_off_b = (const float*)d_in[24];
    const float* dcn1_w = (const float*)d_in[25]; const float* dcn1_b = (const float*)d_in[26];

    float* outp = (float*)d_out;

    const size_t NEED_F32 = 9494528ull;      // unchanged, proven R8-R12
    if (ws_size < NEED_F32 * 4ull) return;

    float* ws = (float*)d_ws;
    const size_t NA = 2097152ull;            // 8*256*32*32
    float* A   = ws;                          // x / rb accum / pre2 ; later Ib
    float* Bb  = ws + NA;                     // h / D ; later wT1 ; later Jb(lo half)
    float* Tmp = ws + 2 * NA;                 // rb tmp ; {wT2,wo2} ; wt3 ; wo1 ; Jb(hi half)
    float* om2 = ws + 3 * NA;                 // [221184] ; after offsum: conv6 wt
    float* om1 = om2 + 221184;                // [884736] ; later conv5 wt
    bf16*  Fb  = (bf16*)(om1 + 884736);       // c3 bf16 ; BEFORE conv3: early MFMA weights
    bf16*  Ib  = (bf16*)A;                    // pre1 bf16
    bf16*  Jb  = (bf16*)Bb;                   // c5 bf16 (Bb+Tmp)
    float* wT2 = Tmp;                         // mdcn2 transposed weights (589824 f32)
    u16*   wo2h = (u16*)(Tmp + 589824);       // dcn2 off-conv MFMA w hi (124416 u16)
    u16*   wo2l = wo2h + 124416;
    u16*   wt3h = (u16*)Tmp;                  // conv3 MFMA w (after mdcn2)
    u16*   wt3l = wt3h + 25 * 128 * 512;
    u16*   wo1h = (u16*)Tmp;                  // dcn1 off-conv MFMA w (after conv3)
    u16*   wo1l = wo1h + 62208;
    float* wT1 = Bb;                          // mdcn1 transposed weights (after conv3)
    u16*   wt5h = (u16*)om1;                  // conv5 MFMA w (after offsum)
    u16*   wt5l = wt5h + 25 * 64 * 256;
    u16*   wt6h = (u16*)om2;                  // conv6 MFMA w (om2 dead after offsum; 9408 x2 u16)
    u16*   wt6l = wt6h + 9408;
    u16*   wEh = (u16*)Fb;                    // early conv MFMA weights (Fb free until conv3)

    copy_kernel<<<8192, 256, 0, stream>>>(x, A, (int)NA);

    // ResBlocks via MFMA (A+W hi/lo split -> ~f32 precision)
    for (int r = 0; r < 2; ++r) {
        wsplit_kernel<<<2304, 256, 0, stream>>>(rbw[r][0], wEh, wEh + 589824, 256, 256, 9);
        conv_mfma<float, float, 3, true, false, 4, 0, true><<<dim3(16, 8, 4), 256, 0, stream>>>(
            A, (const float*)nullptr, 256, 256, wEh, wEh + 589824, rbb[r][0], Bb, 256, 32, 32);
        inorm_kernel<float><<<2048, 256, 0, stream>>>(Bb, nullptr, 1024, 0);
        wsplit_kernel<<<2304, 256, 0, stream>>>(rbw[r][1], wEh, wEh + 589824, 256, 256, 9);
        conv_mfma<float, float, 3, true, false, 4, 0, true><<<dim3(16, 8, 4), 256, 0, stream>>>(
            Bb, (const float*)nullptr, 256, 256, wEh, wEh + 589824, rbb[r][1], Tmp, 256, 32, 32);
        inorm_kernel<float><<<2048, 256, 0, stream>>>(Tmp, A, 1024, 1);
    }

    // conv1 (5x5, 256->256) via MFMA + IN/ReLU
    wsplit_kernel<<<6400, 256, 0, stream>>>(conv1_w, wEh, wEh + 1638400, 256, 256, 25);
    conv_mfma<float, float, 5, true, false, 4, 0, true><<<dim3(16, 8, 4), 256, 0, stream>>>(
        A, (const float*)nullptr, 256, 256, wEh, wEh + 1638400, conv1_b, Bb, 256, 32, 32);
    inorm_kernel<float><<<2048, 256, 0, stream>>>(Bb, nullptr, 1024, 0);

    // dcn2 off-conv: MFMA (zero-pad, K=3, O=27 in 2 N-tiles) -> om2
    wsplit_kernel<<<486, 256, 0, stream>>>(dcn2_off_w, wo2h, wo2l, 27, 512, 9);
    conv_mfma<float, float, 3, false, false, 2, 0, false><<<dim3(16, 8, 1), 256, 0, stream>>>(
        Bb, skip2, 256, 512, wo2h, wo2l, dcn2_off_b, om2, 27, 32, 32);
    wtrans_kernel<<<2304, 256, 0, stream>>>(dcn2_w, wT2, 256, 256);
    mdcn_lds<256, 8, 32, float><<<dim3(128, 8), 256, 0, stream>>>(
        skip2, om2, wT2, dcn2_b, A, 256, 256, 32, 32);

    // conv3: MFMA implicit GEMM, 512->128 @64x64 -> Fb + IN/ReLU
    wsplit_kernel<<<6400, 256, 0, stream>>>(conv3_w, wt3h, wt3l, 128, 512, 25);
    conv_mfma<float, float, 5, true, true, 4, 2, false><<<dim3(64, 8, 2), 256, 0, stream>>>(
        A, Bb, 256, 512, wt3h, wt3l, conv3_b, Fb, 128, 64, 64);
    inorm_kernel<bf16><<<1024, 256, 0, stream>>>(Fb, nullptr, 4096, 0);

    // dcn1 off-conv: MFMA -> om1
    wsplit_kernel<<<243, 256, 0, stream>>>(dcn1_off_w, wo1h, wo1l, 27, 256, 9);
    conv_mfma<bf16, float, 3, false, false, 2, 0, false><<<dim3(64, 8, 1), 256, 0, stream>>>(
        Fb, skip1, 128, 256, wo1h, wo1l, dcn1_off_b, om1, 27, 64, 64);
    wtrans_kernel<<<576, 256, 0, stream>>>(dcn1_w, wT1, 128, 128);
    mdcn_lds<128, 16, 32, bf16><<<dim3(256, 8), 128, 0, stream>>>(
        skip1, om1, wT1, dcn1_b, Ib, 128, 128, 64, 64);

    // offset_sum now (frees om1/om2 regions for conv5/conv6 weights)
    zero1_kernel<<<1, 64, 0, stream>>>(outp + 393216);
    offsum_one<<<64, 256, 0, stream>>>(om1, 4096, outp + 393216);
    offsum_one<<<64, 256, 0, stream>>>(om2, 1024, outp + 393216);

    // conv5: MFMA implicit GEMM, 256->64 @128x128 -> Jb + IN/ReLU
    wsplit_kernel<<<1600, 256, 0, stream>>>(conv5_w, wt5h, wt5l, 64, 256, 25);
    conv_mfma<bf16, bf16, 5, true, true, 4, 2, false><<<dim3(256, 8, 1), 256, 0, stream>>>(
        Ib, Fb, 128, 256, wt5h, wt5l, conv5_b, Jb, 64, 128, 128);
    inorm_kernel<bf16><<<512, 256, 0, stream>>>(Jb, nullptr, 16384, 0);

    // conv6: 7x7, 64->3, tanh via MFMA -> d_out (f32)
    wsplit_kernel<<<37, 256, 0, stream>>>(conv6_w, wt6h, wt6l, 3, 64, 49);
    conv_mfma<bf16, float, 7, true, false, 1, 1, false><<<dim3(256, 8, 1), 256, 0, stream>>>(
        Jb, (const float*)nullptr, 64, 64, wt6h, wt6l, conv6_b, (void*)outp, 3, 128, 128);
}

// Round 14
// 2559.759 us; speedup vs baseline: 23.2868x; 1.1919x over previous
//
#include <hip/hip_runtime.h>
#include <hip/hip_bf16.h>
#include <math.h>

typedef __hip_bfloat16 bf16;
typedef unsigned short u16;
typedef __attribute__((ext_vector_type(8))) short short8;   // 8 bf16 (4 VGPRs)
typedef __attribute__((ext_vector_type(4))) float f32x4;

__device__ __forceinline__ float LD(const float* p) { return *p; }
__device__ __forceinline__ float LD(const bf16* p)  { return __bfloat162float(*p); }
__device__ __forceinline__ void  ST(float* p, float v) { *p = v; }
__device__ __forceinline__ void  ST(bf16* p, float v)  { *p = __float2bfloat16(v); }
__device__ __forceinline__ u16   f2b(float v) { bf16 h = __float2bfloat16(v); return *reinterpret_cast<u16*>(&h); }
__device__ __forceinline__ float b2fu(u16 u) { bf16 h = *reinterpret_cast<bf16*>(&u); return __bfloat162float(h); }

// ---------------- f32 copy ----------------
__global__ __launch_bounds__(256) void copy_kernel(const float* __restrict__ in,
                                                   float* __restrict__ out, int n) {
    int i = blockIdx.x * blockDim.x + threadIdx.x;
    if (i < n) out[i] = in[i];
}

// ---------------- weight split+transpose for MFMA: w[o][c][t] f32 -> hi/lo [t][o][c] bf16 ----
__global__ __launch_bounds__(256) void wsplit_kernel(const float* __restrict__ w,
                                                     u16* __restrict__ hi, u16* __restrict__ lo,
                                                     int O, int C, int KK)
{
    const int i = blockIdx.x * 256 + threadIdx.x;
    const int n = O * C * KK;
    if (i >= n) return;
    const int o = i / (C * KK);
    const int r = i - o * C * KK;
    const int c = r / KK;
    const int t = r - c * KK;
    const float v = w[i];
    const bf16 h = __float2bfloat16(v);
    const float hv = __bfloat162float(h);
    const bf16 l = __float2bfloat16(v - hv);
    const size_t dst = ((size_t)t * O + o) * C + c;
    hi[dst] = *(const u16*)&h;
    lo[dst] = *(const u16*)&l;
}

// ---------------- MFMA implicit-GEMM conv (generalized) ----------------
// block: 256 thr = 4 waves; M=64 pixels x N=NTN*16 out-channels (obase=z*NTN*16).
// Loop: C-chunks(32) OUTER, taps t INNER -> A-tile stays L1-hot across taps.
// LDS col-block XOR swizzle (^ (row>>3)&3) -> 2-way max bank aliasing (free).
// W hi/lo split -> 2 MFMAs. ASPLIT: A also split -> +1 MFMA => ~f32 precision.
// EPI: 0=f32, 1=tanh->f32, 2=bf16
template<typename T1, typename T2, int K, bool REFLECT, bool UP, int NTN, int EPI, bool ASPLIT>
__global__ __launch_bounds__(256) void conv_mfma(
        const T1* __restrict__ src1, const T2* __restrict__ src2,
        int C1, int C,
        const u16* __restrict__ wth, const u16* __restrict__ wtl,
        const float* __restrict__ bias,
        void* __restrict__ outv, int O, int H, int W)
{
    constexpr int KK = K * K;
    __shared__ __align__(16) u16 As[64 * 40];
    __shared__ __align__(16) u16 Alo[ASPLIT ? 64 * 40 : 8];
    __shared__ __align__(16) u16 Bh[NTN * 16 * 40];
    __shared__ __align__(16) u16 Bl[NTN * 16 * 40];

    const int tid  = threadIdx.x;
    const int wv   = tid >> 6;          // wave 0..3
    const int lane = tid & 63;
    const int ln15 = lane & 15;
    const int b    = blockIdx.y;
    const int p0   = blockIdx.x * 64;
    const int obase = blockIdx.z * (NTN * 16);
    const int HW = H * W;
    const int Hs = UP ? (H >> 1) : H;
    const int Ws = UP ? (W >> 1) : W;
    const int HsWs = Hs * Ws;
    const int PAD = K / 2;
    const int C2 = C - C1;

    const int m_stage = tid & 63;       // staging pixel = lane

    const int p = p0 + m_stage;
    const int y = p / W, x = p - y * W;
    int off[KK];
    float msk[KK];
#pragma unroll
    for (int ty = 0; ty < K; ++ty) {
#pragma unroll
        for (int tx = 0; tx < K; ++tx) {
            int yy = y + ty - PAD, xx = x + tx - PAD;
            bool vv = true;
            if (REFLECT) {
                yy = yy < 0 ? -yy : yy; yy = yy >= H ? 2 * H - 2 - yy : yy;
                xx = xx < 0 ? -xx : xx; xx = xx >= W ? 2 * W - 2 - xx : xx;
            } else {
                vv = (yy >= 0 && yy < H && xx >= 0 && xx < W);
                yy = yy < 0 ? 0 : (yy >= H ? H - 1 : yy);
                xx = xx < 0 ? 0 : (xx >= W ? W - 1 : xx);
            }
            off[ty * K + tx] = (UP ? (yy >> 1) : yy) * Ws + (UP ? (xx >> 1) : xx);
            msk[ty * K + tx] = vv ? 1.f : 0.f;
        }
    }

    f32x4 acc[NTN];
#pragma unroll
    for (int nt = 0; nt < NTN; ++nt) acc[nt] = (f32x4)0.f;

    // LDS addressing (swizzled col-blocks)
    const int aswz = (m_stage >> 3) & 3;                       // staging row swizzle
    const int awr  = m_stage * 40 + ((wv ^ aswz) << 3);        // A stage write addr
    const int arow = wv * 16 + ln15;
    const int ard  = arow * 40 + (((lane >> 4) ^ ((arow >> 3) & 3)) << 3);  // A read addr

    const int nch = C >> 5;
    for (int cc = 0; cc < nch; ++cc) {
        const int c0 = cc << 5;
        for (int t = 0; t < KK; ++t) {
            const int offt = off[t];
            const float mskt = msk[t];
            __syncthreads();
            // stage A: wave wv handles 8-channel block wv; one short8 write per thread
            {
                short8 avh, avl;
#pragma unroll
                for (int q = 0; q < 8; ++q) {
                    const int c = c0 + (wv << 3) + q;
                    float v;
                    if (c < C1) v = LD(src1 + ((size_t)(b * C1 + c)) * HsWs + offt);
                    else        v = LD(src2 + ((size_t)(b * C2 + (c - C1))) * HsWs + offt);
                    if (!REFLECT) v *= mskt;
                    const u16 hv = f2b(v);
                    avh[q] = (short)hv;
                    if (ASPLIT) avl[q] = (short)f2b(v - b2fu(hv));
                }
                *(short8*)&As[awr] = avh;
                if (ASPLIT) *(short8*)&Alo[awr] = avl;
            }
            // stage B: rows = NTN*16 out-chans, 4 col-parts (swizzled)
            for (int i = tid; i < NTN * 16 * 4; i += 256) {
                const int row = i >> 2, part = i & 3;
                int o = obase + row; if (o >= O) o = O - 1;
                const int pw = row * 40 + ((part ^ ((row >> 3) & 3)) << 3);
                const size_t wb = ((size_t)t * O + o) * C + c0 + (part << 3);
                *(short8*)&Bh[pw] = *(const short8*)(wth + wb);
                *(short8*)&Bl[pw] = *(const short8*)(wtl + wb);
            }
            __syncthreads();
            const short8 a = *(const short8*)&As[ard];
            short8 al;
            if (ASPLIT) al = *(const short8*)&Alo[ard];
#pragma unroll
            for (int nt = 0; nt < NTN; ++nt) {
                const int brow = nt * 16 + ln15;
                const int brd = brow * 40 + (((lane >> 4) ^ ((brow >> 3) & 3)) << 3);
                const short8 bh = *(const short8*)&Bh[brd];
                acc[nt] = __builtin_amdgcn_mfma_f32_16x16x32_bf16(a, bh, acc[nt], 0, 0, 0);
                const short8 bl = *(const short8*)&Bl[brd];
                acc[nt] = __builtin_amdgcn_mfma_f32_16x16x32_bf16(a, bl, acc[nt], 0, 0, 0);
                if (ASPLIT)
                    acc[nt] = __builtin_amdgcn_mfma_f32_16x16x32_bf16(al, bh, acc[nt], 0, 0, 0);
            }
        }
    }

    // epilogue: D col=lane&15 -> o, row=(lane>>4)*4+r -> pixel
#pragma unroll
    for (int nt = 0; nt < NTN; ++nt) {
        const int o = obase + nt * 16 + ln15;
        if (o < O) {
            const float bv = bias[o];
#pragma unroll
            for (int r = 0; r < 4; ++r) {
                const int pp = p0 + wv * 16 + ((lane >> 4) << 2) + r;
                const float v = acc[nt][r] + bv;
                const size_t oidx = ((size_t)(b * O + o)) * HW + pp;
                if (EPI == 0)      ((float*)outv)[oidx] = v;
                else if (EPI == 1) ((float*)outv)[oidx] = tanhf(v);
                else               ((bf16*)outv)[oidx] = __float2bfloat16(v);
            }
        }
    }
}

// ---------------- instance norm ----------------
template<typename T>
__global__ __launch_bounds__(256) void inorm_kernel(T* __restrict__ buf,
                                                    float* __restrict__ resid,
                                                    int HW, int mode)
{
    __shared__ double sh0[256], sh1[256];
    const int pl = blockIdx.x;
    T* p = buf + (size_t)pl * HW;
    double s = 0.0, ss = 0.0;
    for (int i = threadIdx.x; i < HW; i += 256) {
        float v = LD(p + i);
        s += (double)v; ss += (double)v * (double)v;
    }
    sh0[threadIdx.x] = s; sh1[threadIdx.x] = ss;
    __syncthreads();
    for (int st = 128; st > 0; st >>= 1) {
        if (threadIdx.x < st) {
            sh0[threadIdx.x] += sh0[threadIdx.x + st];
            sh1[threadIdx.x] += sh1[threadIdx.x + st];
        }
        __syncthreads();
    }
    const double mean = sh0[0] / HW;
    const float m = (float)mean;
    const float var = (float)(sh1[0] / HW - mean * mean);
    const float inv = rsqrtf(var + 1e-5f);
    if (mode == 0) {
        for (int i = threadIdx.x; i < HW; i += 256) {
            float v = (LD(p + i) - m) * inv;
            ST(p + i, v > 0.f ? v : 0.f);
        }
    } else {
        float* r = resid + (size_t)pl * HW;
        for (int i = threadIdx.x; i < HW; i += 256)
            r[i] = r[i] + (LD(p + i) - m) * inv;
    }
}

// ---------------- weight transpose for mdcn: w[o][c][k] -> wT[c*9+k][o] ----------------
__global__ __launch_bounds__(256) void wtrans_kernel(const float* __restrict__ w,
                                                     float* __restrict__ wT, int C, int O)
{
    const int i = blockIdx.x * 256 + threadIdx.x;
    const int n = O * C * 9;
    if (i >= n) return;
    const int o = i / (C * 9);
    const int r = i - o * C * 9;
    wT[(size_t)r * O + o] = w[i];
}

// ---------------- modulated deformable conv, cooperative LDS ----------------
template<int NT, int T, int CC, typename OT>
__global__ __launch_bounds__(256) void mdcn_lds(
        const float* __restrict__ skip, const float* __restrict__ om,
        const float* __restrict__ wT, const float* __restrict__ bias,
        OT* __restrict__ out, int C, int O, int H, int W)
{
    __shared__ __align__(16) float smp[CC * 9 * T];
    __shared__ float tpy[9 * T], tpx[9 * T], tm[9 * T];
    const int b = blockIdx.y;
    const int p0 = blockIdx.x * T;
    const int tid = threadIdx.x;
    const int HW = H * W;
    const float* omb = om + (size_t)b * 27 * HW;
    for (int i = tid; i < 9 * T; i += NT) {
        const int k = i / T, t = i - k * T;
        const int p = p0 + t;
        const int y = p / W, x = p - y * W;
        const float dy = omb[(2 * k) * HW + p];
        const float dx = omb[(2 * k + 1) * HW + p];
        const float mk = 1.f / (1.f + expf(-omb[(18 + k) * HW + p]));
        float py = (float)(y + k / 3 - 1) + dy;
        float pxx = (float)(x + k % 3 - 1) + dx;
        py  = fminf(fmaxf(py, -2.f), (float)H + 1.f);
        pxx = fminf(fmaxf(pxx, -2.f), (float)W + 1.f);
        tpy[i] = py; tpx[i] = pxx; tm[i] = mk;
    }

    float acc[T];
#pragma unroll
    for (int t = 0; t < T; ++t) acc[t] = 0.f;
    const int o = tid;
    const float* xb = skip + (size_t)b * C * HW;

    for (int c0 = 0; c0 < C; c0 += CC) {
        __syncthreads();
        for (int i = tid; i < CC * 9 * T; i += NT) {
            const int t = i % T;
            const int kk = (i / T) % 9;
            const int ci = i / (9 * T);
            const int ti = kk * T + t;
            const float py = tpy[ti], pxx = tpx[ti], mk = tm[ti];
            const float y0f = floorf(py), x0f = floorf(pxx);
            const int y0 = (int)y0f, x0 = (int)x0f;
            const float wy1 = py - y0f, wx1 = pxx - x0f;
            const float wy0 = 1.f - wy1, wx0 = 1.f - wx1;
            const float* pl = xb + (size_t)(c0 + ci) * HW;
            float v = 0.f;
            if (y0 >= 0 && y0 < H) {
                const float* r = pl + y0 * W;
                if (x0 >= 0 && x0 < W)         v += wy0 * wx0 * r[x0];
                if (x0 + 1 >= 0 && x0 + 1 < W) v += wy0 * wx1 * r[x0 + 1];
            }
            if (y0 + 1 >= 0 && y0 + 1 < H) {
                const float* r = pl + (y0 + 1) * W;
                if (x0 >= 0 && x0 < W)         v += wy1 * wx0 * r[x0];
                if (x0 + 1 >= 0 && x0 + 1 < W) v += wy1 * wx1 * r[x0 + 1];
            }
            smp[i] = v * mk;
        }
        __syncthreads();
        for (int ci = 0; ci < CC; ++ci) {
#pragma unroll
            for (int k = 0; k < 9; ++k) {
                const float wvv = wT[((size_t)(c0 + ci) * 9 + k) * O + o];
                const float4* sp = (const float4*)(smp + (ci * 9 + k) * T);
#pragma unroll
                for (int q = 0; q < T / 4; ++q) {
                    const float4 s = sp[q];
                    acc[q * 4 + 0] += wvv * s.x;
                    acc[q * 4 + 1] += wvv * s.y;
                    acc[q * 4 + 2] += wvv * s.z;
                    acc[q * 4 + 3] += wvv * s.w;
                }
            }
        }
    }
    const float bv = bias[o];
    OT* op = out + (size_t)(b * O + o) * HW + p0;
#pragma unroll
    for (int t = 0; t < T; ++t) ST(op + t, acc[t] + bv);
}

// ---------------- offset_sum ----------------
__global__ void zero1_kernel(float* __restrict__ out) { if (threadIdx.x == 0) out[0] = 0.f; }

__global__ __launch_bounds__(256) void offsum_one(const float* __restrict__ om, int HW,
                                                  float* __restrict__ out)
{
    __shared__ double sh[256];
    const int n = 8 * 18 * HW;
    double s = 0.0;
    for (int i = blockIdx.x * 256 + threadIdx.x; i < n; i += gridDim.x * 256) {
        const int b = i / (18 * HW); const int r = i - b * 18 * HW;
        const int c = r / HW; const int p = r - c * HW;
        s += fabs((double)om[(size_t)(b * 27 + c) * HW + p]);
    }
    sh[threadIdx.x] = s;
    __syncthreads();
    for (int st = 128; st > 0; st >>= 1) {
        if (threadIdx.x < st) sh[threadIdx.x] += sh[threadIdx.x + st];
        __syncthreads();
    }
    if (threadIdx.x == 0) atomicAdd(out, (float)(0.5 * sh[0] / n));
}

// ---------------- launch ----------------
extern "C" void kernel_launch(void* const* d_in, const int* in_sizes, int n_in,
                              void* d_out, int out_size, void* d_ws, size_t ws_size,
                              hipStream_t stream)
{
    if (n_in < 27) return;
    if (out_size < 393217) return;
    if (in_sizes[0] != 8 * 256 * 32 * 32) return;
    if (in_sizes[1] != 8 * 128 * 64 * 64) return;
    if (in_sizes[2] != 8 * 256 * 32 * 32) return;
    if (in_sizes[25] != 128 * 128 * 9) return;
    if (in_sizes[26] != 128) return;

    const float* x        = (const float*)d_in[0];
    const float* skip1    = (const float*)d_in[1];
    const float* skip2    = (const float*)d_in[2];
    const float* rbw[2][2] = {{(const float*)d_in[3], (const float*)d_in[5]},
                              {(const float*)d_in[7], (const float*)d_in[9]}};
    const float* rbb[2][2] = {{(const float*)d_in[4], (const float*)d_in[6]},
                              {(const float*)d_in[8], (const float*)d_in[10]}};
    const float* conv1_w = (const float*)d_in[11]; const float* conv1_b = (const float*)d_in[12];
    const float* conv3_w = (const float*)d_in[13]; const float* conv3_b = (const float*)d_in[14];
    const float* conv5_w = (const float*)d_in[15]; const float* conv5_b = (const float*)d_in[16];
    const float* conv6_w = (const float*)d_in[17]; const float* conv6_b = (const float*)d_in[18];
    const float* dcn2_off_w = (const float*)d_in[19]; const float* dcn2_off_b = (const float*)d_in[20];
    const float* dcn2_w = (const float*)d_in[21]; const float* dcn2_b = (const float*)d_in[22];
    const float* dcn1_off_w = (const float*)d_in[23]; const float* dcn1_off_b = (const float*)d_in[24];
    const float* dcn1_w = (const float*)d_in[25]; const float* dcn1_b = (const float*)d_in[26];

    float* outp = (float*)d_out;

    const size_t NEED_F32 = 9494528ull;      // unchanged, proven R8-R13
    if (ws_size < NEED_F32 * 4ull) return;

    float* ws = (float*)d_ws;
    const size_t NA = 2097152ull;            // 8*256*32*32
    float* A   = ws;                          // x / rb accum / pre2 ; later Ib
    float* Bb  = ws + NA;                     // h / D ; later wT1 ; later Jb(lo half)
    float* Tmp = ws + 2 * NA;                 // rb tmp ; {wT2,wo2} ; wt3 ; wo1 ; Jb(hi half)
    float* om2 = ws + 3 * NA;                 // [221184] ; after offsum: conv6 wt
    float* om1 = om2 + 221184;                // [884736] ; later conv5 wt
    bf16*  Fb  = (bf16*)(om1 + 884736);       // c3 bf16 ; BEFORE conv3: early MFMA weights
    bf16*  Ib  = (bf16*)A;                    // pre1 bf16
    bf16*  Jb  = (bf16*)Bb;                   // c5 bf16 (Bb+Tmp)
    float* wT2 = Tmp;                         // mdcn2 transposed weights (589824 f32)
    u16*   wo2h = (u16*)(Tmp + 589824);       // dcn2 off-conv MFMA w hi (124416 u16)
    u16*   wo2l = wo2h + 124416;
    u16*   wt3h = (u16*)Tmp;                  // conv3 MFMA w (after mdcn2)
    u16*   wt3l = wt3h + 25 * 128 * 512;
    u16*   wo1h = (u16*)Tmp;                  // dcn1 off-conv MFMA w (after conv3)
    u16*   wo1l = wo1h + 62208;
    float* wT1 = Bb;                          // mdcn1 transposed weights (after conv3)
    u16*   wt5h = (u16*)om1;                  // conv5 MFMA w (after offsum)
    u16*   wt5l = wt5h + 25 * 64 * 256;
    u16*   wt6h = (u16*)om2;                  // conv6 MFMA w (om2 dead after offsum)
    u16*   wt6l = wt6h + 9408;
    u16*   wEh = (u16*)Fb;                    // early conv MFMA weights (Fb free until conv3)

    copy_kernel<<<8192, 256, 0, stream>>>(x, A, (int)NA);

    // ResBlocks via MFMA (A+W hi/lo split -> ~f32 precision)
    for (int r = 0; r < 2; ++r) {
        wsplit_kernel<<<2304, 256, 0, stream>>>(rbw[r][0], wEh, wEh + 589824, 256, 256, 9);
        conv_mfma<float, float, 3, true, false, 4, 0, true><<<dim3(16, 8, 4), 256, 0, stream>>>(
            A, (const float*)nullptr, 256, 256, wEh, wEh + 589824, rbb[r][0], Bb, 256, 32, 32);
        inorm_kernel<float><<<2048, 256, 0, stream>>>(Bb, nullptr, 1024, 0);
        wsplit_kernel<<<2304, 256, 0, stream>>>(rbw[r][1], wEh, wEh + 589824, 256, 256, 9);
        conv_mfma<float, float, 3, true, false, 4, 0, true><<<dim3(16, 8, 4), 256, 0, stream>>>(
            Bb, (const float*)nullptr, 256, 256, wEh, wEh + 589824, rbb[r][1], Tmp, 256, 32, 32);
        inorm_kernel<float><<<2048, 256, 0, stream>>>(Tmp, A, 1024, 1);
    }

    // conv1 (5x5, 256->256) via MFMA + IN/ReLU
    wsplit_kernel<<<6400, 256, 0, stream>>>(conv1_w, wEh, wEh + 1638400, 256, 256, 25);
    conv_mfma<float, float, 5, true, false, 4, 0, true><<<dim3(16, 8, 4), 256, 0, stream>>>(
        A, (const float*)nullptr, 256, 256, wEh, wEh + 1638400, conv1_b, Bb, 256, 32, 32);
    inorm_kernel<float><<<2048, 256, 0, stream>>>(Bb, nullptr, 1024, 0);

    // dcn2 off-conv: MFMA (zero-pad, K=3, O=27 in 2 N-tiles) -> om2
    wsplit_kernel<<<486, 256, 0, stream>>>(dcn2_off_w, wo2h, wo2l, 27, 512, 9);
    conv_mfma<float, float, 3, false, false, 2, 0, false><<<dim3(16, 8, 1), 256, 0, stream>>>(
        Bb, skip2, 256, 512, wo2h, wo2l, dcn2_off_b, om2, 27, 32, 32);
    wtrans_kernel<<<2304, 256, 0, stream>>>(dcn2_w, wT2, 256, 256);
    mdcn_lds<256, 8, 32, float><<<dim3(128, 8), 256, 0, stream>>>(
        skip2, om2, wT2, dcn2_b, A, 256, 256, 32, 32);

    // conv3: MFMA implicit GEMM, 512->128 @64x64 -> Fb + IN/ReLU
    wsplit_kernel<<<6400, 256, 0, stream>>>(conv3_w, wt3h, wt3l, 128, 512, 25);
    conv_mfma<float, float, 5, true, true, 4, 2, false><<<dim3(64, 8, 2), 256, 0, stream>>>(
        A, Bb, 256, 512, wt3h, wt3l, conv3_b, Fb, 128, 64, 64);
    inorm_kernel<bf16><<<1024, 256, 0, stream>>>(Fb, nullptr, 4096, 0);

    // dcn1 off-conv: MFMA -> om1
    wsplit_kernel<<<243, 256, 0, stream>>>(dcn1_off_w, wo1h, wo1l, 27, 256, 9);
    conv_mfma<bf16, float, 3, false, false, 2, 0, false><<<dim3(64, 8, 1), 256, 0, stream>>>(
        Fb, skip1, 128, 256, wo1h, wo1l, dcn1_off_b, om1, 27, 64, 64);
    wtrans_kernel<<<576, 256, 0, stream>>>(dcn1_w, wT1, 128, 128);
    mdcn_lds<128, 16, 32, bf16><<<dim3(256, 8), 128, 0, stream>>>(
        skip1, om1, wT1, dcn1_b, Ib, 128, 128, 64, 64);

    // offset_sum now (frees om1/om2 regions for conv5/conv6 weights)
    zero1_kernel<<<1, 64, 0, stream>>>(outp + 393216);
    offsum_one<<<64, 256, 0, stream>>>(om1, 4096, outp + 393216);
    offsum_one<<<64, 256, 0, stream>>>(om2, 1024, outp + 393216);

    // conv5: MFMA implicit GEMM, 256->64 @128x128 -> Jb + IN/ReLU
    wsplit_kernel<<<1600, 256, 0, stream>>>(conv5_w, wt5h, wt5l, 64, 256, 25);
    conv_mfma<bf16, bf16, 5, true, true, 4, 2, false><<<dim3(256, 8, 1), 256, 0, stream>>>(
        Ib, Fb, 128, 256, wt5h, wt5l, conv5_b, Jb, 64, 128, 128);
    inorm_kernel<bf16><<<512, 256, 0, stream>>>(Jb, nullptr, 16384, 0);

    // conv6: 7x7, 64->3, tanh via MFMA -> d_out (f32)
    wsplit_kernel<<<37, 256, 0, stream>>>(conv6_w, wt6h, wt6l, 3, 64, 49);
    conv_mfma<bf16, float, 7, true, false, 1, 1, false><<<dim3(256, 8, 1), 256, 0, stream>>>(
        Jb, (const float*)nullptr, 64, 64, wt6h, wt6l, conv6_b, (void*)outp, 3, 128, 128);
}

// Round 15
// 1979.832 us; speedup vs baseline: 30.1079x; 1.2929x over previous
//
#include <hip/hip_runtime.h>
#include <hip/hip_bf16.h>
#include <math.h>

typedef __hip_bfloat16 bf16;
typedef unsigned short u16;
typedef __attribute__((ext_vector_type(8))) short short8;   // 8 bf16 (4 VGPRs)
typedef __attribute__((ext_vector_type(4))) float f32x4;

__device__ __forceinline__ float LD(const float* p) { return *p; }
__device__ __forceinline__ float LD(const bf16* p)  { return __bfloat162float(*p); }
__device__ __forceinline__ void  ST(float* p, float v) { *p = v; }
__device__ __forceinline__ void  ST(bf16* p, float v)  { *p = __float2bfloat16(v); }
__device__ __forceinline__ u16   f2b(float v) { bf16 h = __float2bfloat16(v); return *reinterpret_cast<u16*>(&h); }
__device__ __forceinline__ float b2fu(u16 u) { bf16 h = *reinterpret_cast<bf16*>(&u); return __bfloat162float(h); }

// ---------------- f32 copy ----------------
__global__ __launch_bounds__(256) void copy_kernel(const float* __restrict__ in,
                                                   float* __restrict__ out, int n) {
    int i = blockIdx.x * blockDim.x + threadIdx.x;
    if (i < n) out[i] = in[i];
}

// ---- wsplit (old layout [t][o][c], for off-convs + conv6) ----
__global__ __launch_bounds__(256) void wsplit_kernel(const float* __restrict__ w,
                                                     u16* __restrict__ hi, u16* __restrict__ lo,
                                                     int O, int C, int KK)
{
    const int i = blockIdx.x * 256 + threadIdx.x;
    const int n = O * C * KK;
    if (i >= n) return;
    const int o = i / (C * KK);
    const int r = i - o * C * KK;
    const int c = r / KK;
    const int t = r - c * KK;
    const float v = w[i];
    const bf16 h = __float2bfloat16(v);
    const float hv = __bfloat162float(h);
    const bf16 l = __float2bfloat16(v - hv);
    const size_t dst = ((size_t)t * O + o) * C + c;
    hi[dst] = *(const u16*)&h;
    lo[dst] = *(const u16*)&l;
}

// ---- wsplit2: layout [t][cc][quad][O][8] for conv_mfma2 ----
__global__ __launch_bounds__(256) void wsplit2_kernel(const float* __restrict__ w,
                                                      u16* __restrict__ hi, u16* __restrict__ lo,
                                                      int O, int C, int KK)
{
    const int i = blockIdx.x * 256 + threadIdx.x;
    const int n = O * C * KK;
    if (i >= n) return;
    const int o = i / (C * KK);
    const int r = i - o * C * KK;
    const int c = r / KK;
    const int t = r - c * KK;
    const float v = w[i];
    const bf16 h = __float2bfloat16(v);
    const float hv = __bfloat162float(h);
    const bf16 l = __float2bfloat16(v - hv);
    const int nch = C >> 5;
    const int cc = c >> 5, quad = (c >> 3) & 3, q = c & 7;
    const size_t dst = ((((size_t)t * nch + cc) * 4 + quad) * O + o) * 8 + q;
    hi[dst] = *(const u16*)&h;
    lo[dst] = *(const u16*)&l;
}

// ================= conv_mfma2: tiled-input MFMA conv (REFLECT pad) =================
// 256 thr = 4 waves (2x2): block M=64 pixels x N=64 out-chans (obase = z*64).
// Per C-chunk(32): stage source tile Ain[NR rows][NCOL cols][32ch] once (ch-major
// 8-blocks -> conflict-free); per tap: a-frag read directly from tile, B from
// dbuf LDS staged [quad][o][8] (coalesced global, conflict-free LDS), 1 sync/tap.
// ASPLIT: input hi/lo tiles -> +1 MFMA => ~f32. EPI: 0=f32, 2=bf16.
template<typename T1, typename T2, int K, bool UP, int EPI, bool ASPLIT,
         int NR, int NCOL, int PXROWS>
__global__ __launch_bounds__(256) void conv_mfma2(
        const T1* __restrict__ src1, const T2* __restrict__ src2,
        int C1, int C,
        const u16* __restrict__ wth, const u16* __restrict__ wtl,
        const float* __restrict__ bias,
        void* __restrict__ outv, int O, int H, int W)
{
    constexpr int KK = K * K;
    constexpr int ATILE = NR * NCOL * 32;            // u16 elems
    __shared__ __align__(16) u16 Ah[ATILE];
    __shared__ __align__(16) u16 Al[ASPLIT ? ATILE : 8];
    __shared__ __align__(16) u16 Bs[2][2][2048];     // [slot][hi/lo][quad*64+o][8]

    const int tid  = threadIdx.x;
    const int lane = tid & 63;
    const int wv   = tid >> 6;
    const int ln15 = lane & 15;
    const int quad = lane >> 4;
    const int mi = wv & 1, ni = wv >> 1;
    const int b = blockIdx.y;
    const int p0 = blockIdx.x * 64;
    const int obase = blockIdx.z * 64;
    const int HW = H * W;
    const int SH = UP ? (H >> 1) : H;
    const int SW = UP ? (W >> 1) : W;                // == NCOL
    const int SHW = SH * SW;
    const int PAD = K / 2;
    const int C2 = C - C1;
    const int nch = C >> 5;

    const int y0 = p0 / W;
    const int rbase = (y0 <= PAD) ? 0 : (UP ? ((y0 - PAD) >> 1) : (y0 - PAD));

    // per-lane tap tables for the 2 M-subtiles (a-frag pixel = p0+mi*32+ms*16+ln15)
    int rs[2][K], cs[2][K];
#pragma unroll
    for (int ms = 0; ms < 2; ++ms) {
        const int pm = p0 + mi * 32 + ms * 16 + ln15;
        const int ym = pm / W, xm = pm - ym * W;
#pragma unroll
        for (int tt = 0; tt < K; ++tt) {
            int yy = ym + tt - PAD;
            yy = yy < 0 ? -yy : yy; yy = yy >= H ? 2 * H - 2 - yy : yy;
            rs[ms][tt] = (UP ? (yy >> 1) : yy) - rbase;
            int xx = xm + tt - PAD;
            xx = xx < 0 ? -xx : xx; xx = xx >= W ? 2 * W - 2 - xx : xx;
            cs[ms][tt] = UP ? (xx >> 1) : xx;
        }
    }

    const int bo0 = (quad * 64 + ni * 32 + ln15) * 8;    // b-frag addrs (const)
    const int bo1 = bo0 + 16 * 8;

    f32x4 acc[2][2];
#pragma unroll
    for (int i = 0; i < 2; ++i)
#pragma unroll
        for (int j = 0; j < 2; ++j) acc[i][j] = (f32x4)0.f;

    for (int cc = 0; cc < nch; ++cc) {
        const int c0 = cc << 5;
        __syncthreads();   // prior taps' reads of Ah/Bs complete before rewrite
        // ---- stage input tile (once per chunk) ----
        for (int idx = tid; idx < NR * NCOL * 4; idx += 256) {
            const int c_ = idx % NCOL;
            const int r_ = (idx / NCOL) % NR;
            const int cq = idx / (NCOL * NR);
            int rr = rbase + r_; rr = rr >= SH ? SH - 1 : rr;
            const int sidx = rr * SW + c_;
            short8 vh, vl;
#pragma unroll
            for (int q = 0; q < 8; ++q) {
                const int c = c0 + cq * 8 + q;
                float v;
                if (c < C1) v = LD(src1 + (size_t)(b * C1 + c) * SHW + sidx);
                else        v = LD(src2 + (size_t)(b * C2 + (c - C1)) * SHW + sidx);
                const u16 hv = f2b(v);
                vh[q] = (short)hv;
                if (ASPLIT) vl[q] = (short)f2b(v - b2fu(hv));
            }
            *(short8*)&Ah[idx * 8] = vh;
            if (ASPLIT) *(short8*)&Al[idx * 8] = vl;
        }
        // ---- taps ----
        for (int t = 0; t < KK; ++t) {
            const int slot = t & 1;
            {   // stage B (dbuf): 1 chunk per thread, coalesced global, linear LDS
                const size_t base = ((((size_t)t * nch + cc) * 4 + (tid >> 6)) * O
                                     + obase + (tid & 63)) * 8;
                *(short8*)&Bs[slot][0][tid * 8] = *(const short8*)(wth + base);
                *(short8*)&Bs[slot][1][tid * 8] = *(const short8*)(wtl + base);
            }
            __syncthreads();
            const int ty = t / K, tx = t - ty * K;
            const int ao0 = ((quad * NR + rs[0][ty]) * NCOL + cs[0][tx]) * 8;
            const int ao1 = ((quad * NR + rs[1][ty]) * NCOL + cs[1][tx]) * 8;
            const short8 a0 = *(const short8*)&Ah[ao0];
            const short8 a1 = *(const short8*)&Ah[ao1];
            const short8 b0h = *(const short8*)&Bs[slot][0][bo0];
            const short8 b1h = *(const short8*)&Bs[slot][0][bo1];
            const short8 b0l = *(const short8*)&Bs[slot][1][bo0];
            const short8 b1l = *(const short8*)&Bs[slot][1][bo1];
            acc[0][0] = __builtin_amdgcn_mfma_f32_16x16x32_bf16(a0, b0h, acc[0][0], 0, 0, 0);
            acc[0][0] = __builtin_amdgcn_mfma_f32_16x16x32_bf16(a0, b0l, acc[0][0], 0, 0, 0);
            acc[0][1] = __builtin_amdgcn_mfma_f32_16x16x32_bf16(a0, b1h, acc[0][1], 0, 0, 0);
            acc[0][1] = __builtin_amdgcn_mfma_f32_16x16x32_bf16(a0, b1l, acc[0][1], 0, 0, 0);
            acc[1][0] = __builtin_amdgcn_mfma_f32_16x16x32_bf16(a1, b0h, acc[1][0], 0, 0, 0);
            acc[1][0] = __builtin_amdgcn_mfma_f32_16x16x32_bf16(a1, b0l, acc[1][0], 0, 0, 0);
            acc[1][1] = __builtin_amdgcn_mfma_f32_16x16x32_bf16(a1, b1h, acc[1][1], 0, 0, 0);
            acc[1][1] = __builtin_amdgcn_mfma_f32_16x16x32_bf16(a1, b1l, acc[1][1], 0, 0, 0);
            if (ASPLIT) {
                const short8 a0l = *(const short8*)&Al[ao0];
                const short8 a1l = *(const short8*)&Al[ao1];
                acc[0][0] = __builtin_amdgcn_mfma_f32_16x16x32_bf16(a0l, b0h, acc[0][0], 0, 0, 0);
                acc[0][1] = __builtin_amdgcn_mfma_f32_16x16x32_bf16(a0l, b1h, acc[0][1], 0, 0, 0);
                acc[1][0] = __builtin_amdgcn_mfma_f32_16x16x32_bf16(a1l, b0h, acc[1][0], 0, 0, 0);
                acc[1][1] = __builtin_amdgcn_mfma_f32_16x16x32_bf16(a1l, b1h, acc[1][1], 0, 0, 0);
            }
        }
    }

    // epilogue: D col=ln15 -> o, row=quad*4+r -> pixel
#pragma unroll
    for (int ms = 0; ms < 2; ++ms) {
#pragma unroll
        for (int ns = 0; ns < 2; ++ns) {
            const int o = obase + ni * 32 + ns * 16 + ln15;
            const float bv = bias[o];
#pragma unroll
            for (int r = 0; r < 4; ++r) {
                const int pp = p0 + mi * 32 + ms * 16 + (quad << 2) + r;
                const float v = acc[ms][ns][r] + bv;
                const size_t oidx = ((size_t)(b * O + o)) * HW + pp;
                if (EPI == 0) ((float*)outv)[oidx] = v;
                else          ((bf16*)outv)[oidx] = __float2bfloat16(v);
            }
        }
    }
}

// ================= old conv_mfma (R14) — off-convs + conv6 =================
template<typename T1, typename T2, int K, bool REFLECT, bool UP, int NTN, int EPI, bool ASPLIT>
__global__ __launch_bounds__(256) void conv_mfma(
        const T1* __restrict__ src1, const T2* __restrict__ src2,
        int C1, int C,
        const u16* __restrict__ wth, const u16* __restrict__ wtl,
        const float* __restrict__ bias,
        void* __restrict__ outv, int O, int H, int W)
{
    constexpr int KK = K * K;
    __shared__ __align__(16) u16 As[64 * 40];
    __shared__ __align__(16) u16 Alo[ASPLIT ? 64 * 40 : 8];
    __shared__ __align__(16) u16 Bh[NTN * 16 * 40];
    __shared__ __align__(16) u16 Bl[NTN * 16 * 40];

    const int tid  = threadIdx.x;
    const int wv   = tid >> 6;
    const int lane = tid & 63;
    const int ln15 = lane & 15;
    const int b    = blockIdx.y;
    const int p0   = blockIdx.x * 64;
    const int obase = blockIdx.z * (NTN * 16);
    const int HW = H * W;
    const int Hs = UP ? (H >> 1) : H;
    const int Ws = UP ? (W >> 1) : W;
    const int HsWs = Hs * Ws;
    const int PAD = K / 2;
    const int C2 = C - C1;
    const int m_stage = tid & 63;

    const int p = p0 + m_stage;
    const int y = p / W, x = p - y * W;
    int off[KK];
    float msk[KK];
#pragma unroll
    for (int ty = 0; ty < K; ++ty) {
#pragma unroll
        for (int tx = 0; tx < K; ++tx) {
            int yy = y + ty - PAD, xx = x + tx - PAD;
            bool vv = true;
            if (REFLECT) {
                yy = yy < 0 ? -yy : yy; yy = yy >= H ? 2 * H - 2 - yy : yy;
                xx = xx < 0 ? -xx : xx; xx = xx >= W ? 2 * W - 2 - xx : xx;
            } else {
                vv = (yy >= 0 && yy < H && xx >= 0 && xx < W);
                yy = yy < 0 ? 0 : (yy >= H ? H - 1 : yy);
                xx = xx < 0 ? 0 : (xx >= W ? W - 1 : xx);
            }
            off[ty * K + tx] = (UP ? (yy >> 1) : yy) * Ws + (UP ? (xx >> 1) : xx);
            msk[ty * K + tx] = vv ? 1.f : 0.f;
        }
    }

    f32x4 acc[NTN];
#pragma unroll
    for (int nt = 0; nt < NTN; ++nt) acc[nt] = (f32x4)0.f;

    const int aswz = (m_stage >> 3) & 3;
    const int awr  = m_stage * 40 + ((wv ^ aswz) << 3);
    const int arow = wv * 16 + ln15;
    const int ard  = arow * 40 + (((lane >> 4) ^ ((arow >> 3) & 3)) << 3);

    const int nch = C >> 5;
    for (int cc = 0; cc < nch; ++cc) {
        const int c0 = cc << 5;
        for (int t = 0; t < KK; ++t) {
            const int offt = off[t];
            const float mskt = msk[t];
            __syncthreads();
            {
                short8 avh, avl;
#pragma unroll
                for (int q = 0; q < 8; ++q) {
                    const int c = c0 + (wv << 3) + q;
                    float v;
                    if (c < C1) v = LD(src1 + ((size_t)(b * C1 + c)) * HsWs + offt);
                    else        v = LD(src2 + ((size_t)(b * C2 + (c - C1))) * HsWs + offt);
                    if (!REFLECT) v *= mskt;
                    const u16 hv = f2b(v);
                    avh[q] = (short)hv;
                    if (ASPLIT) avl[q] = (short)f2b(v - b2fu(hv));
                }
                *(short8*)&As[awr] = avh;
                if (ASPLIT) *(short8*)&Alo[awr] = avl;
            }
            for (int i = tid; i < NTN * 16 * 4; i += 256) {
                const int row = i >> 2, part = i & 3;
                int o = obase + row; if (o >= O) o = O - 1;
                const int pw = row * 40 + ((part ^ ((row >> 3) & 3)) << 3);
                const size_t wb = ((size_t)t * O + o) * C + c0 + (part << 3);
                *(short8*)&Bh[pw] = *(const short8*)(wth + wb);
                *(short8*)&Bl[pw] = *(const short8*)(wtl + wb);
            }
            __syncthreads();
            const short8 a = *(const short8*)&As[ard];
            short8 al;
            if (ASPLIT) al = *(const short8*)&Alo[ard];
#pragma unroll
            for (int nt = 0; nt < NTN; ++nt) {
                const int brow = nt * 16 + ln15;
                const int brd = brow * 40 + (((lane >> 4) ^ ((brow >> 3) & 3)) << 3);
                const short8 bh = *(const short8*)&Bh[brd];
                acc[nt] = __builtin_amdgcn_mfma_f32_16x16x32_bf16(a, bh, acc[nt], 0, 0, 0);
                const short8 bl = *(const short8*)&Bl[brd];
                acc[nt] = __builtin_amdgcn_mfma_f32_16x16x32_bf16(a, bl, acc[nt], 0, 0, 0);
                if (ASPLIT)
                    acc[nt] = __builtin_amdgcn_mfma_f32_16x16x32_bf16(al, bh, acc[nt], 0, 0, 0);
            }
        }
    }

#pragma unroll
    for (int nt = 0; nt < NTN; ++nt) {
        const int o = obase + nt * 16 + ln15;
        if (o < O) {
            const float bv = bias[o];
#pragma unroll
            for (int r = 0; r < 4; ++r) {
                const int pp = p0 + wv * 16 + ((lane >> 4) << 2) + r;
                const float v = acc[nt][r] + bv;
                const size_t oidx = ((size_t)(b * O + o)) * HW + pp;
                if (EPI == 0)      ((float*)outv)[oidx] = v;
                else if (EPI == 1) ((float*)outv)[oidx] = tanhf(v);
                else               ((bf16*)outv)[oidx] = __float2bfloat16(v);
            }
        }
    }
}

// ---------------- instance norm ----------------
template<typename T>
__global__ __launch_bounds__(256) void inorm_kernel(T* __restrict__ buf,
                                                    float* __restrict__ resid,
                                                    int HW, int mode)
{
    __shared__ double sh0[256], sh1[256];
    const int pl = blockIdx.x;
    T* p = buf + (size_t)pl * HW;
    double s = 0.0, ss = 0.0;
    for (int i = threadIdx.x; i < HW; i += 256) {
        float v = LD(p + i);
        s += (double)v; ss += (double)v * (double)v;
    }
    sh0[threadIdx.x] = s; sh1[threadIdx.x] = ss;
    __syncthreads();
    for (int st = 128; st > 0; st >>= 1) {
        if (threadIdx.x < st) {
            sh0[threadIdx.x] += sh0[threadIdx.x + st];
            sh1[threadIdx.x] += sh1[threadIdx.x + st];
        }
        __syncthreads();
    }
    const double mean = sh0[0] / HW;
    const float m = (float)mean;
    const float var = (float)(sh1[0] / HW - mean * mean);
    const float inv = rsqrtf(var + 1e-5f);
    if (mode == 0) {
        for (int i = threadIdx.x; i < HW; i += 256) {
            float v = (LD(p + i) - m) * inv;
            ST(p + i, v > 0.f ? v : 0.f);
        }
    } else {
        float* r = resid + (size_t)pl * HW;
        for (int i = threadIdx.x; i < HW; i += 256)
            r[i] = r[i] + (LD(p + i) - m) * inv;
    }
}

// ---------------- weight transpose for mdcn ----------------
__global__ __launch_bounds__(256) void wtrans_kernel(const float* __restrict__ w,
                                                     float* __restrict__ wT, int C, int O)
{
    const int i = blockIdx.x * 256 + threadIdx.x;
    const int n = O * C * 9;
    if (i >= n) return;
    const int o = i / (C * 9);
    const int r = i - o * C * 9;
    wT[(size_t)r * O + o] = w[i];
}

// ---------------- modulated deformable conv, cooperative LDS ----------------
template<int NT, int T, int CC, typename OT>
__global__ __launch_bounds__(256) void mdcn_lds(
        const float* __restrict__ skip, const float* __restrict__ om,
        const float* __restrict__ wT, const float* __restrict__ bias,
        OT* __restrict__ out, int C, int O, int H, int W)
{
    __shared__ __align__(16) float smp[CC * 9 * T];
    __shared__ float tpy[9 * T], tpx[9 * T], tm[9 * T];
    const int b = blockIdx.y;
    const int p0 = blockIdx.x * T;
    const int tid = threadIdx.x;
    const int HW = H * W;
    const float* omb = om + (size_t)b * 27 * HW;
    for (int i = tid; i < 9 * T; i += NT) {
        const int k = i / T, t = i - k * T;
        const int p = p0 + t;
        const int y = p / W, x = p - y * W;
        const float dy = omb[(2 * k) * HW + p];
        const float dx = omb[(2 * k + 1) * HW + p];
        const float mk = 1.f / (1.f + expf(-omb[(18 + k) * HW + p]));
        float py = (float)(y + k / 3 - 1) + dy;
        float pxx = (float)(x + k % 3 - 1) + dx;
        py  = fminf(fmaxf(py, -2.f), (float)H + 1.f);
        pxx = fminf(fmaxf(pxx, -2.f), (float)W + 1.f);
        tpy[i] = py; tpx[i] = pxx; tm[i] = mk;
    }

    float acc[T];
#pragma unroll
    for (int t = 0; t < T; ++t) acc[t] = 0.f;
    const int o = tid;
    const float* xb = skip + (size_t)b * C * HW;

    for (int c0 = 0; c0 < C; c0 += CC) {
        __syncthreads();
        for (int i = tid; i < CC * 9 * T; i += NT) {
            const int t = i % T;
            const int kk = (i / T) % 9;
            const int ci = i / (9 * T);
            const int ti = kk * T + t;
            const float py = tpy[ti], pxx = tpx[ti], mk = tm[ti];
            const float y0f = floorf(py), x0f = floorf(pxx);
            const int y0 = (int)y0f, x0 = (int)x0f;
            const float wy1 = py - y0f, wx1 = pxx - x0f;
            const float wy0 = 1.f - wy1, wx0 = 1.f - wx1;
            const float* pl = xb + (size_t)(c0 + ci) * HW;
            float v = 0.f;
            if (y0 >= 0 && y0 < H) {
                const float* r = pl + y0 * W;
                if (x0 >= 0 && x0 < W)         v += wy0 * wx0 * r[x0];
                if (x0 + 1 >= 0 && x0 + 1 < W) v += wy0 * wx1 * r[x0 + 1];
            }
            if (y0 + 1 >= 0 && y0 + 1 < H) {
                const float* r = pl + (y0 + 1) * W;
                if (x0 >= 0 && x0 < W)         v += wy1 * wx0 * r[x0];
                if (x0 + 1 >= 0 && x0 + 1 < W) v += wy1 * wx1 * r[x0 + 1];
            }
            smp[i] = v * mk;
        }
        __syncthreads();
        for (int ci = 0; ci < CC; ++ci) {
#pragma unroll
            for (int k = 0; k < 9; ++k) {
                const float wvv = wT[((size_t)(c0 + ci) * 9 + k) * O + o];
                const float4* sp = (const float4*)(smp + (ci * 9 + k) * T);
#pragma unroll
                for (int q = 0; q < T / 4; ++q) {
                    const float4 s = sp[q];
                    acc[q * 4 + 0] += wvv * s.x;
                    acc[q * 4 + 1] += wvv * s.y;
                    acc[q * 4 + 2] += wvv * s.z;
                    acc[q * 4 + 3] += wvv * s.w;
                }
            }
        }
    }
    const float bv = bias[o];
    OT* op = out + (size_t)(b * O + o) * HW + p0;
#pragma unroll
    for (int t = 0; t < T; ++t) ST(op + t, acc[t] + bv);
}

// ---------------- offset_sum ----------------
__global__ void zero1_kernel(float* __restrict__ out) { if (threadIdx.x == 0) out[0] = 0.f; }

__global__ __launch_bounds__(256) void offsum_one(const float* __restrict__ om, int HW,
                                                  float* __restrict__ out)
{
    __shared__ double sh[256];
    const int n = 8 * 18 * HW;
    double s = 0.0;
    for (int i = blockIdx.x * 256 + threadIdx.x; i < n; i += gridDim.x * 256) {
        const int b = i / (18 * HW); const int r = i - b * 18 * HW;
        const int c = r / HW; const int p = r - c * HW;
        s += fabs((double)om[(size_t)(b * 27 + c) * HW + p]);
    }
    sh[threadIdx.x] = s;
    __syncthreads();
    for (int st = 128; st > 0; st >>= 1) {
        if (threadIdx.x < st) sh[threadIdx.x] += sh[threadIdx.x + st];
        __syncthreads();
    }
    if (threadIdx.x == 0) atomicAdd(out, (float)(0.5 * sh[0] / n));
}

// ---------------- launch ----------------
extern "C" void kernel_launch(void* const* d_in, const int* in_sizes, int n_in,
                              void* d_out, int out_size, void* d_ws, size_t ws_size,
                              hipStream_t stream)
{
    if (n_in < 27) return;
    if (out_size < 393217) return;
    if (in_sizes[0] != 8 * 256 * 32 * 32) return;
    if (in_sizes[1] != 8 * 128 * 64 * 64) return;
    if (in_sizes[2] != 8 * 256 * 32 * 32) return;
    if (in_sizes[25] != 128 * 128 * 9) return;
    if (in_sizes[26] != 128) return;

    const float* x        = (const float*)d_in[0];
    const float* skip1    = (const float*)d_in[1];
    const float* skip2    = (const float*)d_in[2];
    const float* rbw[2][2] = {{(const float*)d_in[3], (const float*)d_in[5]},
                              {(const float*)d_in[7], (const float*)d_in[9]}};
    const float* rbb[2][2] = {{(const float*)d_in[4], (const float*)d_in[6]},
                              {(const float*)d_in[8], (const float*)d_in[10]}};
    const float* conv1_w = (const float*)d_in[11]; const float* conv1_b = (const float*)d_in[12];
    const float* conv3_w = (const float*)d_in[13]; const float* conv3_b = (const float*)d_in[14];
    const float* conv5_w = (const float*)d_in[15]; const float* conv5_b = (const float*)d_in[16];
    const float* conv6_w = (const float*)d_in[17]; const float* conv6_b = (const float*)d_in[18];
    const float* dcn2_off_w = (const float*)d_in[19]; const float* dcn2_off_b = (const float*)d_in[20];
    const float* dcn2_w = (const float*)d_in[21]; const float* dcn2_b = (const float*)d_in[22];
    const float* dcn1_off_w = (const float*)d_in[23]; const float* dcn1_off_b = (const float*)d_in[24];
    const float* dcn1_w = (const float*)d_in[25]; const float* dcn1_b = (const float*)d_in[26];

    float* outp = (float*)d_out;

    const size_t NEED_F32 = 9494528ull;      // unchanged, proven R8-R14
    if (ws_size < NEED_F32 * 4ull) return;

    float* ws = (float*)d_ws;
    const size_t NA = 2097152ull;            // 8*256*32*32
    float* A   = ws;                          // x / rb accum / pre2 ; later Ib
    float* Bb  = ws + NA;                     // h / D ; later wT1 ; later Jb(lo half)
    float* Tmp = ws + 2 * NA;                 // rb tmp ; {wT2,wo2} ; wt3 ; wo1 ; Jb(hi half)
    float* om2 = ws + 3 * NA;                 // [221184] ; after offsum: conv6 wt
    float* om1 = om2 + 221184;                // [884736] ; later conv5 wt
    bf16*  Fb  = (bf16*)(om1 + 884736);       // c3 bf16 ; BEFORE conv3: early MFMA weights
    bf16*  Ib  = (bf16*)A;                    // pre1 bf16
    bf16*  Jb  = (bf16*)Bb;                   // c5 bf16 (Bb+Tmp)
    float* wT2 = Tmp;                         // mdcn2 transposed weights (589824 f32)
    u16*   wo2h = (u16*)(Tmp + 589824);       // dcn2 off-conv MFMA w hi (124416 u16)
    u16*   wo2l = wo2h + 124416;
    u16*   wt3h = (u16*)Tmp;                  // conv3 MFMA w (after mdcn2)
    u16*   wt3l = wt3h + 25 * 128 * 512;
    u16*   wo1h = (u16*)Tmp;                  // dcn1 off-conv MFMA w (after conv3)
    u16*   wo1l = wo1h + 62208;
    float* wT1 = Bb;                          // mdcn1 transposed weights (after conv3)
    u16*   wt5h = (u16*)om1;                  // conv5 MFMA w (after offsum)
    u16*   wt5l = wt5h + 25 * 64 * 256;
    u16*   wt6h = (u16*)om2;                  // conv6 MFMA w (om2 dead after offsum)
    u16*   wt6l = wt6h + 9408;
    u16*   wEh = (u16*)Fb;                    // early conv MFMA weights (Fb free until conv3)

    copy_kernel<<<8192, 256, 0, stream>>>(x, A, (int)NA);

    // ResBlocks via conv_mfma2 (A+W hi/lo split -> ~f32 precision)
    for (int r = 0; r < 2; ++r) {
        wsplit2_kernel<<<2304, 256, 0, stream>>>(rbw[r][0], wEh, wEh + 589824, 256, 256, 9);
        conv_mfma2<float, float, 3, false, 0, true, 4, 32, 2><<<dim3(16, 8, 4), 256, 0, stream>>>(
            A, (const float*)nullptr, 256, 256, wEh, wEh + 589824, rbb[r][0], Bb, 256, 32, 32);
        inorm_kernel<float><<<2048, 256, 0, stream>>>(Bb, nullptr, 1024, 0);
        wsplit2_kernel<<<2304, 256, 0, stream>>>(rbw[r][1], wEh, wEh + 589824, 256, 256, 9);
        conv_mfma2<float, float, 3, false, 0, true, 4, 32, 2><<<dim3(16, 8, 4), 256, 0, stream>>>(
            Bb, (const float*)nullptr, 256, 256, wEh, wEh + 589824, rbb[r][1], Tmp, 256, 32, 32);
        inorm_kernel<float><<<2048, 256, 0, stream>>>(Tmp, A, 1024, 1);
    }

    // conv1 (5x5, 256->256) via conv_mfma2 + IN/ReLU
    wsplit2_kernel<<<6400, 256, 0, stream>>>(conv1_w, wEh, wEh + 1638400, 256, 256, 25);
    conv_mfma2<float, float, 5, false, 0, true, 6, 32, 2><<<dim3(16, 8, 4), 256, 0, stream>>>(
        A, (const float*)nullptr, 256, 256, wEh, wEh + 1638400, conv1_b, Bb, 256, 32, 32);
    inorm_kernel<float><<<2048, 256, 0, stream>>>(Bb, nullptr, 1024, 0);

    // dcn2 off-conv: old conv_mfma (zero-pad, K=3, O=27) -> om2
    wsplit_kernel<<<486, 256, 0, stream>>>(dcn2_off_w, wo2h, wo2l, 27, 512, 9);
    conv_mfma<float, float, 3, false, false, 2, 0, false><<<dim3(16, 8, 1), 256, 0, stream>>>(
        Bb, skip2, 256, 512, wo2h, wo2l, dcn2_off_b, om2, 27, 32, 32);
    wtrans_kernel<<<2304, 256, 0, stream>>>(dcn2_w, wT2, 256, 256);
    mdcn_lds<256, 8, 32, float><<<dim3(128, 8), 256, 0, stream>>>(
        skip2, om2, wT2, dcn2_b, A, 256, 256, 32, 32);

    // conv3: conv_mfma2 (UP), 512->128 @64x64 -> Fb + IN/ReLU
    wsplit2_kernel<<<6400, 256, 0, stream>>>(conv3_w, wt3h, wt3l, 128, 512, 25);
    conv_mfma2<float, float, 5, true, 2, false, 3, 32, 1><<<dim3(64, 8, 2), 256, 0, stream>>>(
        A, Bb, 256, 512, wt3h, wt3l, conv3_b, Fb, 128, 64, 64);
    inorm_kernel<bf16><<<1024, 256, 0, stream>>>(Fb, nullptr, 4096, 0);

    // dcn1 off-conv: old conv_mfma -> om1
    wsplit_kernel<<<243, 256, 0, stream>>>(dcn1_off_w, wo1h, wo1l, 27, 256, 9);
    conv_mfma<bf16, float, 3, false, false, 2, 0, false><<<dim3(64, 8, 1), 256, 0, stream>>>(
        Fb, skip1, 128, 256, wo1h, wo1l, dcn1_off_b, om1, 27, 64, 64);
    wtrans_kernel<<<576, 256, 0, stream>>>(dcn1_w, wT1, 128, 128);
    mdcn_lds<128, 16, 32, bf16><<<dim3(256, 8), 128, 0, stream>>>(
        skip1, om1, wT1, dcn1_b, Ib, 128, 128, 64, 64);

    // offset_sum now (frees om1/om2 regions for conv5/conv6 weights)
    zero1_kernel<<<1, 64, 0, stream>>>(outp + 393216);
    offsum_one<<<64, 256, 0, stream>>>(om1, 4096, outp + 393216);
    offsum_one<<<64, 256, 0, stream>>>(om2, 1024, outp + 393216);

    // conv5: conv_mfma2 (UP), 256->64 @128x128 -> Jb + IN/ReLU
    wsplit2_kernel<<<1600, 256, 0, stream>>>(conv5_w, wt5h, wt5l, 64, 256, 25);
    conv_mfma2<bf16, bf16, 5, true, 2, false, 3, 64, 1><<<dim3(256, 8, 1), 256, 0, stream>>>(
        Ib, Fb, 128, 256, wt5h, wt5l, conv5_b, Jb, 64, 128, 128);
    inorm_kernel<bf16><<<512, 256, 0, stream>>>(Jb, nullptr, 16384, 0);

    // conv6: 7x7, 64->3, tanh via old conv_mfma -> d_out (f32)
    wsplit_kernel<<<37, 256, 0, stream>>>(conv6_w, wt6h, wt6l, 3, 64, 49);
    conv_mfma<bf16, float, 7, true, false, 1, 1, false><<<dim3(256, 8, 1), 256, 0, stream>>>(
        Jb, (const float*)nullptr, 64, 64, wt6h, wt6l, conv6_b, (void*)outp, 3, 128, 128);
}

// Round 16
// 1825.357 us; speedup vs baseline: 32.6559x; 1.0846x over previous
//
#include <hip/hip_runtime.h>
#include <hip/hip_bf16.h>
#include <math.h>

typedef __hip_bfloat16 bf16;
typedef unsigned short u16;
typedef __attribute__((ext_vector_type(8))) short short8;   // 8 bf16 (4 VGPRs)
typedef __attribute__((ext_vector_type(4))) float f32x4;

__device__ __forceinline__ float LD(const float* p) { return *p; }
__device__ __forceinline__ float LD(const bf16* p)  { return __bfloat162float(*p); }
__device__ __forceinline__ void  ST(float* p, float v) { *p = v; }
__device__ __forceinline__ void  ST(bf16* p, float v)  { *p = __float2bfloat16(v); }
__device__ __forceinline__ u16   f2b(float v) { bf16 h = __float2bfloat16(v); return *reinterpret_cast<u16*>(&h); }
__device__ __forceinline__ float b2fu(u16 u) { bf16 h = *reinterpret_cast<bf16*>(&u); return __bfloat162float(h); }

// ---------------- f32 copy ----------------
__global__ __launch_bounds__(256) void copy_kernel(const float* __restrict__ in,
                                                   float* __restrict__ out, int n) {
    int i = blockIdx.x * blockDim.x + threadIdx.x;
    if (i < n) out[i] = in[i];
}

// ---- wsplit (layout [t][o][c], for off-convs + conv6) ----
__global__ __launch_bounds__(256) void wsplit_kernel(const float* __restrict__ w,
                                                     u16* __restrict__ hi, u16* __restrict__ lo,
                                                     int O, int C, int KK)
{
    const int i = blockIdx.x * 256 + threadIdx.x;
    const int n = O * C * KK;
    if (i >= n) return;
    const int o = i / (C * KK);
    const int r = i - o * C * KK;
    const int c = r / KK;
    const int t = r - c * KK;
    const float v = w[i];
    const bf16 h = __float2bfloat16(v);
    const float hv = __bfloat162float(h);
    const bf16 l = __float2bfloat16(v - hv);
    const size_t dst = ((size_t)t * O + o) * C + c;
    hi[dst] = *(const u16*)&h;
    lo[dst] = *(const u16*)&l;
}

// ---- wsplit2: layout [t][cc][quad][O][8] for conv_mfma2 + mdcn_mfma ----
__global__ __launch_bounds__(256) void wsplit2_kernel(const float* __restrict__ w,
                                                      u16* __restrict__ hi, u16* __restrict__ lo,
                                                      int O, int C, int KK)
{
    const int i = blockIdx.x * 256 + threadIdx.x;
    const int n = O * C * KK;
    if (i >= n) return;
    const int o = i / (C * KK);
    const int r = i - o * C * KK;
    const int c = r / KK;
    const int t = r - c * KK;
    const float v = w[i];
    const bf16 h = __float2bfloat16(v);
    const float hv = __bfloat162float(h);
    const bf16 l = __float2bfloat16(v - hv);
    const int nch = C >> 5;
    const int cc = c >> 5, quad = (c >> 3) & 3, q = c & 7;
    const size_t dst = ((((size_t)t * nch + cc) * 4 + quad) * O + o) * 8 + q;
    hi[dst] = *(const u16*)&h;
    lo[dst] = *(const u16*)&l;
}

// ================= conv_mfma2: tiled-input MFMA conv (REFLECT pad) =================
template<typename T1, typename T2, int K, bool UP, int EPI, bool ASPLIT,
         int NR, int NCOL, int PXROWS>
__global__ __launch_bounds__(256) void conv_mfma2(
        const T1* __restrict__ src1, const T2* __restrict__ src2,
        int C1, int C,
        const u16* __restrict__ wth, const u16* __restrict__ wtl,
        const float* __restrict__ bias,
        void* __restrict__ outv, int O, int H, int W)
{
    constexpr int KK = K * K;
    constexpr int ATILE = NR * NCOL * 32;
    __shared__ __align__(16) u16 Ah[ATILE];
    __shared__ __align__(16) u16 Al[ASPLIT ? ATILE : 8];
    __shared__ __align__(16) u16 Bs[2][2][2048];

    const int tid  = threadIdx.x;
    const int lane = tid & 63;
    const int wv   = tid >> 6;
    const int ln15 = lane & 15;
    const int quad = lane >> 4;
    const int mi = wv & 1, ni = wv >> 1;
    const int b = blockIdx.y;
    const int p0 = blockIdx.x * 64;
    const int obase = blockIdx.z * 64;
    const int HW = H * W;
    const int SH = UP ? (H >> 1) : H;
    const int SW = UP ? (W >> 1) : W;
    const int SHW = SH * SW;
    const int PAD = K / 2;
    const int C2 = C - C1;
    const int nch = C >> 5;

    const int y0 = p0 / W;
    const int rbase = (y0 <= PAD) ? 0 : (UP ? ((y0 - PAD) >> 1) : (y0 - PAD));

    int rs[2][K], cs[2][K];
#pragma unroll
    for (int ms = 0; ms < 2; ++ms) {
        const int pm = p0 + mi * 32 + ms * 16 + ln15;
        const int ym = pm / W, xm = pm - ym * W;
#pragma unroll
        for (int tt = 0; tt < K; ++tt) {
            int yy = ym + tt - PAD;
            yy = yy < 0 ? -yy : yy; yy = yy >= H ? 2 * H - 2 - yy : yy;
            rs[ms][tt] = (UP ? (yy >> 1) : yy) - rbase;
            int xx = xm + tt - PAD;
            xx = xx < 0 ? -xx : xx; xx = xx >= W ? 2 * W - 2 - xx : xx;
            cs[ms][tt] = UP ? (xx >> 1) : xx;
        }
    }

    const int bo0 = (quad * 64 + ni * 32 + ln15) * 8;
    const int bo1 = bo0 + 16 * 8;

    f32x4 acc[2][2];
#pragma unroll
    for (int i = 0; i < 2; ++i)
#pragma unroll
        for (int j = 0; j < 2; ++j) acc[i][j] = (f32x4)0.f;

    for (int cc = 0; cc < nch; ++cc) {
        const int c0 = cc << 5;
        __syncthreads();
        for (int idx = tid; idx < NR * NCOL * 4; idx += 256) {
            const int c_ = idx % NCOL;
            const int r_ = (idx / NCOL) % NR;
            const int cq = idx / (NCOL * NR);
            int rr = rbase + r_; rr = rr >= SH ? SH - 1 : rr;
            const int sidx = rr * SW + c_;
            short8 vh, vl;
#pragma unroll
            for (int q = 0; q < 8; ++q) {
                const int c = c0 + cq * 8 + q;
                float v;
                if (c < C1) v = LD(src1 + (size_t)(b * C1 + c) * SHW + sidx);
                else        v = LD(src2 + (size_t)(b * C2 + (c - C1)) * SHW + sidx);
                const u16 hv = f2b(v);
                vh[q] = (short)hv;
                if (ASPLIT) vl[q] = (short)f2b(v - b2fu(hv));
            }
            *(short8*)&Ah[idx * 8] = vh;
            if (ASPLIT) *(short8*)&Al[idx * 8] = vl;
        }
        for (int t = 0; t < KK; ++t) {
            const int slot = t & 1;
            {
                const size_t base = ((((size_t)t * nch + cc) * 4 + (tid >> 6)) * O
                                     + obase + (tid & 63)) * 8;
                *(short8*)&Bs[slot][0][tid * 8] = *(const short8*)(wth + base);
                *(short8*)&Bs[slot][1][tid * 8] = *(const short8*)(wtl + base);
            }
            __syncthreads();
            const int ty = t / K, tx = t - ty * K;
            const int ao0 = ((quad * NR + rs[0][ty]) * NCOL + cs[0][tx]) * 8;
            const int ao1 = ((quad * NR + rs[1][ty]) * NCOL + cs[1][tx]) * 8;
            const short8 a0 = *(const short8*)&Ah[ao0];
            const short8 a1 = *(const short8*)&Ah[ao1];
            const short8 b0h = *(const short8*)&Bs[slot][0][bo0];
            const short8 b1h = *(const short8*)&Bs[slot][0][bo1];
            const short8 b0l = *(const short8*)&Bs[slot][1][bo0];
            const short8 b1l = *(const short8*)&Bs[slot][1][bo1];
            acc[0][0] = __builtin_amdgcn_mfma_f32_16x16x32_bf16(a0, b0h, acc[0][0], 0, 0, 0);
            acc[0][0] = __builtin_amdgcn_mfma_f32_16x16x32_bf16(a0, b0l, acc[0][0], 0, 0, 0);
            acc[0][1] = __builtin_amdgcn_mfma_f32_16x16x32_bf16(a0, b1h, acc[0][1], 0, 0, 0);
            acc[0][1] = __builtin_amdgcn_mfma_f32_16x16x32_bf16(a0, b1l, acc[0][1], 0, 0, 0);
            acc[1][0] = __builtin_amdgcn_mfma_f32_16x16x32_bf16(a1, b0h, acc[1][0], 0, 0, 0);
            acc[1][0] = __builtin_amdgcn_mfma_f32_16x16x32_bf16(a1, b0l, acc[1][0], 0, 0, 0);
            acc[1][1] = __builtin_amdgcn_mfma_f32_16x16x32_bf16(a1, b1h, acc[1][1], 0, 0, 0);
            acc[1][1] = __builtin_amdgcn_mfma_f32_16x16x32_bf16(a1, b1l, acc[1][1], 0, 0, 0);
            if (ASPLIT) {
                const short8 a0l = *(const short8*)&Al[ao0];
                const short8 a1l = *(const short8*)&Al[ao1];
                acc[0][0] = __builtin_amdgcn_mfma_f32_16x16x32_bf16(a0l, b0h, acc[0][0], 0, 0, 0);
                acc[0][1] = __builtin_amdgcn_mfma_f32_16x16x32_bf16(a0l, b1h, acc[0][1], 0, 0, 0);
                acc[1][0] = __builtin_amdgcn_mfma_f32_16x16x32_bf16(a1l, b0h, acc[1][0], 0, 0, 0);
                acc[1][1] = __builtin_amdgcn_mfma_f32_16x16x32_bf16(a1l, b1h, acc[1][1], 0, 0, 0);
            }
        }
    }

#pragma unroll
    for (int ms = 0; ms < 2; ++ms) {
#pragma unroll
        for (int ns = 0; ns < 2; ++ns) {
            const int o = obase + ni * 32 + ns * 16 + ln15;
            const float bv = bias[o];
#pragma unroll
            for (int r = 0; r < 4; ++r) {
                const int pp = p0 + mi * 32 + ms * 16 + (quad << 2) + r;
                const float v = acc[ms][ns][r] + bv;
                const size_t oidx = ((size_t)(b * O + o)) * HW + pp;
                if (EPI == 0) ((float*)outv)[oidx] = v;
                else          ((bf16*)outv)[oidx] = __float2bfloat16(v);
            }
        }
    }
}

// ================= mdcn_mfma: deformable conv contraction on MFMA =================
// 256 thr = 4 waves (2x2): M=64 pixels x N=64 out-chans (obase=z*64).
// K reordered (tap k outer, 32-channel block inner): bilinear params computed once
// per (k, pixel-lane), reused across channels. Samples+weights hi/lo split -> ~f32.
template<typename OT, bool ASPLIT>
__global__ __launch_bounds__(256) void mdcn_mfma(
        const float* __restrict__ skip, const float* __restrict__ om,
        const u16* __restrict__ wth, const u16* __restrict__ wtl,
        const float* __restrict__ bias,
        OT* __restrict__ out, int C, int O, int H, int W)
{
    __shared__ float tpy[576], tpxs[576], tms[576];
    __shared__ __align__(16) u16 Ah[2][2048];
    __shared__ __align__(16) u16 Al[ASPLIT ? 2 : 1][2048];
    __shared__ __align__(16) u16 Bs[2][2][2048];

    const int tid = threadIdx.x;
    const int lane = tid & 63;
    const int wv = tid >> 6;
    const int ln15 = lane & 15;
    const int quad = lane >> 4;
    const int mi = wv & 1, ni = wv >> 1;
    const int b = blockIdx.y;
    const int p0 = blockIdx.x * 64;
    const int obase = blockIdx.z * 64;
    const int HW = H * W;
    const int nch = C >> 5;

    const float* omb = om + (size_t)b * 27 * HW;
    for (int i = tid; i < 576; i += 256) {
        const int k = i >> 6, px_ = i & 63;
        const int p = p0 + px_;
        const int y = p / W, x = p - y * W;
        const float dy = omb[(2 * k) * HW + p];
        const float dx = omb[(2 * k + 1) * HW + p];
        const float mk = 1.f / (1.f + expf(-omb[(18 + k) * HW + p]));
        float py = (float)(y + k / 3 - 1) + dy;
        float pxx = (float)(x + k % 3 - 1) + dx;
        py  = fminf(fmaxf(py, -2.f), (float)H + 1.f);
        pxx = fminf(fmaxf(pxx, -2.f), (float)W + 1.f);
        tpy[i] = py; tpxs[i] = pxx; tms[i] = mk;
    }
    __syncthreads();

    f32x4 acc[2][2];
#pragma unroll
    for (int i = 0; i < 2; ++i)
#pragma unroll
        for (int j = 0; j < 2; ++j) acc[i][j] = (f32x4)0.f;

    const float* xb = skip + (size_t)b * C * HW;
    const int ao0 = ((mi * 32 + ln15) * 4 + quad) * 8;
    const int ao1 = ((mi * 32 + 16 + ln15) * 4 + quad) * 8;
    const int bo0 = (quad * 64 + ni * 32 + ln15) * 8;
    const int bo1 = bo0 + 16 * 8;

    int chunk = 0;
    for (int k = 0; k < 9; ++k) {
        // per-lane bilinear params (pixel = p0 + lane), mask folded into weights
        const float py = tpy[k * 64 + lane], pxx = tpxs[k * 64 + lane], mk = tms[k * 64 + lane];
        const float y0f = floorf(py), x0f = floorf(pxx);
        const int y0 = (int)y0f, x0 = (int)x0f;
        const float wy1 = py - y0f, wx1 = pxx - x0f;
        const float wy0 = 1.f - wy1, wx0 = 1.f - wx1;
        const bool r0v = (y0 >= 0 && y0 < H), r1v = (y0 + 1 >= 0 && y0 + 1 < H);
        const bool c0v = (x0 >= 0 && x0 < W), c1v = (x0 + 1 >= 0 && x0 + 1 < W);
        const float w00 = (r0v && c0v) ? wy0 * wx0 * mk : 0.f;
        const float w01 = (r0v && c1v) ? wy0 * wx1 * mk : 0.f;
        const float w10 = (r1v && c0v) ? wy1 * wx0 * mk : 0.f;
        const float w11 = (r1v && c1v) ? wy1 * wx1 * mk : 0.f;
        const int i00 = (r0v ? y0 : 0) * W + (c0v ? x0 : 0);
        const int i01 = (r0v ? y0 : 0) * W + (c1v ? x0 + 1 : 0);
        const int i10 = (r1v ? y0 + 1 : 0) * W + (c0v ? x0 : 0);
        const int i11 = (r1v ? y0 + 1 : 0) * W + (c1v ? x0 + 1 : 0);

        for (int cc = 0; cc < nch; ++cc, ++chunk) {
            const int s = chunk & 1;
            const int c0c = cc << 5;
            {   // stage A: pixel=lane, 8 channels (quad wv)
                short8 vh, vl;
                const float* pb = xb + (size_t)(c0c + (wv << 3)) * HW;
#pragma unroll
                for (int q = 0; q < 8; ++q) {
                    const float* pl = pb + (size_t)q * HW;
                    const float v = w00 * pl[i00] + w01 * pl[i01] + w10 * pl[i10] + w11 * pl[i11];
                    const u16 hv = f2b(v);
                    vh[q] = (short)hv;
                    if (ASPLIT) vl[q] = (short)f2b(v - b2fu(hv));
                }
                *(short8*)&Ah[s][(lane * 4 + wv) * 8] = vh;
                if (ASPLIT) *(short8*)&Al[s][(lane * 4 + wv) * 8] = vl;
            }
            {   // stage B (wsplit2 layout [k][cc][quad][O][8])
                const size_t base = ((((size_t)k * nch + cc) * 4 + wv) * O + obase + lane) * 8;
                *(short8*)&Bs[s][0][tid * 8] = *(const short8*)(wth + base);
                *(short8*)&Bs[s][1][tid * 8] = *(const short8*)(wtl + base);
            }
            __syncthreads();
            const short8 a0 = *(const short8*)&Ah[s][ao0];
            const short8 a1 = *(const short8*)&Ah[s][ao1];
            const short8 b0h = *(const short8*)&Bs[s][0][bo0];
            const short8 b1h = *(const short8*)&Bs[s][0][bo1];
            const short8 b0l = *(const short8*)&Bs[s][1][bo0];
            const short8 b1l = *(const short8*)&Bs[s][1][bo1];
            acc[0][0] = __builtin_amdgcn_mfma_f32_16x16x32_bf16(a0, b0h, acc[0][0], 0, 0, 0);
            acc[0][0] = __builtin_amdgcn_mfma_f32_16x16x32_bf16(a0, b0l, acc[0][0], 0, 0, 0);
            acc[0][1] = __builtin_amdgcn_mfma_f32_16x16x32_bf16(a0, b1h, acc[0][1], 0, 0, 0);
            acc[0][1] = __builtin_amdgcn_mfma_f32_16x16x32_bf16(a0, b1l, acc[0][1], 0, 0, 0);
            acc[1][0] = __builtin_amdgcn_mfma_f32_16x16x32_bf16(a1, b0h, acc[1][0], 0, 0, 0);
            acc[1][0] = __builtin_amdgcn_mfma_f32_16x16x32_bf16(a1, b0l, acc[1][0], 0, 0, 0);
            acc[1][1] = __builtin_amdgcn_mfma_f32_16x16x32_bf16(a1, b1h, acc[1][1], 0, 0, 0);
            acc[1][1] = __builtin_amdgcn_mfma_f32_16x16x32_bf16(a1, b1l, acc[1][1], 0, 0, 0);
            if (ASPLIT) {
                const short8 a0l = *(const short8*)&Al[s][ao0];
                const short8 a1l = *(const short8*)&Al[s][ao1];
                acc[0][0] = __builtin_amdgcn_mfma_f32_16x16x32_bf16(a0l, b0h, acc[0][0], 0, 0, 0);
                acc[0][1] = __builtin_amdgcn_mfma_f32_16x16x32_bf16(a0l, b1h, acc[0][1], 0, 0, 0);
                acc[1][0] = __builtin_amdgcn_mfma_f32_16x16x32_bf16(a1l, b0h, acc[1][0], 0, 0, 0);
                acc[1][1] = __builtin_amdgcn_mfma_f32_16x16x32_bf16(a1l, b1h, acc[1][1], 0, 0, 0);
            }
        }
    }

#pragma unroll
    for (int ms = 0; ms < 2; ++ms) {
#pragma unroll
        for (int ns = 0; ns < 2; ++ns) {
            const int o = obase + ni * 32 + ns * 16 + ln15;
            const float bv = bias[o];
#pragma unroll
            for (int r = 0; r < 4; ++r) {
                const int pp = p0 + mi * 32 + ms * 16 + (quad << 2) + r;
                ST(out + ((size_t)(b * O + o)) * HW + pp, acc[ms][ns][r] + bv);
            }
        }
    }
}

// ================= old conv_mfma (R14) — off-convs + conv6 =================
template<typename T1, typename T2, int K, bool REFLECT, bool UP, int NTN, int EPI, bool ASPLIT>
__global__ __launch_bounds__(256) void conv_mfma(
        const T1* __restrict__ src1, const T2* __restrict__ src2,
        int C1, int C,
        const u16* __restrict__ wth, const u16* __restrict__ wtl,
        const float* __restrict__ bias,
        void* __restrict__ outv, int O, int H, int W)
{
    constexpr int KK = K * K;
    __shared__ __align__(16) u16 As[64 * 40];
    __shared__ __align__(16) u16 Alo[ASPLIT ? 64 * 40 : 8];
    __shared__ __align__(16) u16 Bh[NTN * 16 * 40];
    __shared__ __align__(16) u16 Bl[NTN * 16 * 40];

    const int tid  = threadIdx.x;
    const int wv   = tid >> 6;
    const int lane = tid & 63;
    const int ln15 = lane & 15;
    const int b    = blockIdx.y;
    const int p0   = blockIdx.x * 64;
    const int obase = blockIdx.z * (NTN * 16);
    const int HW = H * W;
    const int Hs = UP ? (H >> 1) : H;
    const int Ws = UP ? (W >> 1) : W;
    const int HsWs = Hs * Ws;
    const int PAD = K / 2;
    const int C2 = C - C1;
    const int m_stage = tid & 63;

    const int p = p0 + m_stage;
    const int y = p / W, x = p - y * W;
    int off[KK];
    float msk[KK];
#pragma unroll
    for (int ty = 0; ty < K; ++ty) {
#pragma unroll
        for (int tx = 0; tx < K; ++tx) {
            int yy = y + ty - PAD, xx = x + tx - PAD;
            bool vv = true;
            if (REFLECT) {
                yy = yy < 0 ? -yy : yy; yy = yy >= H ? 2 * H - 2 - yy : yy;
                xx = xx < 0 ? -xx : xx; xx = xx >= W ? 2 * W - 2 - xx : xx;
            } else {
                vv = (yy >= 0 && yy < H && xx >= 0 && xx < W);
                yy = yy < 0 ? 0 : (yy >= H ? H - 1 : yy);
                xx = xx < 0 ? 0 : (xx >= W ? W - 1 : xx);
            }
            off[ty * K + tx] = (UP ? (yy >> 1) : yy) * Ws + (UP ? (xx >> 1) : xx);
            msk[ty * K + tx] = vv ? 1.f : 0.f;
        }
    }

    f32x4 acc[NTN];
#pragma unroll
    for (int nt = 0; nt < NTN; ++nt) acc[nt] = (f32x4)0.f;

    const int aswz = (m_stage >> 3) & 3;
    const int awr  = m_stage * 40 + ((wv ^ aswz) << 3);
    const int arow = wv * 16 + ln15;
    const int ard  = arow * 40 + (((lane >> 4) ^ ((arow >> 3) & 3)) << 3);

    const int nch = C >> 5;
    for (int cc = 0; cc < nch; ++cc) {
        const int c0 = cc << 5;
        for (int t = 0; t < KK; ++t) {
            const int offt = off[t];
            const float mskt = msk[t];
            __syncthreads();
            {
                short8 avh, avl;
#pragma unroll
                for (int q = 0; q < 8; ++q) {
                    const int c = c0 + (wv << 3) + q;
                    float v;
                    if (c < C1) v = LD(src1 + ((size_t)(b * C1 + c)) * HsWs + offt);
                    else        v = LD(src2 + ((size_t)(b * C2 + (c - C1))) * HsWs + offt);
                    if (!REFLECT) v *= mskt;
                    const u16 hv = f2b(v);
                    avh[q] = (short)hv;
                    if (ASPLIT) avl[q] = (short)f2b(v - b2fu(hv));
                }
                *(short8*)&As[awr] = avh;
                if (ASPLIT) *(short8*)&Alo[awr] = avl;
            }
            for (int i = tid; i < NTN * 16 * 4; i += 256) {
                const int row = i >> 2, part = i & 3;
                int o = obase + row; if (o >= O) o = O - 1;
                const int pw = row * 40 + ((part ^ ((row >> 3) & 3)) << 3);
                const size_t wb = ((size_t)t * O + o) * C + c0 + (part << 3);
                *(short8*)&Bh[pw] = *(const short8*)(wth + wb);
                *(short8*)&Bl[pw] = *(const short8*)(wtl + wb);
            }
            __syncthreads();
            const short8 a = *(const short8*)&As[ard];
            short8 al;
            if (ASPLIT) al = *(const short8*)&Alo[ard];
#pragma unroll
            for (int nt = 0; nt < NTN; ++nt) {
                const int brow = nt * 16 + ln15;
                const int brd = brow * 40 + (((lane >> 4) ^ ((brow >> 3) & 3)) << 3);
                const short8 bh = *(const short8*)&Bh[brd];
                acc[nt] = __builtin_amdgcn_mfma_f32_16x16x32_bf16(a, bh, acc[nt], 0, 0, 0);
                const short8 bl = *(const short8*)&Bl[brd];
                acc[nt] = __builtin_amdgcn_mfma_f32_16x16x32_bf16(a, bl, acc[nt], 0, 0, 0);
                if (ASPLIT)
                    acc[nt] = __builtin_amdgcn_mfma_f32_16x16x32_bf16(al, bh, acc[nt], 0, 0, 0);
            }
        }
    }

#pragma unroll
    for (int nt = 0; nt < NTN; ++nt) {
        const int o = obase + nt * 16 + ln15;
        if (o < O) {
            const float bv = bias[o];
#pragma unroll
            for (int r = 0; r < 4; ++r) {
                const int pp = p0 + wv * 16 + ((lane >> 4) << 2) + r;
                const float v = acc[nt][r] + bv;
                const size_t oidx = ((size_t)(b * O + o)) * HW + pp;
                if (EPI == 0)      ((float*)outv)[oidx] = v;
                else if (EPI == 1) ((float*)outv)[oidx] = tanhf(v);
                else               ((bf16*)outv)[oidx] = __float2bfloat16(v);
            }
        }
    }
}

// ---------------- instance norm ----------------
template<typename T>
__global__ __launch_bounds__(256) void inorm_kernel(T* __restrict__ buf,
                                                    float* __restrict__ resid,
                                                    int HW, int mode)
{
    __shared__ double sh0[256], sh1[256];
    const int pl = blockIdx.x;
    T* p = buf + (size_t)pl * HW;
    double s = 0.0, ss = 0.0;
    for (int i = threadIdx.x; i < HW; i += 256) {
        float v = LD(p + i);
        s += (double)v; ss += (double)v * (double)v;
    }
    sh0[threadIdx.x] = s; sh1[threadIdx.x] = ss;
    __syncthreads();
    for (int st = 128; st > 0; st >>= 1) {
        if (threadIdx.x < st) {
            sh0[threadIdx.x] += sh0[threadIdx.x + st];
            sh1[threadIdx.x] += sh1[threadIdx.x + st];
        }
        __syncthreads();
    }
    const double mean = sh0[0] / HW;
    const float m = (float)mean;
    const float var = (float)(sh1[0] / HW - mean * mean);
    const float inv = rsqrtf(var + 1e-5f);
    if (mode == 0) {
        for (int i = threadIdx.x; i < HW; i += 256) {
            float v = (LD(p + i) - m) * inv;
            ST(p + i, v > 0.f ? v : 0.f);
        }
    } else {
        float* r = resid + (size_t)pl * HW;
        for (int i = threadIdx.x; i < HW; i += 256)
            r[i] = r[i] + (LD(p + i) - m) * inv;
    }
}

// ---------------- offset_sum ----------------
__global__ void zero1_kernel(float* __restrict__ out) { if (threadIdx.x == 0) out[0] = 0.f; }

__global__ __launch_bounds__(256) void offsum_one(const float* __restrict__ om, int HW,
                                                  float* __restrict__ out)
{
    __shared__ double sh[256];
    const int n = 8 * 18 * HW;
    double s = 0.0;
    for (int i = blockIdx.x * 256 + threadIdx.x; i < n; i += gridDim.x * 256) {
        const int b = i / (18 * HW); const int r = i - b * 18 * HW;
        const int c = r / HW; const int p = r - c * HW;
        s += fabs((double)om[(size_t)(b * 27 + c) * HW + p]);
    }
    sh[threadIdx.x] = s;
    __syncthreads();
    for (int st = 128; st > 0; st >>= 1) {
        if (threadIdx.x < st) sh[threadIdx.x] += sh[threadIdx.x + st];
        __syncthreads();
    }
    if (threadIdx.x == 0) atomicAdd(out, (float)(0.5 * sh[0] / n));
}

// ---------------- launch ----------------
extern "C" void kernel_launch(void* const* d_in, const int* in_sizes, int n_in,
                              void* d_out, int out_size, void* d_ws, size_t ws_size,
                              hipStream_t stream)
{
    if (n_in < 27) return;
    if (out_size < 393217) return;
    if (in_sizes[0] != 8 * 256 * 32 * 32) return;
    if (in_sizes[1] != 8 * 128 * 64 * 64) return;
    if (in_sizes[2] != 8 * 256 * 32 * 32) return;
    if (in_sizes[25] != 128 * 128 * 9) return;
    if (in_sizes[26] != 128) return;

    const float* x        = (const float*)d_in[0];
    const float* skip1    = (const float*)d_in[1];
    const float* skip2    = (const float*)d_in[2];
    const float* rbw[2][2] = {{(const float*)d_in[3], (const float*)d_in[5]},
                              {(const float*)d_in[7], (const float*)d_in[9]}};
    const float* rbb[2][2] = {{(const float*)d_in[4], (const float*)d_in[6]},
                              {(const float*)d_in[8], (const float*)d_in[10]}};
    const float* conv1_w = (const float*)d_in[11]; const float* conv1_b = (const float*)d_in[12];
    const float* conv3_w = (const float*)d_in[13]; const float* conv3_b = (const float*)d_in[14];
    const float* conv5_w = (const float*)d_in[15]; const float* conv5_b = (const float*)d_in[16];
    const float* conv6_w = (const float*)d_in[17]; const float* conv6_b = (const float*)d_in[18];
    const float* dcn2_off_w = (const float*)d_in[19]; const float* dcn2_off_b = (const float*)d_in[20];
    const float* dcn2_w = (const float*)d_in[21]; const float* dcn2_b = (const float*)d_in[22];
    const float* dcn1_off_w = (const float*)d_in[23]; const float* dcn1_off_b = (const float*)d_in[24];
    const float* dcn1_w = (const float*)d_in[25]; const float* dcn1_b = (const float*)d_in[26];

    float* outp = (float*)d_out;

    const size_t NEED_F32 = 9494528ull;      // unchanged, proven R8-R15
    if (ws_size < NEED_F32 * 4ull) return;

    float* ws = (float*)d_ws;
    const size_t NA = 2097152ull;            // 8*256*32*32
    float* A   = ws;                          // x / rb accum / pre2 ; later Ib
    float* Bb  = ws + NA;                     // h / D ; later wm1 ; later Jb(lo half)
    float* Tmp = ws + 2 * NA;                 // rb tmp ; {wm2,wo2} ; wt3 ; wo1 ; Jb(hi half)
    float* om2 = ws + 3 * NA;                 // [221184] ; after offsum: conv6 wt
    float* om1 = om2 + 221184;                // [884736] ; later conv5 wt
    bf16*  Fb  = (bf16*)(om1 + 884736);       // c3 bf16 ; BEFORE conv3: early MFMA weights
    bf16*  Ib  = (bf16*)A;                    // pre1 bf16
    bf16*  Jb  = (bf16*)Bb;                   // c5 bf16 (Bb+Tmp)
    u16*   wm2h = (u16*)Tmp;                  // mdcn2 MFMA w (589824 x2 u16 = 589824 f32-eq)
    u16*   wm2l = wm2h + 589824;
    u16*   wo2h = (u16*)(Tmp + 589824);       // dcn2 off-conv MFMA w (124416 x2 u16)
    u16*   wo2l = wo2h + 124416;
    u16*   wt3h = (u16*)Tmp;                  // conv3 MFMA w (after mdcn2)
    u16*   wt3l = wt3h + 25 * 128 * 512;
    u16*   wo1h = (u16*)Tmp;                  // dcn1 off-conv MFMA w (after conv3)
    u16*   wo1l = wo1h + 62208;
    u16*   wm1h = (u16*)Bb;                   // mdcn1 MFMA w (147456 x2 u16; Bb dead after conv3)
    u16*   wm1l = wm1h + 147456;
    u16*   wt5h = (u16*)om1;                  // conv5 MFMA w (after offsum)
    u16*   wt5l = wt5h + 25 * 64 * 256;
    u16*   wt6h = (u16*)om2;                  // conv6 MFMA w (om2 dead after offsum)
    u16*   wt6l = wt6h + 9408;
    u16*   wEh = (u16*)Fb;                    // early conv MFMA weights (Fb free until conv3)

    copy_kernel<<<8192, 256, 0, stream>>>(x, A, (int)NA);

    // ResBlocks via conv_mfma2 (A+W hi/lo split -> ~f32 precision)
    for (int r = 0; r < 2; ++r) {
        wsplit2_kernel<<<2304, 256, 0, stream>>>(rbw[r][0], wEh, wEh + 589824, 256, 256, 9);
        conv_mfma2<float, float, 3, false, 0, true, 4, 32, 2><<<dim3(16, 8, 4), 256, 0, stream>>>(
            A, (const float*)nullptr, 256, 256, wEh, wEh + 589824, rbb[r][0], Bb, 256, 32, 32);
        inorm_kernel<float><<<2048, 256, 0, stream>>>(Bb, nullptr, 1024, 0);
        wsplit2_kernel<<<2304, 256, 0, stream>>>(rbw[r][1], wEh, wEh + 589824, 256, 256, 9);
        conv_mfma2<float, float, 3, false, 0, true, 4, 32, 2><<<dim3(16, 8, 4), 256, 0, stream>>>(
            Bb, (const float*)nullptr, 256, 256, wEh, wEh + 589824, rbb[r][1], Tmp, 256, 32, 32);
        inorm_kernel<float><<<2048, 256, 0, stream>>>(Tmp, A, 1024, 1);
    }

    // conv1 (5x5, 256->256) via conv_mfma2 + IN/ReLU
    wsplit2_kernel<<<6400, 256, 0, stream>>>(conv1_w, wEh, wEh + 1638400, 256, 256, 25);
    conv_mfma2<float, float, 5, false, 0, true, 6, 32, 2><<<dim3(16, 8, 4), 256, 0, stream>>>(
        A, (const float*)nullptr, 256, 256, wEh, wEh + 1638400, conv1_b, Bb, 256, 32, 32);
    inorm_kernel<float><<<2048, 256, 0, stream>>>(Bb, nullptr, 1024, 0);

    // dcn2: off-conv MFMA -> om2 ; mdcn_mfma -> A (pre2 f32)
    wsplit_kernel<<<486, 256, 0, stream>>>(dcn2_off_w, wo2h, wo2l, 27, 512, 9);
    conv_mfma<float, float, 3, false, false, 2, 0, false><<<dim3(16, 8, 1), 256, 0, stream>>>(
        Bb, skip2, 256, 512, wo2h, wo2l, dcn2_off_b, om2, 27, 32, 32);
    wsplit2_kernel<<<2304, 256, 0, stream>>>(dcn2_w, wm2h, wm2l, 256, 256, 9);
    mdcn_mfma<float, true><<<dim3(16, 8, 4), 256, 0, stream>>>(
        skip2, om2, wm2h, wm2l, dcn2_b, A, 256, 256, 32, 32);

    // conv3: conv_mfma2 (UP), 512->128 @64x64 -> Fb + IN/ReLU
    wsplit2_kernel<<<6400, 256, 0, stream>>>(conv3_w, wt3h, wt3l, 128, 512, 25);
    conv_mfma2<float, float, 5, true, 2, false, 3, 32, 1><<<dim3(64, 8, 2), 256, 0, stream>>>(
        A, Bb, 256, 512, wt3h, wt3l, conv3_b, Fb, 128, 64, 64);
    inorm_kernel<bf16><<<1024, 256, 0, stream>>>(Fb, nullptr, 4096, 0);

    // dcn1: off-conv MFMA -> om1 ; mdcn_mfma -> Ib (pre1 bf16)
    wsplit_kernel<<<243, 256, 0, stream>>>(dcn1_off_w, wo1h, wo1l, 27, 256, 9);
    conv_mfma<bf16, float, 3, false, false, 2, 0, false><<<dim3(64, 8, 1), 256, 0, stream>>>(
        Fb, skip1, 128, 256, wo1h, wo1l, dcn1_off_b, om1, 27, 64, 64);
    wsplit2_kernel<<<576, 256, 0, stream>>>(dcn1_w, wm1h, wm1l, 128, 128, 9);
    mdcn_mfma<bf16, true><<<dim3(64, 8, 2), 256, 0, stream>>>(
        skip1, om1, wm1h, wm1l, dcn1_b, Ib, 128, 128, 64, 64);

    // offset_sum now (frees om1/om2 regions for conv5/conv6 weights)
    zero1_kernel<<<1, 64, 0, stream>>>(outp + 393216);
    offsum_one<<<64, 256, 0, stream>>>(om1, 4096, outp + 393216);
    offsum_one<<<64, 256, 0, stream>>>(om2, 1024, outp + 393216);

    // conv5: conv_mfma2 (UP), 256->64 @128x128 -> Jb + IN/ReLU
    wsplit2_kernel<<<1600, 256, 0, stream>>>(conv5_w, wt5h, wt5l, 64, 256, 25);
    conv_mfma2<bf16, bf16, 5, true, 2, false, 3, 64, 1><<<dim3(256, 8, 1), 256, 0, stream>>>(
        Ib, Fb, 128, 256, wt5h, wt5l, conv5_b, Jb, 64, 128, 128);
    inorm_kernel<bf16><<<512, 256, 0, stream>>>(Jb, nullptr, 16384, 0);

    // conv6: 7x7, 64->3, tanh via conv_mfma -> d_out (f32)
    wsplit_kernel<<<37, 256, 0, stream>>>(conv6_w, wt6h, wt6l, 3, 64, 49);
    conv_mfma<bf16, float, 7, true, false, 1, 1, false><<<dim3(256, 8, 1), 256, 0, stream>>>(
        Jb, (const float*)nullptr, 64, 64, wt6h, wt6l, conv6_b, (void*)outp, 3, 128, 128);
}

// Round 17
// 1666.036 us; speedup vs baseline: 35.7787x; 1.0956x over previous
//
#include <hip/hip_runtime.h>
#include <hip/hip_bf16.h>
#include <math.h>

typedef __hip_bfloat16 bf16;
typedef unsigned short u16;
typedef __attribute__((ext_vector_type(8))) short short8;   // 8 bf16 (4 VGPRs)
typedef __attribute__((ext_vector_type(4))) float f32x4;

__device__ __forceinline__ float LD(const float* p) { return *p; }
__device__ __forceinline__ float LD(const bf16* p)  { return __bfloat162float(*p); }
__device__ __forceinline__ void  ST(float* p, float v) { *p = v; }
__device__ __forceinline__ void  ST(bf16* p, float v)  { *p = __float2bfloat16(v); }
__device__ __forceinline__ u16   f2b(float v) { bf16 h = __float2bfloat16(v); return *reinterpret_cast<u16*>(&h); }
__device__ __forceinline__ float b2fu(u16 u) { bf16 h = *reinterpret_cast<bf16*>(&u); return __bfloat162float(h); }

// ---------------- f32 copy ----------------
__global__ __launch_bounds__(256) void copy_kernel(const float* __restrict__ in,
                                                   float* __restrict__ out, int n) {
    int i = blockIdx.x * blockDim.x + threadIdx.x;
    if (i < n) out[i] = in[i];
}

// ---- wsplit (layout [t][o][c], for off-convs + conv6) ----
__global__ __launch_bounds__(256) void wsplit_kernel(const float* __restrict__ w,
                                                     u16* __restrict__ hi, u16* __restrict__ lo,
                                                     int O, int C, int KK)
{
    const int i = blockIdx.x * 256 + threadIdx.x;
    const int n = O * C * KK;
    if (i >= n) return;
    const int o = i / (C * KK);
    const int r = i - o * C * KK;
    const int c = r / KK;
    const int t = r - c * KK;
    const float v = w[i];
    const bf16 h = __float2bfloat16(v);
    const float hv = __bfloat162float(h);
    const bf16 l = __float2bfloat16(v - hv);
    const size_t dst = ((size_t)t * O + o) * C + c;
    hi[dst] = *(const u16*)&h;
    lo[dst] = *(const u16*)&l;
}

// ---- wsplit2: layout [t][cc][quad][O][8] for conv_mfma3 + mdcn_mfma ----
__global__ __launch_bounds__(256) void wsplit2_kernel(const float* __restrict__ w,
                                                      u16* __restrict__ hi, u16* __restrict__ lo,
                                                      int O, int C, int KK)
{
    const int i = blockIdx.x * 256 + threadIdx.x;
    const int n = O * C * KK;
    if (i >= n) return;
    const int o = i / (C * KK);
    const int r = i - o * C * KK;
    const int c = r / KK;
    const int t = r - c * KK;
    const float v = w[i];
    const bf16 h = __float2bfloat16(v);
    const float hv = __bfloat162float(h);
    const bf16 l = __float2bfloat16(v - hv);
    const int nch = C >> 5;
    const int cc = c >> 5, quad = (c >> 3) & 3, q = c & 7;
    const size_t dst = ((((size_t)t * nch + cc) * 4 + quad) * O + o) * 8 + q;
    hi[dst] = *(const u16*)&h;
    lo[dst] = *(const u16*)&l;
}

// ======== conv_mfma3: tiled-input MFMA conv, B direct from global (REFLECT pad) ========
// 256 thr = 4 waves (2x2): M = MT*32 pixels x N=64 out-chans (obase=z*64).
// Per C-chunk(32): stage A tile once (2 syncs); taps loop barrier-free — B fragments
// loaded straight from global in wsplit2 layout (L2-hot, per-lane dwordx4).
// ASPLIT: input hi/lo tiles -> +MFMA => ~f32. EPI: 0=f32, 2=bf16.
template<typename T1, typename T2, int K, bool UP, int EPI, bool ASPLIT,
         int NR, int NCOL, int MT>
__global__ __launch_bounds__(256) void conv_mfma3(
        const T1* __restrict__ src1, const T2* __restrict__ src2,
        int C1, int C,
        const u16* __restrict__ wth, const u16* __restrict__ wtl,
        const float* __restrict__ bias,
        void* __restrict__ outv, int O, int H, int W)
{
    constexpr int KK = K * K;
    constexpr int ATILE = NR * NCOL * 32;
    __shared__ __align__(16) u16 Ah[ATILE];
    __shared__ __align__(16) u16 Al[ASPLIT ? ATILE : 8];

    const int tid  = threadIdx.x;
    const int lane = tid & 63;
    const int wv   = tid >> 6;
    const int ln15 = lane & 15;
    const int quad = lane >> 4;
    const int mi = wv & 1, ni = wv >> 1;
    const int b = blockIdx.y;
    const int p0 = blockIdx.x * (MT * 32);
    const int obase = blockIdx.z * 64;
    const int HW = H * W;
    const int SH = UP ? (H >> 1) : H;
    const int SW = UP ? (W >> 1) : W;
    const int SHW = SH * SW;
    const int PAD = K / 2;
    const int C2 = C - C1;
    const int nch = C >> 5;

    const int y0 = p0 / W;
    const int rbase = (y0 <= PAD) ? 0 : (UP ? ((y0 - PAD) >> 1) : (y0 - PAD));

    int rs[MT][K], cs[MT][K];
#pragma unroll
    for (int ms = 0; ms < MT; ++ms) {
        const int pm = p0 + mi * (MT * 16) + ms * 16 + ln15;
        const int ym = pm / W, xm = pm - ym * W;
#pragma unroll
        for (int tt = 0; tt < K; ++tt) {
            int yy = ym + tt - PAD;
            yy = yy < 0 ? -yy : yy; yy = yy >= H ? 2 * H - 2 - yy : yy;
            rs[ms][tt] = (UP ? (yy >> 1) : yy) - rbase;
            int xx = xm + tt - PAD;
            xx = xx < 0 ? -xx : xx; xx = xx >= W ? 2 * W - 2 - xx : xx;
            cs[ms][tt] = UP ? (xx >> 1) : xx;
        }
    }

    f32x4 acc[MT][2];
#pragma unroll
    for (int i = 0; i < MT; ++i)
#pragma unroll
        for (int j = 0; j < 2; ++j) acc[i][j] = (f32x4)0.f;

    for (int cc = 0; cc < nch; ++cc) {
        const int c0 = cc << 5;
        __syncthreads();                       // prior chunk's reads done
        for (int idx = tid; idx < NR * NCOL * 4; idx += 256) {
            const int c_ = idx % NCOL;
            const int r_ = (idx / NCOL) % NR;
            const int cq = idx / (NCOL * NR);
            int rr = rbase + r_; rr = rr >= SH ? SH - 1 : rr;
            const int sidx = rr * SW + c_;
            short8 vh, vl;
#pragma unroll
            for (int q = 0; q < 8; ++q) {
                const int c = c0 + cq * 8 + q;
                float v;
                if (c < C1) v = LD(src1 + (size_t)(b * C1 + c) * SHW + sidx);
                else        v = LD(src2 + (size_t)(b * C2 + (c - C1)) * SHW + sidx);
                const u16 hv = f2b(v);
                vh[q] = (short)hv;
                if (ASPLIT) vl[q] = (short)f2b(v - b2fu(hv));
            }
            *(short8*)&Ah[idx * 8] = vh;
            if (ASPLIT) *(short8*)&Al[idx * 8] = vl;
        }
        __syncthreads();                       // tile ready

#pragma unroll
        for (int t = 0; t < KK; ++t) {
            const int ty = t / K, tx = t - ty * K;
            // B fragments straight from global (wsplit2 layout)
            const size_t wb0 = ((((size_t)t * nch + cc) * 4 + quad) * O
                                + obase + ni * 32 + ln15) * 8;
            const short8 b0h = *(const short8*)(wth + wb0);
            const short8 b1h = *(const short8*)(wth + wb0 + 128);
            const short8 b0l = *(const short8*)(wtl + wb0);
            const short8 b1l = *(const short8*)(wtl + wb0 + 128);
#pragma unroll
            for (int ms = 0; ms < MT; ++ms) {
                const int ao = ((quad * NR + rs[ms][ty]) * NCOL + cs[ms][tx]) * 8;
                const short8 a = *(const short8*)&Ah[ao];
                acc[ms][0] = __builtin_amdgcn_mfma_f32_16x16x32_bf16(a, b0h, acc[ms][0], 0, 0, 0);
                acc[ms][0] = __builtin_amdgcn_mfma_f32_16x16x32_bf16(a, b0l, acc[ms][0], 0, 0, 0);
                acc[ms][1] = __builtin_amdgcn_mfma_f32_16x16x32_bf16(a, b1h, acc[ms][1], 0, 0, 0);
                acc[ms][1] = __builtin_amdgcn_mfma_f32_16x16x32_bf16(a, b1l, acc[ms][1], 0, 0, 0);
                if (ASPLIT) {
                    const short8 al = *(const short8*)&Al[ao];
                    acc[ms][0] = __builtin_amdgcn_mfma_f32_16x16x32_bf16(al, b0h, acc[ms][0], 0, 0, 0);
                    acc[ms][1] = __builtin_amdgcn_mfma_f32_16x16x32_bf16(al, b1h, acc[ms][1], 0, 0, 0);
                }
            }
        }
    }

    // epilogue: D col=ln15 -> o, row=quad*4+r -> pixel
#pragma unroll
    for (int ms = 0; ms < MT; ++ms) {
#pragma unroll
        for (int ns = 0; ns < 2; ++ns) {
            const int o = obase + ni * 32 + ns * 16 + ln15;
            const float bv = bias[o];
            const f32x4 av = acc[ms][ns];
#pragma unroll
            for (int r = 0; r < 4; ++r) {
                const int pp = p0 + mi * (MT * 16) + ms * 16 + (quad << 2) + r;
                const float v = av[r] + bv;
                const size_t oidx = ((size_t)(b * O + o)) * HW + pp;
                if (EPI == 0) ((float*)outv)[oidx] = v;
                else          ((bf16*)outv)[oidx] = __float2bfloat16(v);
            }
        }
    }
}

// ================= mdcn_mfma: deformable conv contraction on MFMA =================
template<typename OT, bool ASPLIT>
__global__ __launch_bounds__(256) void mdcn_mfma(
        const float* __restrict__ skip, const float* __restrict__ om,
        const u16* __restrict__ wth, const u16* __restrict__ wtl,
        const float* __restrict__ bias,
        OT* __restrict__ out, int C, int O, int H, int W)
{
    __shared__ float tpy[576], tpxs[576], tms[576];
    __shared__ __align__(16) u16 Ah[2][2048];
    __shared__ __align__(16) u16 Al[ASPLIT ? 2 : 1][2048];
    __shared__ __align__(16) u16 Bs[2][2][2048];

    const int tid = threadIdx.x;
    const int lane = tid & 63;
    const int wv = tid >> 6;
    const int ln15 = lane & 15;
    const int quad = lane >> 4;
    const int mi = wv & 1, ni = wv >> 1;
    const int b = blockIdx.y;
    const int p0 = blockIdx.x * 64;
    const int obase = blockIdx.z * 64;
    const int HW = H * W;
    const int nch = C >> 5;

    const float* omb = om + (size_t)b * 27 * HW;
    for (int i = tid; i < 576; i += 256) {
        const int k = i >> 6, px_ = i & 63;
        const int p = p0 + px_;
        const int y = p / W, x = p - y * W;
        const float dy = omb[(2 * k) * HW + p];
        const float dx = omb[(2 * k + 1) * HW + p];
        const float mk = 1.f / (1.f + expf(-omb[(18 + k) * HW + p]));
        float py = (float)(y + k / 3 - 1) + dy;
        float pxx = (float)(x + k % 3 - 1) + dx;
        py  = fminf(fmaxf(py, -2.f), (float)H + 1.f);
        pxx = fminf(fmaxf(pxx, -2.f), (float)W + 1.f);
        tpy[i] = py; tpxs[i] = pxx; tms[i] = mk;
    }
    __syncthreads();

    f32x4 acc[2][2];
#pragma unroll
    for (int i = 0; i < 2; ++i)
#pragma unroll
        for (int j = 0; j < 2; ++j) acc[i][j] = (f32x4)0.f;

    const float* xb = skip + (size_t)b * C * HW;
    const int ao0 = ((mi * 32 + ln15) * 4 + quad) * 8;
    const int ao1 = ((mi * 32 + 16 + ln15) * 4 + quad) * 8;
    const int bo0 = (quad * 64 + ni * 32 + ln15) * 8;
    const int bo1 = bo0 + 16 * 8;

    int chunk = 0;
    for (int k = 0; k < 9; ++k) {
        const float py = tpy[k * 64 + lane], pxx = tpxs[k * 64 + lane], mk = tms[k * 64 + lane];
        const float y0f = floorf(py), x0f = floorf(pxx);
        const int y0 = (int)y0f, x0 = (int)x0f;
        const float wy1 = py - y0f, wx1 = pxx - x0f;
        const float wy0 = 1.f - wy1, wx0 = 1.f - wx1;
        const bool r0v = (y0 >= 0 && y0 < H), r1v = (y0 + 1 >= 0 && y0 + 1 < H);
        const bool c0v = (x0 >= 0 && x0 < W), c1v = (x0 + 1 >= 0 && x0 + 1 < W);
        const float w00 = (r0v && c0v) ? wy0 * wx0 * mk : 0.f;
        const float w01 = (r0v && c1v) ? wy0 * wx1 * mk : 0.f;
        const float w10 = (r1v && c0v) ? wy1 * wx0 * mk : 0.f;
        const float w11 = (r1v && c1v) ? wy1 * wx1 * mk : 0.f;
        const int i00 = (r0v ? y0 : 0) * W + (c0v ? x0 : 0);
        const int i01 = (r0v ? y0 : 0) * W + (c1v ? x0 + 1 : 0);
        const int i10 = (r1v ? y0 + 1 : 0) * W + (c0v ? x0 : 0);
        const int i11 = (r1v ? y0 + 1 : 0) * W + (c1v ? x0 + 1 : 0);

        for (int cc = 0; cc < nch; ++cc, ++chunk) {
            const int s = chunk & 1;
            const int c0c = cc << 5;
            {
                short8 vh, vl;
                const float* pb = xb + (size_t)(c0c + (wv << 3)) * HW;
#pragma unroll
                for (int q = 0; q < 8; ++q) {
                    const float* pl = pb + (size_t)q * HW;
                    const float v = w00 * pl[i00] + w01 * pl[i01] + w10 * pl[i10] + w11 * pl[i11];
                    const u16 hv = f2b(v);
                    vh[q] = (short)hv;
                    if (ASPLIT) vl[q] = (short)f2b(v - b2fu(hv));
                }
                *(short8*)&Ah[s][(lane * 4 + wv) * 8] = vh;
                if (ASPLIT) *(short8*)&Al[s][(lane * 4 + wv) * 8] = vl;
            }
            {
                const size_t base = ((((size_t)k * nch + cc) * 4 + wv) * O + obase + lane) * 8;
                *(short8*)&Bs[s][0][tid * 8] = *(const short8*)(wth + base);
                *(short8*)&Bs[s][1][tid * 8] = *(const short8*)(wtl + base);
            }
            __syncthreads();
            const short8 a0 = *(const short8*)&Ah[s][ao0];
            const short8 a1 = *(const short8*)&Ah[s][ao1];
            const short8 b0h = *(const short8*)&Bs[s][0][bo0];
            const short8 b1h = *(const short8*)&Bs[s][0][bo1];
            const short8 b0l = *(const short8*)&Bs[s][1][bo0];
            const short8 b1l = *(const short8*)&Bs[s][1][bo1];
            acc[0][0] = __builtin_amdgcn_mfma_f32_16x16x32_bf16(a0, b0h, acc[0][0], 0, 0, 0);
            acc[0][0] = __builtin_amdgcn_mfma_f32_16x16x32_bf16(a0, b0l, acc[0][0], 0, 0, 0);
            acc[0][1] = __builtin_amdgcn_mfma_f32_16x16x32_bf16(a0, b1h, acc[0][1], 0, 0, 0);
            acc[0][1] = __builtin_amdgcn_mfma_f32_16x16x32_bf16(a0, b1l, acc[0][1], 0, 0, 0);
            acc[1][0] = __builtin_amdgcn_mfma_f32_16x16x32_bf16(a1, b0h, acc[1][0], 0, 0, 0);
            acc[1][0] = __builtin_amdgcn_mfma_f32_16x16x32_bf16(a1, b0l, acc[1][0], 0, 0, 0);
            acc[1][1] = __builtin_amdgcn_mfma_f32_16x16x32_bf16(a1, b1h, acc[1][1], 0, 0, 0);
            acc[1][1] = __builtin_amdgcn_mfma_f32_16x16x32_bf16(a1, b1l, acc[1][1], 0, 0, 0);
            if (ASPLIT) {
                const short8 a0l = *(const short8*)&Al[s][ao0];
                const short8 a1l = *(const short8*)&Al[s][ao1];
                acc[0][0] = __builtin_amdgcn_mfma_f32_16x16x32_bf16(a0l, b0h, acc[0][0], 0, 0, 0);
                acc[0][1] = __builtin_amdgcn_mfma_f32_16x16x32_bf16(a0l, b1h, acc[0][1], 0, 0, 0);
                acc[1][0] = __builtin_amdgcn_mfma_f32_16x16x32_bf16(a1l, b0h, acc[1][0], 0, 0, 0);
                acc[1][1] = __builtin_amdgcn_mfma_f32_16x16x32_bf16(a1l, b1h, acc[1][1], 0, 0, 0);
            }
        }
    }

#pragma unroll
    for (int ms = 0; ms < 2; ++ms) {
#pragma unroll
        for (int ns = 0; ns < 2; ++ns) {
            const int o = obase + ni * 32 + ns * 16 + ln15;
            const float bv = bias[o];
#pragma unroll
            for (int r = 0; r < 4; ++r) {
                const int pp = p0 + mi * 32 + ms * 16 + (quad << 2) + r;
                ST(out + ((size_t)(b * O + o)) * HW + pp, acc[ms][ns][r] + bv);
            }
        }
    }
}

// ================= old conv_mfma (R14) — off-convs + conv6 =================
template<typename T1, typename T2, int K, bool REFLECT, bool UP, int NTN, int EPI, bool ASPLIT>
__global__ __launch_bounds__(256) void conv_mfma(
        const T1* __restrict__ src1, const T2* __restrict__ src2,
        int C1, int C,
        const u16* __restrict__ wth, const u16* __restrict__ wtl,
        const float* __restrict__ bias,
        void* __restrict__ outv, int O, int H, int W)
{
    constexpr int KK = K * K;
    __shared__ __align__(16) u16 As[64 * 40];
    __shared__ __align__(16) u16 Alo[ASPLIT ? 64 * 40 : 8];
    __shared__ __align__(16) u16 Bh[NTN * 16 * 40];
    __shared__ __align__(16) u16 Bl[NTN * 16 * 40];

    const int tid  = threadIdx.x;
    const int wv   = tid >> 6;
    const int lane = tid & 63;
    const int ln15 = lane & 15;
    const int b    = blockIdx.y;
    const int p0   = blockIdx.x * 64;
    const int obase = blockIdx.z * (NTN * 16);
    const int HW = H * W;
    const int Hs = UP ? (H >> 1) : H;
    const int Ws = UP ? (W >> 1) : W;
    const int HsWs = Hs * Ws;
    const int PAD = K / 2;
    const int C2 = C - C1;
    const int m_stage = tid & 63;

    const int p = p0 + m_stage;
    const int y = p / W, x = p - y * W;
    int off[KK];
    float msk[KK];
#pragma unroll
    for (int ty = 0; ty < K; ++ty) {
#pragma unroll
        for (int tx = 0; tx < K; ++tx) {
            int yy = y + ty - PAD, xx = x + tx - PAD;
            bool vv = true;
            if (REFLECT) {
                yy = yy < 0 ? -yy : yy; yy = yy >= H ? 2 * H - 2 - yy : yy;
                xx = xx < 0 ? -xx : xx; xx = xx >= W ? 2 * W - 2 - xx : xx;
            } else {
                vv = (yy >= 0 && yy < H && xx >= 0 && xx < W);
                yy = yy < 0 ? 0 : (yy >= H ? H - 1 : yy);
                xx = xx < 0 ? 0 : (xx >= W ? W - 1 : xx);
            }
            off[ty * K + tx] = (UP ? (yy >> 1) : yy) * Ws + (UP ? (xx >> 1) : xx);
            msk[ty * K + tx] = vv ? 1.f : 0.f;
        }
    }

    f32x4 acc[NTN];
#pragma unroll
    for (int nt = 0; nt < NTN; ++nt) acc[nt] = (f32x4)0.f;

    const int aswz = (m_stage >> 3) & 3;
    const int awr  = m_stage * 40 + ((wv ^ aswz) << 3);
    const int arow = wv * 16 + ln15;
    const int ard  = arow * 40 + (((lane >> 4) ^ ((arow >> 3) & 3)) << 3);

    const int nch = C >> 5;
    for (int cc = 0; cc < nch; ++cc) {
        const int c0 = cc << 5;
        for (int t = 0; t < KK; ++t) {
            const int offt = off[t];
            const float mskt = msk[t];
            __syncthreads();
            {
                short8 avh, avl;
#pragma unroll
                for (int q = 0; q < 8; ++q) {
                    const int c = c0 + (wv << 3) + q;
                    float v;
                    if (c < C1) v = LD(src1 + ((size_t)(b * C1 + c)) * HsWs + offt);
                    else        v = LD(src2 + ((size_t)(b * C2 + (c - C1))) * HsWs + offt);
                    if (!REFLECT) v *= mskt;
                    const u16 hv = f2b(v);
                    avh[q] = (short)hv;
                    if (ASPLIT) avl[q] = (short)f2b(v - b2fu(hv));
                }
                *(short8*)&As[awr] = avh;
                if (ASPLIT) *(short8*)&Alo[awr] = avl;
            }
            for (int i = tid; i < NTN * 16 * 4; i += 256) {
                const int row = i >> 2, part = i & 3;
                int o = obase + row; if (o >= O) o = O - 1;
                const int pw = row * 40 + ((part ^ ((row >> 3) & 3)) << 3);
                const size_t wb = ((size_t)t * O + o) * C + c0 + (part << 3);
                *(short8*)&Bh[pw] = *(const short8*)(wth + wb);
                *(short8*)&Bl[pw] = *(const short8*)(wtl + wb);
            }
            __syncthreads();
            const short8 a = *(const short8*)&As[ard];
            short8 al;
            if (ASPLIT) al = *(const short8*)&Alo[ard];
#pragma unroll
            for (int nt = 0; nt < NTN; ++nt) {
                const int brow = nt * 16 + ln15;
                const int brd = brow * 40 + (((lane >> 4) ^ ((brow >> 3) & 3)) << 3);
                const short8 bh = *(const short8*)&Bh[brd];
                acc[nt] = __builtin_amdgcn_mfma_f32_16x16x32_bf16(a, bh, acc[nt], 0, 0, 0);
                const short8 bl = *(const short8*)&Bl[brd];
                acc[nt] = __builtin_amdgcn_mfma_f32_16x16x32_bf16(a, bl, acc[nt], 0, 0, 0);
                if (ASPLIT)
                    acc[nt] = __builtin_amdgcn_mfma_f32_16x16x32_bf16(al, bh, acc[nt], 0, 0, 0);
            }
        }
    }

#pragma unroll
    for (int nt = 0; nt < NTN; ++nt) {
        const int o = obase + nt * 16 + ln15;
        if (o < O) {
            const float bv = bias[o];
#pragma unroll
            for (int r = 0; r < 4; ++r) {
                const int pp = p0 + wv * 16 + ((lane >> 4) << 2) + r;
                const float v = acc[nt][r] + bv;
                const size_t oidx = ((size_t)(b * O + o)) * HW + pp;
                if (EPI == 0)      ((float*)outv)[oidx] = v;
                else if (EPI == 1) ((float*)outv)[oidx] = tanhf(v);
                else               ((bf16*)outv)[oidx] = __float2bfloat16(v);
            }
        }
    }
}

// ---------------- instance norm ----------------
template<typename T>
__global__ __launch_bounds__(256) void inorm_kernel(T* __restrict__ buf,
                                                    float* __restrict__ resid,
                                                    int HW, int mode)
{
    __shared__ double sh0[256], sh1[256];
    const int pl = blockIdx.x;
    T* p = buf + (size_t)pl * HW;
    double s = 0.0, ss = 0.0;
    for (int i = threadIdx.x; i < HW; i += 256) {
        float v = LD(p + i);
        s += (double)v; ss += (double)v * (double)v;
    }
    sh0[threadIdx.x] = s; sh1[threadIdx.x] = ss;
    __syncthreads();
    for (int st = 128; st > 0; st >>= 1) {
        if (threadIdx.x < st) {
            sh0[threadIdx.x] += sh0[threadIdx.x + st];
            sh1[threadIdx.x] += sh1[threadIdx.x + st];
        }
        __syncthreads();
    }
    const double mean = sh0[0] / HW;
    const float m = (float)mean;
    const float var = (float)(sh1[0] / HW - mean * mean);
    const float inv = rsqrtf(var + 1e-5f);
    if (mode == 0) {
        for (int i = threadIdx.x; i < HW; i += 256) {
            float v = (LD(p + i) - m) * inv;
            ST(p + i, v > 0.f ? v : 0.f);
        }
    } else {
        float* r = resid + (size_t)pl * HW;
        for (int i = threadIdx.x; i < HW; i += 256)
            r[i] = r[i] + (LD(p + i) - m) * inv;
    }
}

// ---------------- offset_sum ----------------
__global__ void zero1_kernel(float* __restrict__ out) { if (threadIdx.x == 0) out[0] = 0.f; }

__global__ __launch_bounds__(256) void offsum_one(const float* __restrict__ om, int HW,
                                                  float* __restrict__ out)
{
    __shared__ double sh[256];
    const int n = 8 * 18 * HW;
    double s = 0.0;
    for (int i = blockIdx.x * 256 + threadIdx.x; i < n; i += gridDim.x * 256) {
        const int b = i / (18 * HW); const int r = i - b * 18 * HW;
        const int c = r / HW; const int p = r - c * HW;
        s += fabs((double)om[(size_t)(b * 27 + c) * HW + p]);
    }
    sh[threadIdx.x] = s;
    __syncthreads();
    for (int st = 128; st > 0; st >>= 1) {
        if (threadIdx.x < st) sh[threadIdx.x] += sh[threadIdx.x + st];
        __syncthreads();
    }
    if (threadIdx.x == 0) atomicAdd(out, (float)(0.5 * sh[0] / n));
}

// ---------------- launch ----------------
extern "C" void kernel_launch(void* const* d_in, const int* in_sizes, int n_in,
                              void* d_out, int out_size, void* d_ws, size_t ws_size,
                              hipStream_t stream)
{
    if (n_in < 27) return;
    if (out_size < 393217) return;
    if (in_sizes[0] != 8 * 256 * 32 * 32) return;
    if (in_sizes[1] != 8 * 128 * 64 * 64) return;
    if (in_sizes[2] != 8 * 256 * 32 * 32) return;
    if (in_sizes[25] != 128 * 128 * 9) return;
    if (in_sizes[26] != 128) return;

    const float* x        = (const float*)d_in[0];
    const float* skip1    = (const float*)d_in[1];
    const float* skip2    = (const float*)d_in[2];
    const float* rbw[2][2] = {{(const float*)d_in[3], (const float*)d_in[5]},
                              {(const float*)d_in[7], (const float*)d_in[9]}};
    const float* rbb[2][2] = {{(const float*)d_in[4], (const float*)d_in[6]},
                              {(const float*)d_in[8], (const float*)d_in[10]}};
    const float* conv1_w = (const float*)d_in[11]; const float* conv1_b = (const float*)d_in[12];
    const float* conv3_w = (const float*)d_in[13]; const float* conv3_b = (const float*)d_in[14];
    const float* conv5_w = (const float*)d_in[15]; const float* conv5_b = (const float*)d_in[16];
    const float* conv6_w = (const float*)d_in[17]; const float* conv6_b = (const float*)d_in[18];
    const float* dcn2_off_w = (const float*)d_in[19]; const float* dcn2_off_b = (const float*)d_in[20];
    const float* dcn2_w = (const float*)d_in[21]; const float* dcn2_b = (const float*)d_in[22];
    const float* dcn1_off_w = (const float*)d_in[23]; const float* dcn1_off_b = (const float*)d_in[24];
    const float* dcn1_w = (const float*)d_in[25]; const float* dcn1_b = (const float*)d_in[26];

    float* outp = (float*)d_out;

    const size_t NEED_F32 = 9494528ull;      // unchanged, proven R8-R16
    if (ws_size < NEED_F32 * 4ull) return;

    float* ws = (float*)d_ws;
    const size_t NA = 2097152ull;            // 8*256*32*32
    float* A   = ws;                          // x / rb accum / pre2 ; later Ib
    float* Bb  = ws + NA;                     // h / D ; later wm1 ; later Jb(lo half)
    float* Tmp = ws + 2 * NA;                 // rb tmp ; {wm2,wo2} ; wt3 ; wo1 ; Jb(hi half)
    float* om2 = ws + 3 * NA;                 // [221184] ; after offsum: conv6 wt
    float* om1 = om2 + 221184;                // [884736] ; later conv5 wt
    bf16*  Fb  = (bf16*)(om1 + 884736);       // c3 bf16 ; BEFORE conv3: early MFMA weights
    bf16*  Ib  = (bf16*)A;                    // pre1 bf16
    bf16*  Jb  = (bf16*)Bb;                   // c5 bf16 (Bb+Tmp)
    u16*   wm2h = (u16*)Tmp;                  // mdcn2 MFMA w
    u16*   wm2l = wm2h + 589824;
    u16*   wo2h = (u16*)(Tmp + 589824);       // dcn2 off-conv MFMA w
    u16*   wo2l = wo2h + 124416;
    u16*   wt3h = (u16*)Tmp;                  // conv3 MFMA w (after mdcn2)
    u16*   wt3l = wt3h + 25 * 128 * 512;
    u16*   wo1h = (u16*)Tmp;                  // dcn1 off-conv MFMA w (after conv3)
    u16*   wo1l = wo1h + 62208;
    u16*   wm1h = (u16*)Bb;                   // mdcn1 MFMA w (Bb dead after conv3)
    u16*   wm1l = wm1h + 147456;
    u16*   wt5h = (u16*)om1;                  // conv5 MFMA w (after offsum)
    u16*   wt5l = wt5h + 25 * 64 * 256;
    u16*   wt6h = (u16*)om2;                  // conv6 MFMA w (om2 dead after offsum)
    u16*   wt6l = wt6h + 9408;
    u16*   wEh = (u16*)Fb;                    // early conv MFMA weights (Fb free until conv3)

    copy_kernel<<<8192, 256, 0, stream>>>(x, A, (int)NA);

    // ResBlocks via conv_mfma3 (A+W hi/lo split -> ~f32 precision)
    for (int r = 0; r < 2; ++r) {
        wsplit2_kernel<<<2304, 256, 0, stream>>>(rbw[r][0], wEh, wEh + 589824, 256, 256, 9);
        conv_mfma3<float, float, 3, false, 0, true, 4, 32, 2><<<dim3(16, 8, 4), 256, 0, stream>>>(
            A, (const float*)nullptr, 256, 256, wEh, wEh + 589824, rbb[r][0], Bb, 256, 32, 32);
        inorm_kernel<float><<<2048, 256, 0, stream>>>(Bb, nullptr, 1024, 0);
        wsplit2_kernel<<<2304, 256, 0, stream>>>(rbw[r][1], wEh, wEh + 589824, 256, 256, 9);
        conv_mfma3<float, float, 3, false, 0, true, 4, 32, 2><<<dim3(16, 8, 4), 256, 0, stream>>>(
            Bb, (const float*)nullptr, 256, 256, wEh, wEh + 589824, rbb[r][1], Tmp, 256, 32, 32);
        inorm_kernel<float><<<2048, 256, 0, stream>>>(Tmp, A, 1024, 1);
    }

    // conv1 (5x5, 256->256) via conv_mfma3 + IN/ReLU
    wsplit2_kernel<<<6400, 256, 0, stream>>>(conv1_w, wEh, wEh + 1638400, 256, 256, 25);
    conv_mfma3<float, float, 5, false, 0, true, 6, 32, 2><<<dim3(16, 8, 4), 256, 0, stream>>>(
        A, (const float*)nullptr, 256, 256, wEh, wEh + 1638400, conv1_b, Bb, 256, 32, 32);
    inorm_kernel<float><<<2048, 256, 0, stream>>>(Bb, nullptr, 1024, 0);

    // dcn2: off-conv MFMA -> om2 ; mdcn_mfma -> A (pre2 f32)
    wsplit_kernel<<<486, 256, 0, stream>>>(dcn2_off_w, wo2h, wo2l, 27, 512, 9);
    conv_mfma<float, float, 3, false, false, 2, 0, false><<<dim3(16, 8, 1), 256, 0, stream>>>(
        Bb, skip2, 256, 512, wo2h, wo2l, dcn2_off_b, om2, 27, 32, 32);
    wsplit2_kernel<<<2304, 256, 0, stream>>>(dcn2_w, wm2h, wm2l, 256, 256, 9);
    mdcn_mfma<float, true><<<dim3(16, 8, 4), 256, 0, stream>>>(
        skip2, om2, wm2h, wm2l, dcn2_b, A, 256, 256, 32, 32);

    // conv3: conv_mfma3 (UP, MT=4 -> M=128 = 2 rows), 512->128 @64x64 -> Fb + IN/ReLU
    wsplit2_kernel<<<6400, 256, 0, stream>>>(conv3_w, wt3h, wt3l, 128, 512, 25);
    conv_mfma3<float, float, 5, true, 2, false, 4, 32, 4><<<dim3(32, 8, 2), 256, 0, stream>>>(
        A, Bb, 256, 512, wt3h, wt3l, conv3_b, Fb, 128, 64, 64);
    inorm_kernel<bf16><<<1024, 256, 0, stream>>>(Fb, nullptr, 4096, 0);

    // dcn1: off-conv MFMA -> om1 ; mdcn_mfma -> Ib (pre1 bf16)
    wsplit_kernel<<<243, 256, 0, stream>>>(dcn1_off_w, wo1h, wo1l, 27, 256, 9);
    conv_mfma<bf16, float, 3, false, false, 2, 0, false><<<dim3(64, 8, 1), 256, 0, stream>>>(
        Fb, skip1, 128, 256, wo1h, wo1l, dcn1_off_b, om1, 27, 64, 64);
    wsplit2_kernel<<<576, 256, 0, stream>>>(dcn1_w, wm1h, wm1l, 128, 128, 9);
    mdcn_mfma<bf16, true><<<dim3(64, 8, 2), 256, 0, stream>>>(
        skip1, om1, wm1h, wm1l, dcn1_b, Ib, 128, 128, 64, 64);

    // offset_sum now (frees om1/om2 regions for conv5/conv6 weights)
    zero1_kernel<<<1, 64, 0, stream>>>(outp + 393216);
    offsum_one<<<64, 256, 0, stream>>>(om1, 4096, outp + 393216);
    offsum_one<<<64, 256, 0, stream>>>(om2, 1024, outp + 393216);

    // conv5: conv_mfma3 (UP, MT=4 -> M=128 = 1 full row), 256->64 @128x128 -> Jb + IN/ReLU
    wsplit2_kernel<<<1600, 256, 0, stream>>>(conv5_w, wt5h, wt5l, 64, 256, 25);
    conv_mfma3<bf16, bf16, 5, true, 2, false, 3, 64, 4><<<dim3(128, 8, 1), 256, 0, stream>>>(
        Ib, Fb, 128, 256, wt5h, wt5l, conv5_b, Jb, 64, 128, 128);
    inorm_kernel<bf16><<<512, 256, 0, stream>>>(Jb, nullptr, 16384, 0);

    // conv6: 7x7, 64->3, tanh via conv_mfma -> d_out (f32)
    wsplit_kernel<<<37, 256, 0, stream>>>(conv6_w, wt6h, wt6l, 3, 64, 49);
    conv_mfma<bf16, float, 7, true, false, 1, 1, false><<<dim3(256, 8, 1), 256, 0, stream>>>(
        Jb, (const float*)nullptr, 64, 64, wt6h, wt6l, conv6_b, (void*)outp, 3, 128, 128);
}

// Round 18
// 1639.917 us; speedup vs baseline: 36.3486x; 1.0159x over previous
//
#include <hip/hip_runtime.h>
#include <hip/hip_bf16.h>
#include <math.h>

typedef __hip_bfloat16 bf16;
typedef unsigned short u16;
typedef __attribute__((ext_vector_type(8))) short short8;   // 8 bf16 (4 VGPRs)
typedef __attribute__((ext_vector_type(4))) float f32x4;

__device__ __forceinline__ float LD(const float* p) { return *p; }
__device__ __forceinline__ float LD(const bf16* p)  { return __bfloat162float(*p); }
__device__ __forceinline__ void  ST(float* p, float v) { *p = v; }
__device__ __forceinline__ void  ST(bf16* p, float v)  { *p = __float2bfloat16(v); }
__device__ __forceinline__ u16   f2b(float v) { bf16 h = __float2bfloat16(v); return *reinterpret_cast<u16*>(&h); }
__device__ __forceinline__ float b2fu(u16 u) { bf16 h = *reinterpret_cast<bf16*>(&u); return __bfloat162float(h); }

// ---------------- f32 copy ----------------
__global__ __launch_bounds__(256) void copy_kernel(const float* __restrict__ in,
                                                   float* __restrict__ out, int n) {
    int i = blockIdx.x * blockDim.x + threadIdx.x;
    if (i < n) out[i] = in[i];
}

// ---- wsplit (layout [t][o][c], for off-convs + conv6) ----
__global__ __launch_bounds__(256) void wsplit_kernel(const float* __restrict__ w,
                                                     u16* __restrict__ hi, u16* __restrict__ lo,
                                                     int O, int C, int KK)
{
    const int i = blockIdx.x * 256 + threadIdx.x;
    const int n = O * C * KK;
    if (i >= n) return;
    const int o = i / (C * KK);
    const int r = i - o * C * KK;
    const int c = r / KK;
    const int t = r - c * KK;
    const float v = w[i];
    const bf16 h = __float2bfloat16(v);
    const float hv = __bfloat162float(h);
    const bf16 l = __float2bfloat16(v - hv);
    const size_t dst = ((size_t)t * O + o) * C + c;
    hi[dst] = *(const u16*)&h;
    lo[dst] = *(const u16*)&l;
}

// ---- wsplit2: layout [t][cc][quad][O][8] for conv_mfma3 + mdcn_mfma ----
__global__ __launch_bounds__(256) void wsplit2_kernel(const float* __restrict__ w,
                                                      u16* __restrict__ hi, u16* __restrict__ lo,
                                                      int O, int C, int KK)
{
    const int i = blockIdx.x * 256 + threadIdx.x;
    const int n = O * C * KK;
    if (i >= n) return;
    const int o = i / (C * KK);
    const int r = i - o * C * KK;
    const int c = r / KK;
    const int t = r - c * KK;
    const float v = w[i];
    const bf16 h = __float2bfloat16(v);
    const float hv = __bfloat162float(h);
    const bf16 l = __float2bfloat16(v - hv);
    const int nch = C >> 5;
    const int cc = c >> 5, quad = (c >> 3) & 3, q = c & 7;
    const size_t dst = ((((size_t)t * nch + cc) * 4 + quad) * O + o) * 8 + q;
    hi[dst] = *(const u16*)&h;
    lo[dst] = *(const u16*)&l;
}

// ======== conv_mfma3: tiled-input MFMA conv, B direct from global (REFLECT pad) ========
template<typename T1, typename T2, int K, bool UP, int EPI, bool ASPLIT,
         int NR, int NCOL, int MT>
__global__ __launch_bounds__(256) void conv_mfma3(
        const T1* __restrict__ src1, const T2* __restrict__ src2,
        int C1, int C,
        const u16* __restrict__ wth, const u16* __restrict__ wtl,
        const float* __restrict__ bias,
        void* __restrict__ outv, int O, int H, int W)
{
    constexpr int KK = K * K;
    constexpr int ATILE = NR * NCOL * 32;
    __shared__ __align__(16) u16 Ah[ATILE];
    __shared__ __align__(16) u16 Al[ASPLIT ? ATILE : 8];

    const int tid  = threadIdx.x;
    const int lane = tid & 63;
    const int wv   = tid >> 6;
    const int ln15 = lane & 15;
    const int quad = lane >> 4;
    const int mi = wv & 1, ni = wv >> 1;
    const int b = blockIdx.y;
    const int p0 = blockIdx.x * (MT * 32);
    const int obase = blockIdx.z * 64;
    const int HW = H * W;
    const int SH = UP ? (H >> 1) : H;
    const int SW = UP ? (W >> 1) : W;
    const int SHW = SH * SW;
    const int PAD = K / 2;
    const int C2 = C - C1;
    const int nch = C >> 5;

    const int y0 = p0 / W;
    const int rbase = (y0 <= PAD) ? 0 : (UP ? ((y0 - PAD) >> 1) : (y0 - PAD));

    int rs[MT][K], cs[MT][K];
#pragma unroll
    for (int ms = 0; ms < MT; ++ms) {
        const int pm = p0 + mi * (MT * 16) + ms * 16 + ln15;
        const int ym = pm / W, xm = pm - ym * W;
#pragma unroll
        for (int tt = 0; tt < K; ++tt) {
            int yy = ym + tt - PAD;
            yy = yy < 0 ? -yy : yy; yy = yy >= H ? 2 * H - 2 - yy : yy;
            rs[ms][tt] = (UP ? (yy >> 1) : yy) - rbase;
            int xx = xm + tt - PAD;
            xx = xx < 0 ? -xx : xx; xx = xx >= W ? 2 * W - 2 - xx : xx;
            cs[ms][tt] = UP ? (xx >> 1) : xx;
        }
    }

    f32x4 acc[MT][2];
#pragma unroll
    for (int i = 0; i < MT; ++i)
#pragma unroll
        for (int j = 0; j < 2; ++j) acc[i][j] = (f32x4)0.f;

    for (int cc = 0; cc < nch; ++cc) {
        const int c0 = cc << 5;
        __syncthreads();
        for (int idx = tid; idx < NR * NCOL * 4; idx += 256) {
            const int c_ = idx % NCOL;
            const int r_ = (idx / NCOL) % NR;
            const int cq = idx / (NCOL * NR);
            int rr = rbase + r_; rr = rr >= SH ? SH - 1 : rr;
            const int sidx = rr * SW + c_;
            short8 vh, vl;
#pragma unroll
            for (int q = 0; q < 8; ++q) {
                const int c = c0 + cq * 8 + q;
                float v;
                if (c < C1) v = LD(src1 + (size_t)(b * C1 + c) * SHW + sidx);
                else        v = LD(src2 + (size_t)(b * C2 + (c - C1)) * SHW + sidx);
                const u16 hv = f2b(v);
                vh[q] = (short)hv;
                if (ASPLIT) vl[q] = (short)f2b(v - b2fu(hv));
            }
            *(short8*)&Ah[idx * 8] = vh;
            if (ASPLIT) *(short8*)&Al[idx * 8] = vl;
        }
        __syncthreads();

#pragma unroll
        for (int t = 0; t < KK; ++t) {
            const int ty = t / K, tx = t - ty * K;
            const size_t wb0 = ((((size_t)t * nch + cc) * 4 + quad) * O
                                + obase + ni * 32 + ln15) * 8;
            const short8 b0h = *(const short8*)(wth + wb0);
            const short8 b1h = *(const short8*)(wth + wb0 + 128);
            const short8 b0l = *(const short8*)(wtl + wb0);
            const short8 b1l = *(const short8*)(wtl + wb0 + 128);
#pragma unroll
            for (int ms = 0; ms < MT; ++ms) {
                const int ao = ((quad * NR + rs[ms][ty]) * NCOL + cs[ms][tx]) * 8;
                const short8 a = *(const short8*)&Ah[ao];
                acc[ms][0] = __builtin_amdgcn_mfma_f32_16x16x32_bf16(a, b0h, acc[ms][0], 0, 0, 0);
                acc[ms][0] = __builtin_amdgcn_mfma_f32_16x16x32_bf16(a, b0l, acc[ms][0], 0, 0, 0);
                acc[ms][1] = __builtin_amdgcn_mfma_f32_16x16x32_bf16(a, b1h, acc[ms][1], 0, 0, 0);
                acc[ms][1] = __builtin_amdgcn_mfma_f32_16x16x32_bf16(a, b1l, acc[ms][1], 0, 0, 0);
                if (ASPLIT) {
                    const short8 al = *(const short8*)&Al[ao];
                    acc[ms][0] = __builtin_amdgcn_mfma_f32_16x16x32_bf16(al, b0h, acc[ms][0], 0, 0, 0);
                    acc[ms][1] = __builtin_amdgcn_mfma_f32_16x16x32_bf16(al, b1h, acc[ms][1], 0, 0, 0);
                }
            }
        }
    }

#pragma unroll
    for (int ms = 0; ms < MT; ++ms) {
#pragma unroll
        for (int ns = 0; ns < 2; ++ns) {
            const int o = obase + ni * 32 + ns * 16 + ln15;
            const float bv = bias[o];
            const f32x4 av = acc[ms][ns];
#pragma unroll
            for (int r = 0; r < 4; ++r) {
                const int pp = p0 + mi * (MT * 16) + ms * 16 + (quad << 2) + r;
                const float v = av[r] + bv;
                const size_t oidx = ((size_t)(b * O + o)) * HW + pp;
                if (EPI == 0) ((float*)outv)[oidx] = v;
                else          ((bf16*)outv)[oidx] = __float2bfloat16(v);
            }
        }
    }
}

// ========== mdcn_mfma: deformable conv on MFMA, cc-OUTER / k-inner (L2-hot) ==========
// Per 32-channel chunk: the chunk's planes stay L1/L2-hot across all 9 taps.
// Bilinear params recomputed per (cc,k) from LDS tables (~25 VALU, negligible).
template<typename OT, bool ASPLIT>
__global__ __launch_bounds__(256) void mdcn_mfma(
        const float* __restrict__ skip, const float* __restrict__ om,
        const u16* __restrict__ wth, const u16* __restrict__ wtl,
        const float* __restrict__ bias,
        OT* __restrict__ out, int C, int O, int H, int W)
{
    __shared__ float tpy[576], tpxs[576], tms[576];
    __shared__ __align__(16) u16 Ah[2][2048];
    __shared__ __align__(16) u16 Al[ASPLIT ? 2 : 1][2048];
    __shared__ __align__(16) u16 Bs[2][2][2048];

    const int tid = threadIdx.x;
    const int lane = tid & 63;
    const int wv = tid >> 6;
    const int ln15 = lane & 15;
    const int quad = lane >> 4;
    const int mi = wv & 1, ni = wv >> 1;
    const int b = blockIdx.y;
    const int p0 = blockIdx.x * 64;
    const int obase = blockIdx.z * 64;
    const int HW = H * W;
    const int nch = C >> 5;

    const float* omb = om + (size_t)b * 27 * HW;
    for (int i = tid; i < 576; i += 256) {
        const int k = i >> 6, px_ = i & 63;
        const int p = p0 + px_;
        const int y = p / W, x = p - y * W;
        const float dy = omb[(2 * k) * HW + p];
        const float dx = omb[(2 * k + 1) * HW + p];
        const float mk = 1.f / (1.f + expf(-omb[(18 + k) * HW + p]));
        float py = (float)(y + k / 3 - 1) + dy;
        float pxx = (float)(x + k % 3 - 1) + dx;
        py  = fminf(fmaxf(py, -2.f), (float)H + 1.f);
        pxx = fminf(fmaxf(pxx, -2.f), (float)W + 1.f);
        tpy[i] = py; tpxs[i] = pxx; tms[i] = mk;
    }
    __syncthreads();

    f32x4 acc[2][2];
#pragma unroll
    for (int i = 0; i < 2; ++i)
#pragma unroll
        for (int j = 0; j < 2; ++j) acc[i][j] = (f32x4)0.f;

    const float* xb = skip + (size_t)b * C * HW;
    const int ao0 = ((mi * 32 + ln15) * 4 + quad) * 8;
    const int ao1 = ((mi * 32 + 16 + ln15) * 4 + quad) * 8;
    const int bo0 = (quad * 64 + ni * 32 + ln15) * 8;
    const int bo1 = bo0 + 16 * 8;

    int chunk = 0;
    for (int cc = 0; cc < nch; ++cc) {
        const int c0c = cc << 5;
        const float* pb = xb + (size_t)(c0c + (wv << 3)) * HW;
        for (int k = 0; k < 9; ++k, ++chunk) {
            const int s = chunk & 1;
            // bilinear params for (k, pixel=lane) from LDS tables
            const float py = tpy[k * 64 + lane], pxx = tpxs[k * 64 + lane], mk = tms[k * 64 + lane];
            const float y0f = floorf(py), x0f = floorf(pxx);
            const int y0 = (int)y0f, x0 = (int)x0f;
            const float wy1 = py - y0f, wx1 = pxx - x0f;
            const float wy0 = 1.f - wy1, wx0 = 1.f - wx1;
            const bool r0v = (y0 >= 0 && y0 < H), r1v = (y0 + 1 >= 0 && y0 + 1 < H);
            const bool c0v = (x0 >= 0 && x0 < W), c1v = (x0 + 1 >= 0 && x0 + 1 < W);
            const float w00 = (r0v && c0v) ? wy0 * wx0 * mk : 0.f;
            const float w01 = (r0v && c1v) ? wy0 * wx1 * mk : 0.f;
            const float w10 = (r1v && c0v) ? wy1 * wx0 * mk : 0.f;
            const float w11 = (r1v && c1v) ? wy1 * wx1 * mk : 0.f;
            const int i00 = (r0v ? y0 : 0) * W + (c0v ? x0 : 0);
            const int i01 = (r0v ? y0 : 0) * W + (c1v ? x0 + 1 : 0);
            const int i10 = (r1v ? y0 + 1 : 0) * W + (c0v ? x0 : 0);
            const int i11 = (r1v ? y0 + 1 : 0) * W + (c1v ? x0 + 1 : 0);
            {   // stage A: pixel=lane, 8 channels (block wv)
                short8 vh, vl;
#pragma unroll
                for (int q = 0; q < 8; ++q) {
                    const float* pl = pb + (size_t)q * HW;
                    const float v = w00 * pl[i00] + w01 * pl[i01] + w10 * pl[i10] + w11 * pl[i11];
                    const u16 hv = f2b(v);
                    vh[q] = (short)hv;
                    if (ASPLIT) vl[q] = (short)f2b(v - b2fu(hv));
                }
                *(short8*)&Ah[s][(lane * 4 + wv) * 8] = vh;
                if (ASPLIT) *(short8*)&Al[s][(lane * 4 + wv) * 8] = vl;
            }
            {   // stage B (wsplit2 layout [k][cc][quad][O][8])
                const size_t base = ((((size_t)k * nch + cc) * 4 + wv) * O + obase + lane) * 8;
                *(short8*)&Bs[s][0][tid * 8] = *(const short8*)(wth + base);
                *(short8*)&Bs[s][1][tid * 8] = *(const short8*)(wtl + base);
            }
            __syncthreads();
            const short8 a0 = *(const short8*)&Ah[s][ao0];
            const short8 a1 = *(const short8*)&Ah[s][ao1];
            const short8 b0h = *(const short8*)&Bs[s][0][bo0];
            const short8 b1h = *(const short8*)&Bs[s][0][bo1];
            const short8 b0l = *(const short8*)&Bs[s][1][bo0];
            const short8 b1l = *(const short8*)&Bs[s][1][bo1];
            acc[0][0] = __builtin_amdgcn_mfma_f32_16x16x32_bf16(a0, b0h, acc[0][0], 0, 0, 0);
            acc[0][0] = __builtin_amdgcn_mfma_f32_16x16x32_bf16(a0, b0l, acc[0][0], 0, 0, 0);
            acc[0][1] = __builtin_amdgcn_mfma_f32_16x16x32_bf16(a0, b1h, acc[0][1], 0, 0, 0);
            acc[0][1] = __builtin_amdgcn_mfma_f32_16x16x32_bf16(a0, b1l, acc[0][1], 0, 0, 0);
            acc[1][0] = __builtin_amdgcn_mfma_f32_16x16x32_bf16(a1, b0h, acc[1][0], 0, 0, 0);
            acc[1][0] = __builtin_amdgcn_mfma_f32_16x16x32_bf16(a1, b0l, acc[1][0], 0, 0, 0);
            acc[1][1] = __builtin_amdgcn_mfma_f32_16x16x32_bf16(a1, b1h, acc[1][1], 0, 0, 0);
            acc[1][1] = __builtin_amdgcn_mfma_f32_16x16x32_bf16(a1, b1l, acc[1][1], 0, 0, 0);
            if (ASPLIT) {
                const short8 a0l = *(const short8*)&Al[s][ao0];
                const short8 a1l = *(const short8*)&Al[s][ao1];
                acc[0][0] = __builtin_amdgcn_mfma_f32_16x16x32_bf16(a0l, b0h, acc[0][0], 0, 0, 0);
                acc[0][1] = __builtin_amdgcn_mfma_f32_16x16x32_bf16(a0l, b1h, acc[0][1], 0, 0, 0);
                acc[1][0] = __builtin_amdgcn_mfma_f32_16x16x32_bf16(a1l, b0h, acc[1][0], 0, 0, 0);
                acc[1][1] = __builtin_amdgcn_mfma_f32_16x16x32_bf16(a1l, b1h, acc[1][1], 0, 0, 0);
            }
        }
    }

#pragma unroll
    for (int ms = 0; ms < 2; ++ms) {
#pragma unroll
        for (int ns = 0; ns < 2; ++ns) {
            const int o = obase + ni * 32 + ns * 16 + ln15;
            const float bv = bias[o];
#pragma unroll
            for (int r = 0; r < 4; ++r) {
                const int pp = p0 + mi * 32 + ms * 16 + (quad << 2) + r;
                ST(out + ((size_t)(b * O + o)) * HW + pp, acc[ms][ns][r] + bv);
            }
        }
    }
}

// ================= old conv_mfma (R14) — off-convs + conv6 =================
template<typename T1, typename T2, int K, bool REFLECT, bool UP, int NTN, int EPI, bool ASPLIT>
__global__ __launch_bounds__(256) void conv_mfma(
        const T1* __restrict__ src1, const T2* __restrict__ src2,
        int C1, int C,
        const u16* __restrict__ wth, const u16* __restrict__ wtl,
        const float* __restrict__ bias,
        void* __restrict__ outv, int O, int H, int W)
{
    constexpr int KK = K * K;
    __shared__ __align__(16) u16 As[64 * 40];
    __shared__ __align__(16) u16 Alo[ASPLIT ? 64 * 40 : 8];
    __shared__ __align__(16) u16 Bh[NTN * 16 * 40];
    __shared__ __align__(16) u16 Bl[NTN * 16 * 40];

    const int tid  = threadIdx.x;
    const int wv   = tid >> 6;
    const int lane = tid & 63;
    const int ln15 = lane & 15;
    const int b    = blockIdx.y;
    const int p0   = blockIdx.x * 64;
    const int obase = blockIdx.z * (NTN * 16);
    const int HW = H * W;
    const int Hs = UP ? (H >> 1) : H;
    const int Ws = UP ? (W >> 1) : W;
    const int HsWs = Hs * Ws;
    const int PAD = K / 2;
    const int C2 = C - C1;
    const int m_stage = tid & 63;

    const int p = p0 + m_stage;
    const int y = p / W, x = p - y * W;
    int off[KK];
    float msk[KK];
#pragma unroll
    for (int ty = 0; ty < K; ++ty) {
#pragma unroll
        for (int tx = 0; tx < K; ++tx) {
            int yy = y + ty - PAD, xx = x + tx - PAD;
            bool vv = true;
            if (REFLECT) {
                yy = yy < 0 ? -yy : yy; yy = yy >= H ? 2 * H - 2 - yy : yy;
                xx = xx < 0 ? -xx : xx; xx = xx >= W ? 2 * W - 2 - xx : xx;
            } else {
                vv = (yy >= 0 && yy < H && xx >= 0 && xx < W);
                yy = yy < 0 ? 0 : (yy >= H ? H - 1 : yy);
                xx = xx < 0 ? 0 : (xx >= W ? W - 1 : xx);
            }
            off[ty * K + tx] = (UP ? (yy >> 1) : yy) * Ws + (UP ? (xx >> 1) : xx);
            msk[ty * K + tx] = vv ? 1.f : 0.f;
        }
    }

    f32x4 acc[NTN];
#pragma unroll
    for (int nt = 0; nt < NTN; ++nt) acc[nt] = (f32x4)0.f;

    const int aswz = (m_stage >> 3) & 3;
    const int awr  = m_stage * 40 + ((wv ^ aswz) << 3);
    const int arow = wv * 16 + ln15;
    const int ard  = arow * 40 + (((lane >> 4) ^ ((arow >> 3) & 3)) << 3);

    const int nch = C >> 5;
    for (int cc = 0; cc < nch; ++cc) {
        const int c0 = cc << 5;
        for (int t = 0; t < KK; ++t) {
            const int offt = off[t];
            const float mskt = msk[t];
            __syncthreads();
            {
                short8 avh, avl;
#pragma unroll
                for (int q = 0; q < 8; ++q) {
                    const int c = c0 + (wv << 3) + q;
                    float v;
                    if (c < C1) v = LD(src1 + ((size_t)(b * C1 + c)) * HsWs + offt);
                    else        v = LD(src2 + ((size_t)(b * C2 + (c - C1))) * HsWs + offt);
                    if (!REFLECT) v *= mskt;
                    const u16 hv = f2b(v);
                    avh[q] = (short)hv;
                    if (ASPLIT) avl[q] = (short)f2b(v - b2fu(hv));
                }
                *(short8*)&As[awr] = avh;
                if (ASPLIT) *(short8*)&Alo[awr] = avl;
            }
            for (int i = tid; i < NTN * 16 * 4; i += 256) {
                const int row = i >> 2, part = i & 3;
                int o = obase + row; if (o >= O) o = O - 1;
                const int pw = row * 40 + ((part ^ ((row >> 3) & 3)) << 3);
                const size_t wb = ((size_t)t * O + o) * C + c0 + (part << 3);
                *(short8*)&Bh[pw] = *(const short8*)(wth + wb);
                *(short8*)&Bl[pw] = *(const short8*)(wtl + wb);
            }
            __syncthreads();
            const short8 a = *(const short8*)&As[ard];
            short8 al;
            if (ASPLIT) al = *(const short8*)&Alo[ard];
#pragma unroll
            for (int nt = 0; nt < NTN; ++nt) {
                const int brow = nt * 16 + ln15;
                const int brd = brow * 40 + (((lane >> 4) ^ ((brow >> 3) & 3)) << 3);
                const short8 bh = *(const short8*)&Bh[brd];
                acc[nt] = __builtin_amdgcn_mfma_f32_16x16x32_bf16(a, bh, acc[nt], 0, 0, 0);
                const short8 bl = *(const short8*)&Bl[brd];
                acc[nt] = __builtin_amdgcn_mfma_f32_16x16x32_bf16(a, bl, acc[nt], 0, 0, 0);
                if (ASPLIT)
                    acc[nt] = __builtin_amdgcn_mfma_f32_16x16x32_bf16(al, bh, acc[nt], 0, 0, 0);
            }
        }
    }

#pragma unroll
    for (int nt = 0; nt < NTN; ++nt) {
        const int o = obase + nt * 16 + ln15;
        if (o < O) {
            const float bv = bias[o];
#pragma unroll
            for (int r = 0; r < 4; ++r) {
                const int pp = p0 + wv * 16 + ((lane >> 4) << 2) + r;
                const float v = acc[nt][r] + bv;
                const size_t oidx = ((size_t)(b * O + o)) * HW + pp;
                if (EPI == 0)      ((float*)outv)[oidx] = v;
                else if (EPI == 1) ((float*)outv)[oidx] = tanhf(v);
                else               ((bf16*)outv)[oidx] = __float2bfloat16(v);
            }
        }
    }
}

// ---------------- instance norm ----------------
template<typename T>
__global__ __launch_bounds__(256) void inorm_kernel(T* __restrict__ buf,
                                                    float* __restrict__ resid,
                                                    int HW, int mode)
{
    __shared__ double sh0[256], sh1[256];
    const int pl = blockIdx.x;
    T* p = buf + (size_t)pl * HW;
    double s = 0.0, ss = 0.0;
    for (int i = threadIdx.x; i < HW; i += 256) {
        float v = LD(p + i);
        s += (double)v; ss += (double)v * (double)v;
    }
    sh0[threadIdx.x] = s; sh1[threadIdx.x] = ss;
    __syncthreads();
    for (int st = 128; st > 0; st >>= 1) {
        if (threadIdx.x < st) {
            sh0[threadIdx.x] += sh0[threadIdx.x + st];
            sh1[threadIdx.x] += sh1[threadIdx.x + st];
        }
        __syncthreads();
    }
    const double mean = sh0[0] / HW;
    const float m = (float)mean;
    const float var = (float)(sh1[0] / HW - mean * mean);
    const float inv = rsqrtf(var + 1e-5f);
    if (mode == 0) {
        for (int i = threadIdx.x; i < HW; i += 256) {
            float v = (LD(p + i) - m) * inv;
            ST(p + i, v > 0.f ? v : 0.f);
        }
    } else {
        float* r = resid + (size_t)pl * HW;
        for (int i = threadIdx.x; i < HW; i += 256)
            r[i] = r[i] + (LD(p + i) - m) * inv;
    }
}

// ---------------- offset_sum ----------------
__global__ void zero1_kernel(float* __restrict__ out) { if (threadIdx.x == 0) out[0] = 0.f; }

__global__ __launch_bounds__(256) void offsum_one(const float* __restrict__ om, int HW,
                                                  float* __restrict__ out)
{
    __shared__ double sh[256];
    const int n = 8 * 18 * HW;
    double s = 0.0;
    for (int i = blockIdx.x * 256 + threadIdx.x; i < n; i += gridDim.x * 256) {
        const int b = i / (18 * HW); const int r = i - b * 18 * HW;
        const int c = r / HW; const int p = r - c * HW;
        s += fabs((double)om[(size_t)(b * 27 + c) * HW + p]);
    }
    sh[threadIdx.x] = s;
    __syncthreads();
    for (int st = 128; st > 0; st >>= 1) {
        if (threadIdx.x < st) sh[threadIdx.x] += sh[threadIdx.x + st];
        __syncthreads();
    }
    if (threadIdx.x == 0) atomicAdd(out, (float)(0.5 * sh[0] / n));
}

// ---------------- launch ----------------
extern "C" void kernel_launch(void* const* d_in, const int* in_sizes, int n_in,
                              void* d_out, int out_size, void* d_ws, size_t ws_size,
                              hipStream_t stream)
{
    if (n_in < 27) return;
    if (out_size < 393217) return;
    if (in_sizes[0] != 8 * 256 * 32 * 32) return;
    if (in_sizes[1] != 8 * 128 * 64 * 64) return;
    if (in_sizes[2] != 8 * 256 * 32 * 32) return;
    if (in_sizes[25] != 128 * 128 * 9) return;
    if (in_sizes[26] != 128) return;

    const float* x        = (const float*)d_in[0];
    const float* skip1    = (const float*)d_in[1];
    const float* skip2    = (const float*)d_in[2];
    const float* rbw[2][2] = {{(const float*)d_in[3], (const float*)d_in[5]},
                              {(const float*)d_in[7], (const float*)d_in[9]}};
    const float* rbb[2][2] = {{(const float*)d_in[4], (const float*)d_in[6]},
                              {(const float*)d_in[8], (const float*)d_in[10]}};
    const float* conv1_w = (const float*)d_in[11]; const float* conv1_b = (const float*)d_in[12];
    const float* conv3_w = (const float*)d_in[13]; const float* conv3_b = (const float*)d_in[14];
    const float* conv5_w = (const float*)d_in[15]; const float* conv5_b = (const float*)d_in[16];
    const float* conv6_w = (const float*)d_in[17]; const float* conv6_b = (const float*)d_in[18];
    const float* dcn2_off_w = (const float*)d_in[19]; const float* dcn2_off_b = (const float*)d_in[20];
    const float* dcn2_w = (const float*)d_in[21]; const float* dcn2_b = (const float*)d_in[22];
    const float* dcn1_off_w = (const float*)d_in[23]; const float* dcn1_off_b = (const float*)d_in[24];
    const float* dcn1_w = (const float*)d_in[25]; const float* dcn1_b = (const float*)d_in[26];

    float* outp = (float*)d_out;

    const size_t NEED_F32 = 9494528ull;      // unchanged, proven R8-R17
    if (ws_size < NEED_F32 * 4ull) return;

    float* ws = (float*)d_ws;
    const size_t NA = 2097152ull;            // 8*256*32*32
    float* A   = ws;                          // x / rb accum / pre2 ; later Ib
    float* Bb  = ws + NA;                     // h / D ; later wm1 ; later Jb(lo half)
    float* Tmp = ws + 2 * NA;                 // rb tmp ; {wm2,wo2} ; wt3 ; wo1 ; Jb(hi half)
    float* om2 = ws + 3 * NA;                 // [221184] ; after offsum: conv6 wt
    float* om1 = om2 + 221184;                // [884736] ; later conv5 wt
    bf16*  Fb  = (bf16*)(om1 + 884736);       // c3 bf16 ; BEFORE conv3: early MFMA weights
    bf16*  Ib  = (bf16*)A;                    // pre1 bf16
    bf16*  Jb  = (bf16*)Bb;                   // c5 bf16 (Bb+Tmp)
    u16*   wm2h = (u16*)Tmp;                  // mdcn2 MFMA w
    u16*   wm2l = wm2h + 589824;
    u16*   wo2h = (u16*)(Tmp + 589824);       // dcn2 off-conv MFMA w
    u16*   wo2l = wo2h + 124416;
    u16*   wt3h = (u16*)Tmp;                  // conv3 MFMA w (after mdcn2)
    u16*   wt3l = wt3h + 25 * 128 * 512;
    u16*   wo1h = (u16*)Tmp;                  // dcn1 off-conv MFMA w (after conv3)
    u16*   wo1l = wo1h + 62208;
    u16*   wm1h = (u16*)Bb;                   // mdcn1 MFMA w (Bb dead after conv3)
    u16*   wm1l = wm1h + 147456;
    u16*   wt5h = (u16*)om1;                  // conv5 MFMA w (after offsum)
    u16*   wt5l = wt5h + 25 * 64 * 256;
    u16*   wt6h = (u16*)om2;                  // conv6 MFMA w (om2 dead after offsum)
    u16*   wt6l = wt6h + 9408;
    u16*   wEh = (u16*)Fb;                    // early conv MFMA weights (Fb free until conv3)

    copy_kernel<<<8192, 256, 0, stream>>>(x, A, (int)NA);

    // ResBlocks via conv_mfma3 (A+W hi/lo split -> ~f32 precision)
    for (int r = 0; r < 2; ++r) {
        wsplit2_kernel<<<2304, 256, 0, stream>>>(rbw[r][0], wEh, wEh + 589824, 256, 256, 9);
        conv_mfma3<float, float, 3, false, 0, true, 4, 32, 2><<<dim3(16, 8, 4), 256, 0, stream>>>(
            A, (const float*)nullptr, 256, 256, wEh, wEh + 589824, rbb[r][0], Bb, 256, 32, 32);
        inorm_kernel<float><<<2048, 256, 0, stream>>>(Bb, nullptr, 1024, 0);
        wsplit2_kernel<<<2304, 256, 0, stream>>>(rbw[r][1], wEh, wEh + 589824, 256, 256, 9);
        conv_mfma3<float, float, 3, false, 0, true, 4, 32, 2><<<dim3(16, 8, 4), 256, 0, stream>>>(
            Bb, (const float*)nullptr, 256, 256, wEh, wEh + 589824, rbb[r][1], Tmp, 256, 32, 32);
        inorm_kernel<float><<<2048, 256, 0, stream>>>(Tmp, A, 1024, 1);
    }

    // conv1 (5x5, 256->256) via conv_mfma3 + IN/ReLU
    wsplit2_kernel<<<6400, 256, 0, stream>>>(conv1_w, wEh, wEh + 1638400, 256, 256, 25);
    conv_mfma3<float, float, 5, false, 0, true, 6, 32, 2><<<dim3(16, 8, 4), 256, 0, stream>>>(
        A, (const float*)nullptr, 256, 256, wEh, wEh + 1638400, conv1_b, Bb, 256, 32, 32);
    inorm_kernel<float><<<2048, 256, 0, stream>>>(Bb, nullptr, 1024, 0);

    // dcn2: off-conv MFMA -> om2 ; mdcn_mfma -> A (pre2 f32)
    wsplit_kernel<<<486, 256, 0, stream>>>(dcn2_off_w, wo2h, wo2l, 27, 512, 9);
    conv_mfma<float, float, 3, false, false, 2, 0, false><<<dim3(16, 8, 1), 256, 0, stream>>>(
        Bb, skip2, 256, 512, wo2h, wo2l, dcn2_off_b, om2, 27, 32, 32);
    wsplit2_kernel<<<2304, 256, 0, stream>>>(dcn2_w, wm2h, wm2l, 256, 256, 9);
    mdcn_mfma<float, true><<<dim3(16, 8, 4), 256, 0, stream>>>(
        skip2, om2, wm2h, wm2l, dcn2_b, A, 256, 256, 32, 32);

    // conv3: conv_mfma3 (UP, MT=4 -> M=128 = 2 rows), 512->128 @64x64 -> Fb + IN/ReLU
    wsplit2_kernel<<<6400, 256, 0, stream>>>(conv3_w, wt3h, wt3l, 128, 512, 25);
    conv_mfma3<float, float, 5, true, 2, false, 4, 32, 4><<<dim3(32, 8, 2), 256, 0, stream>>>(
        A, Bb, 256, 512, wt3h, wt3l, conv3_b, Fb, 128, 64, 64);
    inorm_kernel<bf16><<<1024, 256, 0, stream>>>(Fb, nullptr, 4096, 0);

    // dcn1: off-conv MFMA -> om1 ; mdcn_mfma -> Ib (pre1 bf16)
    wsplit_kernel<<<243, 256, 0, stream>>>(dcn1_off_w, wo1h, wo1l, 27, 256, 9);
    conv_mfma<bf16, float, 3, false, false, 2, 0, false><<<dim3(64, 8, 1), 256, 0, stream>>>(
        Fb, skip1, 128, 256, wo1h, wo1l, dcn1_off_b, om1, 27, 64, 64);
    wsplit2_kernel<<<576, 256, 0, stream>>>(dcn1_w, wm1h, wm1l, 128, 128, 9);
    mdcn_mfma<bf16, true><<<dim3(64, 8, 2), 256, 0, stream>>>(
        skip1, om1, wm1h, wm1l, dcn1_b, Ib, 128, 128, 64, 64);

    // offset_sum now (frees om1/om2 regions for conv5/conv6 weights)
    zero1_kernel<<<1, 64, 0, stream>>>(outp + 393216);
    offsum_one<<<64, 256, 0, stream>>>(om1, 4096, outp + 393216);
    offsum_one<<<64, 256, 0, stream>>>(om2, 1024, outp + 393216);

    // conv5: conv_mfma3 (UP, MT=4 -> M=128 = 1 full row), 256->64 @128x128 -> Jb + IN/ReLU
    wsplit2_kernel<<<1600, 256, 0, stream>>>(conv5_w, wt5h, wt5l, 64, 256, 25);
    conv_mfma3<bf16, bf16, 5, true, 2, false, 3, 64, 4><<<dim3(128, 8, 1), 256, 0, stream>>>(
        Ib, Fb, 128, 256, wt5h, wt5l, conv5_b, Jb, 64, 128, 128);
    inorm_kernel<bf16><<<512, 256, 0, stream>>>(Jb, nullptr, 16384, 0);

    // conv6: 7x7, 64->3, tanh via conv_mfma -> d_out (f32)
    wsplit_kernel<<<37, 256, 0, stream>>>(conv6_w, wt6h, wt6l, 3, 64, 49);
    conv_mfma<bf16, float, 7, true, false, 1, 1, false><<<dim3(256, 8, 1), 256, 0, stream>>>(
        Jb, (const float*)nullptr, 64, 64, wt6h, wt6l, conv6_b, (void*)outp, 3, 128, 128);
}